// Round 12
// baseline (2021.945 us; speedup 1.0000x reference)
//
#include <hip/hip_runtime.h>
#include <cstdint>

// PicoGPT forward: V=32000 D=1024 DK=DV=64 H=16 DH=4096 L=8, input [2,1024]
// bf16 MFMA GEMMs: BK=64, XOR-swizzled LDS, global_load_lds both operands
// (m97+T2), XCD swizzle (T1). R12: BM=64 tiles for layer GEMMs (2x blocks ->
// 3-4 blocks/CU co-resident; readout keeps BM=128), cvtall ILP 4->8.

#define DEVI __device__ __forceinline__
#define NEG_INF (-__builtin_inff())

typedef __attribute__((ext_vector_type(8))) short s8v;            // 8 x bf16
typedef __attribute__((ext_vector_type(8))) unsigned short us8;   // 8 x bf16 store
typedef __attribute__((ext_vector_type(4))) float f4v;

DEVI ushort f2bf(float f) {  // RTNE f32 -> bf16
  uint32_t x = __float_as_uint(f);
  x += 0x7fffu + ((x >> 16) & 1u);
  return (ushort)(x >> 16);
}

DEVI void gload16(const void* g, void* l) {  // async global->LDS, 16B/lane
  __builtin_amdgcn_global_load_lds((const __attribute__((address_space(1))) void*)g,
                                   (__attribute__((address_space(3))) void*)l, 16, 0, 0);
}

// ---------- f32 -> bf16 convert (generic) ----------
__global__ __launch_bounds__(256) void cvt_kernel(const float* __restrict__ in,
                                                  ushort* __restrict__ out, int n) {
  int i = (blockIdx.x * 256 + threadIdx.x) * 4;
  if (i >= n) return;
  float4 v = *reinterpret_cast<const float4*>(in + i);
  ushort4 o;
  o.x = f2bf(v.x); o.y = f2bf(v.y); o.z = f2bf(v.z); o.w = f2bf(v.w);
  *reinterpret_cast<ushort4*>(out + i) = o;
}

// ---------- all weights f32 -> bf16, 8-way ILP ----------
// grid = 125042688/8192 = 15264 blocks; every segment boundary divides 8192.
__global__ __launch_bounds__(256) void cvtall_kernel(const float* __restrict__ wq,
                                                     const float* __restrict__ wk,
                                                     const float* __restrict__ wv,
                                                     const float* __restrict__ fc1w,
                                                     const float* __restrict__ fc2w,
                                                     const float* __restrict__ row_,
                                                     ushort* __restrict__ wqkv_bf,
                                                     ushort* __restrict__ fc1_bf,
                                                     ushort* __restrict__ fc2_bf,
                                                     ushort* __restrict__ ro_bf) {
  const size_t NQ3 = 25165824, NF = 33554432;   // 3*8M, 32M
  size_t b0 = (size_t)blockIdx.x * 8192;
  const float* src;
  ushort* dst;
  if (b0 < NQ3) {                                // qkv -> [L][3][1M] interleave
    int which = (int)(b0 >> 23);
    size_t j = b0 & 8388607;
    src = (which == 0 ? wq : which == 1 ? wk : wv) + j;
    dst = wqkv_bf + (j >> 20) * 3145728 + (size_t)which * 1048576 + (j & 1048575);
  } else if (b0 < NQ3 + NF) {
    size_t r = b0 - NQ3;
    src = fc1w + r; dst = fc1_bf + r;
  } else if (b0 < NQ3 + 2 * NF) {
    size_t r = b0 - NQ3 - NF;
    src = fc2w + r; dst = fc2_bf + r;
  } else {
    size_t r = b0 - NQ3 - 2 * NF;
    src = row_ + r; dst = ro_bf + r;
  }
  int t4 = threadIdx.x * 4;
  float4 v[8];
#pragma unroll
  for (int k = 0; k < 8; ++k)
    v[k] = *reinterpret_cast<const float4*>(src + t4 + k * 1024);
#pragma unroll
  for (int k = 0; k < 8; ++k) {
    ushort4 o = {f2bf(v[k].x), f2bf(v[k].y), f2bf(v[k].z), f2bf(v[k].w)};
    *reinterpret_cast<ushort4*>(dst + t4 + k * 1024) = o;
  }
}

// ---------- embedding + sinusoidal pos encoding, grid = 2048 rows ----------
__global__ __launch_bounds__(256) void embed_kernel(const int* __restrict__ ids,
                                                    const float* __restrict__ emb,
                                                    float* __restrict__ x) {
  int row = blockIdx.x;  // n*1024 + t
  int t = row & 1023;
  int id = ids[row];
  int d0 = threadIdx.x * 4;
  float4 e = *reinterpret_cast<const float4*>(emb + (size_t)id * 1024 + d0);
  float pe[4];
#pragma unroll
  for (int i = 0; i < 4; ++i) {
    int d = d0 + i;
    float dv = expf((float)(d & ~1) * (-9.210340371976184f / 1024.f));
    float ang = (float)t * dv;
    pe[i] = (d & 1) ? cosf(ang) : sinf(ang);
  }
  float4 o;
  o.x = e.x + pe[0]; o.y = e.y + pe[1]; o.z = e.z + pe[2]; o.w = e.w + pe[3];
  *reinterpret_cast<float4*>(x + (size_t)row * 1024 + d0) = o;
}

// ---------- LayerNorm (f32 in, bf16 out), grid = 2048 rows ----------
__global__ __launch_bounds__(256) void ln_kernel(const float* __restrict__ x,
                                                 const float* __restrict__ w,
                                                 const float* __restrict__ b,
                                                 ushort* __restrict__ out) {
  int row = blockIdx.x, tid = threadIdx.x;
  int lane = tid & 63, wid = tid >> 6;
  const float* xr = x + (size_t)row * 1024;
  float4 v = reinterpret_cast<const float4*>(xr)[tid];
  __shared__ float red[8];
  float s = v.x + v.y + v.z + v.w;
#pragma unroll
  for (int o = 32; o; o >>= 1) s += __shfl_xor(s, o);
  if (lane == 0) red[wid] = s;
  __syncthreads();
  float mean = (red[0] + red[1] + red[2] + red[3]) * (1.f / 1024.f);
  float d0 = v.x - mean, d1 = v.y - mean, d2 = v.z - mean, d3 = v.w - mean;
  float s2 = d0 * d0 + d1 * d1 + d2 * d2 + d3 * d3;
#pragma unroll
  for (int o = 32; o; o >>= 1) s2 += __shfl_xor(s2, o);
  if (lane == 0) red[4 + wid] = s2;
  __syncthreads();
  float var = (red[4] + red[5] + red[6] + red[7]) * (1.f / 1024.f);
  float rstd = rsqrtf(var + 1e-5f);
  float4 wv = reinterpret_cast<const float4*>(w)[tid];
  float4 bv = reinterpret_cast<const float4*>(b)[tid];
  ushort4 o;
  o.x = f2bf(d0 * rstd * wv.x + bv.x);
  o.y = f2bf(d1 * rstd * wv.y + bv.y);
  o.z = f2bf(d2 * rstd * wv.z + bv.z);
  o.w = f2bf(d3 * rstd * wv.w + bv.w);
  *reinterpret_cast<ushort4*>(out + (size_t)row * 1024 + tid * 4) = o;
}

// ---------- bf16 MFMA GEMM: C[M,N] = A[M,K] * Bw[N,K]^T ----------
// BMx128 tile, BK=64, 256 thr = 4 waves (2x2), wave = (BM/2)x64.
// XCD-bijective swizzle (needs gridDim.x*gridDim.y % 8 == 0).
enum { EPI_QKV = 0, EPI_GELU = 1, EPI_RES = 2, EPI_BIAS = 3 };

template <int EPI, int BM>
__global__ __launch_bounds__(256, 4) void gemm_kernel(const ushort* __restrict__ A,
                                                      const ushort* __restrict__ Bw,
                                                      const float* __restrict__ bias,
                                                      void* __restrict__ outp,
                                                      void* __restrict__ outp2,
                                                      int M, int N, int K, int kz) {
  constexpr int MI = BM / 32;            // 16-row frag groups per wave
  __shared__ char smem[BM * 128 + 16384];
  ushort* As = (ushort*)smem;            // [BM][64] bf16, chunk-swizzled
  ushort* Bs = (ushort*)(smem + BM * 128);  // [128][64]
  int tid = threadIdx.x;
  int lane = tid & 63;
  int wid = tid >> 6;
  int wr = wid >> 1, wc = wid & 1;       // 2x2 wave grid, wave = (BM/2)x64

  // XCD swizzle: consecutive tiles land on one XCD -> B panels fetched once/XCD
  int gx = gridDim.x;
  int nwg = gx * gridDim.y;
  int bid = blockIdx.x + blockIdx.y * gx;
  int swz = (bid & 7) * (nwg >> 3) + (bid >> 3);
  int bm = swz % gx, bn = swz / gx;

  int kbeg = 0, kend = K;
  if constexpr (EPI == EPI_RES) {        // split-K over gridDim.z
    kbeg = blockIdx.z * kz;
    kend = kbeg + kz;
  }

  const ushort* Ab = A + (size_t)(bm * BM) * K;
  const ushort* Bb = Bw + (size_t)(bn * 128) * K;

  auto stage = [&](int k0) {
#pragma unroll
    for (int i = 0; i < BM / 32; ++i) {  // BM*8 chunks of 16B
      int c = tid + i * 256;
      int row = c >> 3, j = c & 7;
      gload16(Ab + (size_t)row * K + k0 + ((j ^ (row & 7)) * 8), &As[c * 8]);
    }
#pragma unroll
    for (int i = 0; i < 4; ++i) {
      int c = tid + i * 256;
      int row = c >> 3, j = c & 7;
      gload16(Bb + (size_t)row * K + k0 + ((j ^ (row & 7)) * 8), &Bs[c * 8]);
    }
  };

  f4v acc[MI][4] = {};
  int lr = lane & 15, g = lane >> 4;
  int sx = lr & 7;  // swizzle key (row&7 of every frag row this lane reads)

  stage(kbeg);
  for (int k0 = kbeg; k0 < kend; k0 += 64) {
    __syncthreads();  // staging complete (compiler drains vmcnt at barrier)
    s8v af[MI], bf[4];
#pragma unroll
    for (int mi = 0; mi < MI; ++mi)
      af[mi] = *reinterpret_cast<const s8v*>(
          &As[(wr * (BM / 2) + mi * 16 + lr) * 64 + ((g ^ sx) * 8)]);
#pragma unroll
    for (int ni = 0; ni < 4; ++ni)
      bf[ni] = *reinterpret_cast<const s8v*>(
          &Bs[(wc * 64 + ni * 16 + lr) * 64 + ((g ^ sx) * 8)]);
#pragma unroll
    for (int mi = 0; mi < MI; ++mi)
#pragma unroll
      for (int ni = 0; ni < 4; ++ni)
        acc[mi][ni] = __builtin_amdgcn_mfma_f32_16x16x32_bf16(af[mi], bf[ni],
                                                              acc[mi][ni], 0, 0, 0);
    __builtin_amdgcn_sched_barrier(0);   // keep k-half-1 reads after MFMA batch
#pragma unroll
    for (int mi = 0; mi < MI; ++mi)
      af[mi] = *reinterpret_cast<const s8v*>(
          &As[(wr * (BM / 2) + mi * 16 + lr) * 64 + (((4 + g) ^ sx) * 8)]);
#pragma unroll
    for (int ni = 0; ni < 4; ++ni)
      bf[ni] = *reinterpret_cast<const s8v*>(
          &Bs[(wc * 64 + ni * 16 + lr) * 64 + (((4 + g) ^ sx) * 8)]);
    __syncthreads();               // all frag reads done -> LDS reusable
    if (k0 + 64 < kend) stage(k0 + 64);  // next-tile loads fly under MFMA
#pragma unroll
    for (int mi = 0; mi < MI; ++mi)
#pragma unroll
      for (int ni = 0; ni < 4; ++ni)
        acc[mi][ni] = __builtin_amdgcn_mfma_f32_16x16x32_bf16(af[mi], bf[ni],
                                                              acc[mi][ni], 0, 0, 0);
  }

  // ---- epilogue: per-wave LDS transpose (aliases As/Bs) -> coalesced stores ----
  __syncthreads();  // all frag reads done before aliasing
  float* sw = (float*)smem + wid * (16 * 36);
  int s = lane >> 3, q = lane & 7;
  for (int mi = 0; mi < MI; ++mi) {
    for (int np = 0; np < 2; ++np) {   // 2 column halves of the wave's 64 cols
#pragma unroll
      for (int ni2 = 0; ni2 < 2; ++ni2)
#pragma unroll
        for (int r = 0; r < 4; ++r)
          sw[(g * 4 + r) * 36 + ni2 * 16 + lr] = acc[mi][np * 2 + ni2][r];
      // wave-private scratch round-trip; compiler inserts lgkm waits
      int gnb = bn * 128 + wc * 64 + np * 32;      // wave-uniform col base
      if constexpr (EPI == EPI_QKV) {
        int z = gnb >> 10;                          // 0=q 1=k 2=v (uniform)
        int row0 = bm * BM + wr * (BM / 2) + mi * 16;  // t base (16 rows)
        int nb = row0 >> 10, tp0 = row0 & 1023;
        int hh = (gnb >> 6) & 15, dd0 = gnb & 63;
        if (z < 2) {                                // q/k: row-major [nh][t][64]
          ushort* o = (ushort*)outp;
#pragma unroll
          for (int h = 0; h < 2; ++h) {
            float4 v4 = *reinterpret_cast<const float4*>(&sw[(h * 8 + s) * 36 + q * 4]);
            int tpos = tp0 + h * 8 + s;
            ushort4 o4 = {f2bf(v4.x), f2bf(v4.y), f2bf(v4.z), f2bf(v4.w)};
            *reinterpret_cast<ushort4*>(o + (size_t)z * 2097152 + (size_t)nb * 1048576 +
                                        (size_t)hh * 65536 + (size_t)tpos * 64 +
                                        dd0 + q * 4) = o4;
          }
        } else {                                    // v: transposed [nh][dv][1024]
          ushort* ov = (ushort*)outp2;
          int dvq = lane & 31, hf = lane >> 5;
          us8 w;
#pragma unroll
          for (int j = 0; j < 8; ++j)
            w[j] = f2bf(sw[(hf * 8 + j) * 36 + dvq]);
          *reinterpret_cast<us8*>(ov + (size_t)nb * 1048576 + (size_t)hh * 65536 +
                                  (size_t)(dd0 + dvq) * 1024 + tp0 + hf * 8) = w;
        }
      } else {
#pragma unroll
        for (int h = 0; h < 2; ++h) {
          float4 v4 = *reinterpret_cast<const float4*>(&sw[(h * 8 + s) * 36 + q * 4]);
          int gm = bm * BM + wr * (BM / 2) + mi * 16 + h * 8 + s;
          int gn = gnb + q * 4;
          if constexpr (EPI == EPI_GELU) {
            const float4 bb = *reinterpret_cast<const float4*>(bias + gn);
            float u[4] = {v4.x + bb.x, v4.y + bb.y, v4.z + bb.z, v4.w + bb.w};
            ushort4 o4;
            ushort* po = (ushort*)&o4;
#pragma unroll
            for (int j = 0; j < 4; ++j) {
              float zz = u[j] * (1.5957691216f + 0.0713548162f * u[j] * u[j]);
              float gl = u[j] / (1.f + exp2f(zz * -1.4426950409f));
              po[j] = f2bf(gl);
            }
            *reinterpret_cast<ushort4*>((ushort*)outp + (size_t)gm * N + gn) = o4;
          } else if constexpr (EPI == EPI_RES) {
            float* o = (float*)outp + (size_t)gm * N + gn;
            float4 bb = *reinterpret_cast<const float4*>(bias + gn);
            bool addb = (blockIdx.z == 0);
            atomicAdd(o + 0, v4.x + (addb ? bb.x : 0.f));
            atomicAdd(o + 1, v4.y + (addb ? bb.y : 0.f));
            atomicAdd(o + 2, v4.z + (addb ? bb.z : 0.f));
            atomicAdd(o + 3, v4.w + (addb ? bb.w : 0.f));
          } else {  // EPI_BIAS (readout): non-temporal
            const float4 bb = *reinterpret_cast<const float4*>(bias + gn);
            f4v o4 = {v4.x + bb.x, v4.y + bb.y, v4.z + bb.z, v4.w + bb.w};
            __builtin_nontemporal_store(o4, (f4v*)((float*)outp + (size_t)gm * N + gn));
          }
        }
      }
    }
  }
}

// ---------- MFMA flash attention, balanced q-tile pairs ----------
// grid (8, 32): block bx handles q-tiles {bx, 15-bx} -> constant 17 tile-steps.
__global__ __launch_bounds__(256) void attn_kernel(const ushort* __restrict__ qg,
                                                   const ushort* __restrict__ kg,
                                                   const ushort* __restrict__ vtg,
                                                   float* __restrict__ x) {
  __shared__ ushort Ks[2][4096];  // [64 s][64 d] bf16, swizzled
  __shared__ ushort Vs[2][4096];  // [64 dv][64 s] bf16, swizzled
  __shared__ ushort Ps[4][1024];  // per-wave P [16 q][64 s] bf16, swizzled
  int bx = blockIdx.x;
  int nh = blockIdx.y;
  int tid = threadIdx.x, lane = tid & 63, wid = tid >> 6;
  int lr = lane & 15, g = lane >> 4;
  size_t base = (size_t)nh * 65536;
  const ushort* kb = kg + base;
  const ushort* vb = vtg + base;
  const float SCALE = 0.125f * 1.44269504088896f;

  auto stage = [&](int st, int buf) {
    int s0 = st * 64;
#pragma unroll
    for (int j = 0; j < 2; ++j) {
      int c = tid + j * 256;
      int row = c >> 3;
      int col = ((c & 7) ^ (row & 7)) * 8;  // inverse-swizzled source column
      gload16(kb + (size_t)(s0 + row) * 64 + col, &Ks[buf][c * 8]);
      gload16(vb + (size_t)row * 1024 + s0 + col, &Vs[buf][c * 8]);
    }
  };

  for (int qi = 0; qi < 2; ++qi) {
    int qt = qi ? (15 - bx) : bx;
    int qrow = qt * 64 + wid * 16 + lr;
    s8v qf[2];
    qf[0] = *reinterpret_cast<const s8v*>(qg + base + (size_t)qrow * 64 + g * 8);
    qf[1] = *reinterpret_cast<const s8v*>(qg + base + (size_t)qrow * 64 + 32 + g * 8);

    float m_run = NEG_INF, l_run = 0.f;
    f4v accy[4] = {};
    __syncthreads();               // prior q-tile's LDS reads done
    stage(0, 0);
    int cur = 0;
    for (int st = 0; st <= qt; ++st) {
      __syncthreads();
      if (st < qt) stage(st + 1, cur ^ 1);

      f4v accs[4] = {};
#pragma unroll
      for (int kc = 0; kc < 2; ++kc)
#pragma unroll
        for (int mi = 0; mi < 4; ++mi) {
          int bo = ((mi * 16 + lr) * 128 + kc * 64 + g * 16) ^ ((lr & 7) << 4);
          s8v kf = *reinterpret_cast<const s8v*>(&Ks[cur][bo >> 1]);
          accs[mi] = __builtin_amdgcn_mfma_f32_16x16x32_bf16(kf, qf[kc], accs[mi], 0, 0, 0);
        }

      float z[16];
      float tmax = NEG_INF;
      bool diag = (st == qt);
      int qcol = qt * 64 + wid * 16 + lr;
#pragma unroll
      for (int mi = 0; mi < 4; ++mi)
#pragma unroll
        for (int r = 0; r < 4; ++r) {
          float zz = accs[mi][r] * SCALE;
          if (diag && st * 64 + mi * 16 + g * 4 + r > qcol) zz = NEG_INF;
          z[mi * 4 + r] = zz;
          tmax = fmaxf(tmax, zz);
        }
      tmax = fmaxf(tmax, __shfl_xor(tmax, 16));
      tmax = fmaxf(tmax, __shfl_xor(tmax, 32));
      float m_new = fmaxf(m_run, tmax);
      float corr = exp2f(m_run - m_new);
      float psum = 0.f;
      ushort pb[16];
#pragma unroll
      for (int i = 0; i < 16; ++i) {
        float pv = exp2f(z[i] - m_new);
        psum += pv;
        pb[i] = f2bf(pv);
      }
      psum += __shfl_xor(psum, 16);
      psum += __shfl_xor(psum, 32);
      l_run = l_run * corr + psum;
      m_run = m_new;

      {
        ushort* pw = Ps[wid];
#pragma unroll
        for (int mi = 0; mi < 4; ++mi) {
          int bo = (lr * 128 + mi * 32 + g * 8) ^ ((lr & 7) << 4);
          ushort4 w4 = {pb[mi * 4], pb[mi * 4 + 1], pb[mi * 4 + 2], pb[mi * 4 + 3]};
          *reinterpret_cast<ushort4*>(&pw[bo >> 1]) = w4;
        }
      }

      float cq[4];
#pragma unroll
      for (int r = 0; r < 4; ++r) cq[r] = __shfl(corr, (lane >> 4) * 4 + r);
#pragma unroll
      for (int ni = 0; ni < 4; ++ni)
#pragma unroll
        for (int r = 0; r < 4; ++r) accy[ni][r] *= cq[r];

#pragma unroll
      for (int ks = 0; ks < 2; ++ks) {
        int po = (lr * 128 + ks * 64 + g * 16) ^ ((lr & 7) << 4);
        s8v pa = *reinterpret_cast<const s8v*>(&Ps[wid][po >> 1]);
#pragma unroll
        for (int ni = 0; ni < 4; ++ni) {
          int vo = ((ni * 16 + lr) * 128 + ks * 64 + g * 16) ^ ((lr & 7) << 4);
          s8v vf = *reinterpret_cast<const s8v*>(&Vs[cur][vo >> 1]);
          accy[ni] = __builtin_amdgcn_mfma_f32_16x16x32_bf16(pa, vf, accy[ni], 0, 0, 0);
        }
      }
      cur ^= 1;
    }

    float lq[4];
#pragma unroll
    for (int r = 0; r < 4; ++r) lq[r] = 1.f / __shfl(l_run, (lane >> 4) * 4 + r);
    int n = nh >> 4, hh = nh & 15;
    float* xb = x + ((size_t)(n * 1024 + qt * 64 + wid * 16)) * 1024 + hh * 64;
#pragma unroll
    for (int r = 0; r < 4; ++r) {
      float* xr = xb + (size_t)(g * 4 + r) * 1024;
#pragma unroll
      for (int ni = 0; ni < 4; ++ni)
        xr[ni * 16 + lr] += accy[ni][r] * lq[r];
    }
  }
}

// ---------------------------------------------------------------------------
extern "C" void kernel_launch(void* const* d_in, const int* in_sizes, int n_in,
                              void* d_out, int out_size, void* d_ws, size_t ws_size,
                              hipStream_t stream) {
  const int*   ids  = (const int*)  d_in[0];
  const float* emb  = (const float*)d_in[1];
  const float* ln1w = (const float*)d_in[2];
  const float* ln1b = (const float*)d_in[3];
  const float* wq   = (const float*)d_in[4];
  const float* wk   = (const float*)d_in[5];
  const float* wv   = (const float*)d_in[6];
  const float* ln2w = (const float*)d_in[7];
  const float* ln2b = (const float*)d_in[8];
  const float* fc1w = (const float*)d_in[9];
  const float* fc1b = (const float*)d_in[10];
  const float* fc2w = (const float*)d_in[11];
  const float* fc2b = (const float*)d_in[12];
  const float* row_ = (const float*)d_in[13];
  const float* rob  = (const float*)d_in[14];
  (void)in_sizes; (void)n_in; (void)out_size;

  char* p = (char*)d_ws;
  auto carve = [&](size_t bytes) {
    char* r = p;
    p += (bytes + 255) & ~(size_t)255;
    return (void*)r;
  };
  ushort* ro_bf = (ushort*)carve(32000ull * 1024 * 2);
  float*  x     = (float*) carve(2048ull * 1024 * 4);
  ushort* h     = (ushort*)carve(2048ull * 1024 * 2);
  ushort* qkvb  = (ushort*)carve(3ull * 2097152 * 2);   // bf16 q/k [z][nh][t][64]
  ushort* vtb   = (ushort*)carve(2097152ull * 2);       // bf16 vT [nh][64][1024]
  ushort* mbuf  = (ushort*)carve(2048ull * 4096 * 2);
  ushort* xb    = (ushort*)carve(2048ull * 1024 * 2);
  size_t used_common = (size_t)(p - (char*)d_ws);

  const size_t SZ_WQKV_ALL = 3ull * 8388608 * 2;   // merged [L][3][1M]
  const size_t SZ_FC_ALL   = 33554432ull * 2;
  const size_t SZ_WQKV_1   = 3ull * 1048576 * 2;
  const size_t SZ_FC_1     = 4194304ull * 2;
  bool upfront = ws_size >= used_common + SZ_WQKV_ALL + 2 * SZ_FC_ALL + 4096;

  ushort *wqkv_bf, *fc1_bf, *fc2_bf;
  size_t lq3, lf;
  if (upfront) {
    wqkv_bf = (ushort*)carve(SZ_WQKV_ALL);
    fc1_bf  = (ushort*)carve(SZ_FC_ALL);
    fc2_bf  = (ushort*)carve(SZ_FC_ALL);
    lq3 = 3145728; lf = 4194304;
    cvtall_kernel<<<15264, 256, 0, stream>>>(wq, wk, wv, fc1w, fc2w, row_,
                                             wqkv_bf, fc1_bf, fc2_bf, ro_bf);
  } else {
    wqkv_bf = (ushort*)carve(SZ_WQKV_1);
    fc1_bf  = (ushort*)carve(SZ_FC_1);
    fc2_bf  = (ushort*)carve(SZ_FC_1);
    lq3 = 0; lf = 0;
    cvt_kernel<<<32000, 256, 0, stream>>>(row_, ro_bf, 32768000);
  }

  embed_kernel<<<2048, 256, 0, stream>>>(ids, emb, x);

  for (int l = 0; l < 8; ++l) {
    if (!upfront) {
      cvt_kernel<<<1024, 256, 0, stream>>>(wq + (size_t)l * 1048576, wqkv_bf, 1048576);
      cvt_kernel<<<1024, 256, 0, stream>>>(wk + (size_t)l * 1048576, wqkv_bf + 1048576, 1048576);
      cvt_kernel<<<1024, 256, 0, stream>>>(wv + (size_t)l * 1048576, wqkv_bf + 2097152, 1048576);
      cvt_kernel<<<4096, 256, 0, stream>>>(fc1w + (size_t)l * 4194304, fc1_bf, 4194304);
      cvt_kernel<<<4096, 256, 0, stream>>>(fc2w + (size_t)l * 4194304, fc2_bf, 4194304);
    }
    const ushort* wqkv_l = wqkv_bf + (size_t)l * lq3;
    const ushort* fc1_l  = fc1_bf + (size_t)l * lf;
    const ushort* fc2_l  = fc2_bf + (size_t)l * lf;

    ln_kernel<<<2048, 256, 0, stream>>>(x, ln1w + l * 1024, ln1b + l * 1024, h);
    gemm_kernel<EPI_QKV, 64><<<dim3(32, 24), 256, 0, stream>>>(
        h, wqkv_l, nullptr, qkvb, vtb, 2048, 3072, 1024, 0);
    attn_kernel<<<dim3(8, 32), 256, 0, stream>>>(qkvb, qkvb + 2097152, vtb, x);
    ln_kernel<<<2048, 256, 0, stream>>>(x, ln2w + l * 1024, ln2b + l * 1024, h);
    gemm_kernel<EPI_GELU, 64><<<dim3(32, 32), 256, 0, stream>>>(
        h, fc1_l, fc1b + (size_t)l * 4096, mbuf, nullptr, 2048, 4096, 1024, 0);
    gemm_kernel<EPI_RES, 64><<<dim3(32, 8, 4), 256, 0, stream>>>(
        mbuf, fc2_l, fc2b + (size_t)l * 1024, x, nullptr, 2048, 1024, 4096, 1024);
  }
  cvt_kernel<<<2048, 256, 0, stream>>>(x, xb, 2097152);
  gemm_kernel<EPI_BIAS, 128><<<dim3(16, 250), 256, 0, stream>>>(
      xb, ro_bf, rob, d_out, nullptr, 2048, 32000, 1024, 0);
}

// Round 14
// 1973.345 us; speedup vs baseline: 1.0246x; 1.0246x over previous
//
#include <hip/hip_runtime.h>
#include <cstdint>

// PicoGPT forward: V=32000 D=1024 DK=DV=64 H=16 DH=4096 L=8, input [2,1024]
// bf16 MFMA GEMMs: BK=64, XOR-swizzled LDS, global_load_lds both operands
// (m97+T2), XCD swizzle (T1). R13b: attn 512 blocks (2/CU, complementary
// q-tile pairs co-resident) + setprio (T5); cvtall nt f32 loads (via f4v —
// __builtin_nontemporal_load rejects HIP_vector_type float4).

#define DEVI __device__ __forceinline__
#define NEG_INF (-__builtin_inff())

typedef __attribute__((ext_vector_type(8))) short s8v;            // 8 x bf16
typedef __attribute__((ext_vector_type(8))) unsigned short us8;   // 8 x bf16 store
typedef __attribute__((ext_vector_type(4))) float f4v;

DEVI ushort f2bf(float f) {  // RTNE f32 -> bf16
  uint32_t x = __float_as_uint(f);
  x += 0x7fffu + ((x >> 16) & 1u);
  return (ushort)(x >> 16);
}

DEVI void gload16(const void* g, void* l) {  // async global->LDS, 16B/lane
  __builtin_amdgcn_global_load_lds((const __attribute__((address_space(1))) void*)g,
                                   (__attribute__((address_space(3))) void*)l, 16, 0, 0);
}

// ---------- f32 -> bf16 convert (generic) ----------
__global__ __launch_bounds__(256) void cvt_kernel(const float* __restrict__ in,
                                                  ushort* __restrict__ out, int n) {
  int i = (blockIdx.x * 256 + threadIdx.x) * 4;
  if (i >= n) return;
  float4 v = *reinterpret_cast<const float4*>(in + i);
  ushort4 o;
  o.x = f2bf(v.x); o.y = f2bf(v.y); o.z = f2bf(v.z); o.w = f2bf(v.w);
  *reinterpret_cast<ushort4*>(out + i) = o;
}

// ---------- all weights f32 -> bf16, 8-way ILP, nt loads ----------
// grid = 125042688/8192 = 15264 blocks; every segment boundary divides 8192.
// f32 sources are single-use: non-temporal loads keep L2/L3 for the bf16 copies.
__global__ __launch_bounds__(256) void cvtall_kernel(const float* __restrict__ wq,
                                                     const float* __restrict__ wk,
                                                     const float* __restrict__ wv,
                                                     const float* __restrict__ fc1w,
                                                     const float* __restrict__ fc2w,
                                                     const float* __restrict__ row_,
                                                     ushort* __restrict__ wqkv_bf,
                                                     ushort* __restrict__ fc1_bf,
                                                     ushort* __restrict__ fc2_bf,
                                                     ushort* __restrict__ ro_bf) {
  const size_t NQ3 = 25165824, NF = 33554432;   // 3*8M, 32M
  size_t b0 = (size_t)blockIdx.x * 8192;
  const float* src;
  ushort* dst;
  if (b0 < NQ3) {                                // qkv -> [L][3][1M] interleave
    int which = (int)(b0 >> 23);
    size_t j = b0 & 8388607;
    src = (which == 0 ? wq : which == 1 ? wk : wv) + j;
    dst = wqkv_bf + (j >> 20) * 3145728 + (size_t)which * 1048576 + (j & 1048575);
  } else if (b0 < NQ3 + NF) {
    size_t r = b0 - NQ3;
    src = fc1w + r; dst = fc1_bf + r;
  } else if (b0 < NQ3 + 2 * NF) {
    size_t r = b0 - NQ3 - NF;
    src = fc2w + r; dst = fc2_bf + r;
  } else {
    size_t r = b0 - NQ3 - 2 * NF;
    src = row_ + r; dst = ro_bf + r;
  }
  int t4 = threadIdx.x * 4;
  f4v v[8];
#pragma unroll
  for (int k = 0; k < 8; ++k)
    v[k] = __builtin_nontemporal_load(reinterpret_cast<const f4v*>(src + t4 + k * 1024));
#pragma unroll
  for (int k = 0; k < 8; ++k) {
    ushort4 o = {f2bf(v[k].x), f2bf(v[k].y), f2bf(v[k].z), f2bf(v[k].w)};
    *reinterpret_cast<ushort4*>(dst + t4 + k * 1024) = o;
  }
}

// ---------- embedding + sinusoidal pos encoding, grid = 2048 rows ----------
__global__ __launch_bounds__(256) void embed_kernel(const int* __restrict__ ids,
                                                    const float* __restrict__ emb,
                                                    float* __restrict__ x) {
  int row = blockIdx.x;  // n*1024 + t
  int t = row & 1023;
  int id = ids[row];
  int d0 = threadIdx.x * 4;
  float4 e = *reinterpret_cast<const float4*>(emb + (size_t)id * 1024 + d0);
  float pe[4];
#pragma unroll
  for (int i = 0; i < 4; ++i) {
    int d = d0 + i;
    float dv = expf((float)(d & ~1) * (-9.210340371976184f / 1024.f));
    float ang = (float)t * dv;
    pe[i] = (d & 1) ? cosf(ang) : sinf(ang);
  }
  float4 o;
  o.x = e.x + pe[0]; o.y = e.y + pe[1]; o.z = e.z + pe[2]; o.w = e.w + pe[3];
  *reinterpret_cast<float4*>(x + (size_t)row * 1024 + d0) = o;
}

// ---------- LayerNorm (f32 in, bf16 out), grid = 2048 rows ----------
__global__ __launch_bounds__(256) void ln_kernel(const float* __restrict__ x,
                                                 const float* __restrict__ w,
                                                 const float* __restrict__ b,
                                                 ushort* __restrict__ out) {
  int row = blockIdx.x, tid = threadIdx.x;
  int lane = tid & 63, wid = tid >> 6;
  const float* xr = x + (size_t)row * 1024;
  float4 v = reinterpret_cast<const float4*>(xr)[tid];
  __shared__ float red[8];
  float s = v.x + v.y + v.z + v.w;
#pragma unroll
  for (int o = 32; o; o >>= 1) s += __shfl_xor(s, o);
  if (lane == 0) red[wid] = s;
  __syncthreads();
  float mean = (red[0] + red[1] + red[2] + red[3]) * (1.f / 1024.f);
  float d0 = v.x - mean, d1 = v.y - mean, d2 = v.z - mean, d3 = v.w - mean;
  float s2 = d0 * d0 + d1 * d1 + d2 * d2 + d3 * d3;
#pragma unroll
  for (int o = 32; o; o >>= 1) s2 += __shfl_xor(s2, o);
  if (lane == 0) red[4 + wid] = s2;
  __syncthreads();
  float var = (red[4] + red[5] + red[6] + red[7]) * (1.f / 1024.f);
  float rstd = rsqrtf(var + 1e-5f);
  float4 wv = reinterpret_cast<const float4*>(w)[tid];
  float4 bv = reinterpret_cast<const float4*>(b)[tid];
  ushort4 o;
  o.x = f2bf(d0 * rstd * wv.x + bv.x);
  o.y = f2bf(d1 * rstd * wv.y + bv.y);
  o.z = f2bf(d2 * rstd * wv.z + bv.z);
  o.w = f2bf(d3 * rstd * wv.w + bv.w);
  *reinterpret_cast<ushort4*>(out + (size_t)row * 1024 + tid * 4) = o;
}

// ---------- bf16 MFMA GEMM: C[M,N] = A[M,K] * Bw[N,K]^T ----------
// BMx128 tile, BK=64, 256 thr = 4 waves (2x2), wave = (BM/2)x64.
// XCD-bijective swizzle (needs gridDim.x*gridDim.y % 8 == 0).
enum { EPI_QKV = 0, EPI_GELU = 1, EPI_RES = 2, EPI_BIAS = 3 };

template <int EPI, int BM>
__global__ __launch_bounds__(256, 4) void gemm_kernel(const ushort* __restrict__ A,
                                                      const ushort* __restrict__ Bw,
                                                      const float* __restrict__ bias,
                                                      void* __restrict__ outp,
                                                      void* __restrict__ outp2,
                                                      int M, int N, int K, int kz) {
  constexpr int MI = BM / 32;            // 16-row frag groups per wave
  __shared__ char smem[BM * 128 + 16384];
  ushort* As = (ushort*)smem;            // [BM][64] bf16, chunk-swizzled
  ushort* Bs = (ushort*)(smem + BM * 128);  // [128][64]
  int tid = threadIdx.x;
  int lane = tid & 63;
  int wid = tid >> 6;
  int wr = wid >> 1, wc = wid & 1;       // 2x2 wave grid, wave = (BM/2)x64

  // XCD swizzle: consecutive tiles land on one XCD -> B panels fetched once/XCD
  int gx = gridDim.x;
  int nwg = gx * gridDim.y;
  int bid = blockIdx.x + blockIdx.y * gx;
  int swz = (bid & 7) * (nwg >> 3) + (bid >> 3);
  int bm = swz % gx, bn = swz / gx;

  int kbeg = 0, kend = K;
  if constexpr (EPI == EPI_RES) {        // split-K over gridDim.z
    kbeg = blockIdx.z * kz;
    kend = kbeg + kz;
  }

  const ushort* Ab = A + (size_t)(bm * BM) * K;
  const ushort* Bb = Bw + (size_t)(bn * 128) * K;

  auto stage = [&](int k0) {
#pragma unroll
    for (int i = 0; i < BM / 32; ++i) {  // BM*8 chunks of 16B
      int c = tid + i * 256;
      int row = c >> 3, j = c & 7;
      gload16(Ab + (size_t)row * K + k0 + ((j ^ (row & 7)) * 8), &As[c * 8]);
    }
#pragma unroll
    for (int i = 0; i < 4; ++i) {
      int c = tid + i * 256;
      int row = c >> 3, j = c & 7;
      gload16(Bb + (size_t)row * K + k0 + ((j ^ (row & 7)) * 8), &Bs[c * 8]);
    }
  };

  f4v acc[MI][4] = {};
  int lr = lane & 15, g = lane >> 4;
  int sx = lr & 7;  // swizzle key (row&7 of every frag row this lane reads)

  stage(kbeg);
  for (int k0 = kbeg; k0 < kend; k0 += 64) {
    __syncthreads();  // staging complete (compiler drains vmcnt at barrier)
    s8v af[MI], bf[4];
#pragma unroll
    for (int mi = 0; mi < MI; ++mi)
      af[mi] = *reinterpret_cast<const s8v*>(
          &As[(wr * (BM / 2) + mi * 16 + lr) * 64 + ((g ^ sx) * 8)]);
#pragma unroll
    for (int ni = 0; ni < 4; ++ni)
      bf[ni] = *reinterpret_cast<const s8v*>(
          &Bs[(wc * 64 + ni * 16 + lr) * 64 + ((g ^ sx) * 8)]);
#pragma unroll
    for (int mi = 0; mi < MI; ++mi)
#pragma unroll
      for (int ni = 0; ni < 4; ++ni)
        acc[mi][ni] = __builtin_amdgcn_mfma_f32_16x16x32_bf16(af[mi], bf[ni],
                                                              acc[mi][ni], 0, 0, 0);
    __builtin_amdgcn_sched_barrier(0);   // keep k-half-1 reads after MFMA batch
#pragma unroll
    for (int mi = 0; mi < MI; ++mi)
      af[mi] = *reinterpret_cast<const s8v*>(
          &As[(wr * (BM / 2) + mi * 16 + lr) * 64 + (((4 + g) ^ sx) * 8)]);
#pragma unroll
    for (int ni = 0; ni < 4; ++ni)
      bf[ni] = *reinterpret_cast<const s8v*>(
          &Bs[(wc * 64 + ni * 16 + lr) * 64 + (((4 + g) ^ sx) * 8)]);
    __syncthreads();               // all frag reads done -> LDS reusable
    if (k0 + 64 < kend) stage(k0 + 64);  // next-tile loads fly under MFMA
#pragma unroll
    for (int mi = 0; mi < MI; ++mi)
#pragma unroll
      for (int ni = 0; ni < 4; ++ni)
        acc[mi][ni] = __builtin_amdgcn_mfma_f32_16x16x32_bf16(af[mi], bf[ni],
                                                              acc[mi][ni], 0, 0, 0);
  }

  // ---- epilogue: per-wave LDS transpose (aliases As/Bs) -> coalesced stores ----
  __syncthreads();  // all frag reads done before aliasing
  float* sw = (float*)smem + wid * (16 * 36);
  int s = lane >> 3, q = lane & 7;
  for (int mi = 0; mi < MI; ++mi) {
    for (int np = 0; np < 2; ++np) {   // 2 column halves of the wave's 64 cols
#pragma unroll
      for (int ni2 = 0; ni2 < 2; ++ni2)
#pragma unroll
        for (int r = 0; r < 4; ++r)
          sw[(g * 4 + r) * 36 + ni2 * 16 + lr] = acc[mi][np * 2 + ni2][r];
      // wave-private scratch round-trip; compiler inserts lgkm waits
      int gnb = bn * 128 + wc * 64 + np * 32;      // wave-uniform col base
      if constexpr (EPI == EPI_QKV) {
        int z = gnb >> 10;                          // 0=q 1=k 2=v (uniform)
        int row0 = bm * BM + wr * (BM / 2) + mi * 16;  // t base (16 rows)
        int nb = row0 >> 10, tp0 = row0 & 1023;
        int hh = (gnb >> 6) & 15, dd0 = gnb & 63;
        if (z < 2) {                                // q/k: row-major [nh][t][64]
          ushort* o = (ushort*)outp;
#pragma unroll
          for (int h = 0; h < 2; ++h) {
            float4 v4 = *reinterpret_cast<const float4*>(&sw[(h * 8 + s) * 36 + q * 4]);
            int tpos = tp0 + h * 8 + s;
            ushort4 o4 = {f2bf(v4.x), f2bf(v4.y), f2bf(v4.z), f2bf(v4.w)};
            *reinterpret_cast<ushort4*>(o + (size_t)z * 2097152 + (size_t)nb * 1048576 +
                                        (size_t)hh * 65536 + (size_t)tpos * 64 +
                                        dd0 + q * 4) = o4;
          }
        } else {                                    // v: transposed [nh][dv][1024]
          ushort* ov = (ushort*)outp2;
          int dvq = lane & 31, hf = lane >> 5;
          us8 w;
#pragma unroll
          for (int j = 0; j < 8; ++j)
            w[j] = f2bf(sw[(hf * 8 + j) * 36 + dvq]);
          *reinterpret_cast<us8*>(ov + (size_t)nb * 1048576 + (size_t)hh * 65536 +
                                  (size_t)(dd0 + dvq) * 1024 + tp0 + hf * 8) = w;
        }
      } else {
#pragma unroll
        for (int h = 0; h < 2; ++h) {
          float4 v4 = *reinterpret_cast<const float4*>(&sw[(h * 8 + s) * 36 + q * 4]);
          int gm = bm * BM + wr * (BM / 2) + mi * 16 + h * 8 + s;
          int gn = gnb + q * 4;
          if constexpr (EPI == EPI_GELU) {
            const float4 bb = *reinterpret_cast<const float4*>(bias + gn);
            float u[4] = {v4.x + bb.x, v4.y + bb.y, v4.z + bb.z, v4.w + bb.w};
            ushort4 o4;
            ushort* po = (ushort*)&o4;
#pragma unroll
            for (int j = 0; j < 4; ++j) {
              float zz = u[j] * (1.5957691216f + 0.0713548162f * u[j] * u[j]);
              float gl = u[j] / (1.f + exp2f(zz * -1.4426950409f));
              po[j] = f2bf(gl);
            }
            *reinterpret_cast<ushort4*>((ushort*)outp + (size_t)gm * N + gn) = o4;
          } else if constexpr (EPI == EPI_RES) {
            float* o = (float*)outp + (size_t)gm * N + gn;
            float4 bb = *reinterpret_cast<const float4*>(bias + gn);
            bool addb = (blockIdx.z == 0);
            atomicAdd(o + 0, v4.x + (addb ? bb.x : 0.f));
            atomicAdd(o + 1, v4.y + (addb ? bb.y : 0.f));
            atomicAdd(o + 2, v4.z + (addb ? bb.z : 0.f));
            atomicAdd(o + 3, v4.w + (addb ? bb.w : 0.f));
          } else {  // EPI_BIAS (readout): non-temporal
            const float4 bb = *reinterpret_cast<const float4*>(bias + gn);
            f4v o4 = {v4.x + bb.x, v4.y + bb.y, v4.z + bb.z, v4.w + bb.w};
            __builtin_nontemporal_store(o4, (f4v*)((float*)outp + (size_t)gm * N + gn));
          }
        }
      }
    }
  }
}

// ---------- MFMA flash attention ----------
// grid 512: bid = half*256 + bx*32 + nh_r; qt = half ? 15-bx : bx.
// Co-resident blocks (c, c+256) share nh and have complementary qt -> each CU
// carries a constant 15+2 tile-steps with 8 waves resident (2 blocks/CU).
__global__ __launch_bounds__(256) void attn_kernel(const ushort* __restrict__ qg,
                                                   const ushort* __restrict__ kg,
                                                   const ushort* __restrict__ vtg,
                                                   float* __restrict__ x) {
  __shared__ ushort Ks[2][4096];  // [64 s][64 d] bf16, swizzled
  __shared__ ushort Vs[2][4096];  // [64 dv][64 s] bf16, swizzled
  __shared__ ushort Ps[4][1024];  // per-wave P [16 q][64 s] bf16, swizzled
  int bid = blockIdx.x;
  int half = bid >> 8, r = bid & 255;
  int bx = r >> 5, nh = r & 31;
  int qt = half ? (15 - bx) : bx;
  int tid = threadIdx.x, lane = tid & 63, wid = tid >> 6;
  int lr = lane & 15, g = lane >> 4;
  size_t base = (size_t)nh * 65536;
  const ushort* kb = kg + base;
  const ushort* vb = vtg + base;
  const float SCALE = 0.125f * 1.44269504088896f;

  auto stage = [&](int st, int buf) {
    int s0 = st * 64;
#pragma unroll
    for (int j = 0; j < 2; ++j) {
      int c = tid + j * 256;
      int row = c >> 3;
      int col = ((c & 7) ^ (row & 7)) * 8;  // inverse-swizzled source column
      gload16(kb + (size_t)(s0 + row) * 64 + col, &Ks[buf][c * 8]);
      gload16(vb + (size_t)row * 1024 + s0 + col, &Vs[buf][c * 8]);
    }
  };

  int qrow = qt * 64 + wid * 16 + lr;
  s8v qf[2];
  qf[0] = *reinterpret_cast<const s8v*>(qg + base + (size_t)qrow * 64 + g * 8);
  qf[1] = *reinterpret_cast<const s8v*>(qg + base + (size_t)qrow * 64 + 32 + g * 8);

  float m_run = NEG_INF, l_run = 0.f;
  f4v accy[4] = {};
  stage(0, 0);
  int cur = 0;
  for (int st = 0; st <= qt; ++st) {
    __syncthreads();
    if (st < qt) stage(st + 1, cur ^ 1);

    f4v accs[4] = {};
    __builtin_amdgcn_s_setprio(1);
#pragma unroll
    for (int kc = 0; kc < 2; ++kc)
#pragma unroll
      for (int mi = 0; mi < 4; ++mi) {
        int bo = ((mi * 16 + lr) * 128 + kc * 64 + g * 16) ^ ((lr & 7) << 4);
        s8v kf = *reinterpret_cast<const s8v*>(&Ks[cur][bo >> 1]);
        accs[mi] = __builtin_amdgcn_mfma_f32_16x16x32_bf16(kf, qf[kc], accs[mi], 0, 0, 0);
      }
    __builtin_amdgcn_s_setprio(0);

    float z[16];
    float tmax = NEG_INF;
    bool diag = (st == qt);
    int qcol = qt * 64 + wid * 16 + lr;
#pragma unroll
    for (int mi = 0; mi < 4; ++mi)
#pragma unroll
      for (int r2 = 0; r2 < 4; ++r2) {
        float zz = accs[mi][r2] * SCALE;
        if (diag && st * 64 + mi * 16 + g * 4 + r2 > qcol) zz = NEG_INF;
        z[mi * 4 + r2] = zz;
        tmax = fmaxf(tmax, zz);
      }
    tmax = fmaxf(tmax, __shfl_xor(tmax, 16));
    tmax = fmaxf(tmax, __shfl_xor(tmax, 32));
    float m_new = fmaxf(m_run, tmax);
    float corr = exp2f(m_run - m_new);
    float psum = 0.f;
    ushort pb[16];
#pragma unroll
    for (int i = 0; i < 16; ++i) {
      float pv = exp2f(z[i] - m_new);
      psum += pv;
      pb[i] = f2bf(pv);
    }
    psum += __shfl_xor(psum, 16);
    psum += __shfl_xor(psum, 32);
    l_run = l_run * corr + psum;
    m_run = m_new;

    {
      ushort* pw = Ps[wid];
#pragma unroll
      for (int mi = 0; mi < 4; ++mi) {
        int bo = (lr * 128 + mi * 32 + g * 8) ^ ((lr & 7) << 4);
        ushort4 w4 = {pb[mi * 4], pb[mi * 4 + 1], pb[mi * 4 + 2], pb[mi * 4 + 3]};
        *reinterpret_cast<ushort4*>(&pw[bo >> 1]) = w4;
      }
    }

    float cq[4];
#pragma unroll
    for (int r2 = 0; r2 < 4; ++r2) cq[r2] = __shfl(corr, (lane >> 4) * 4 + r2);
#pragma unroll
    for (int ni = 0; ni < 4; ++ni)
#pragma unroll
      for (int r2 = 0; r2 < 4; ++r2) accy[ni][r2] *= cq[r2];

    __builtin_amdgcn_s_setprio(1);
#pragma unroll
    for (int ks = 0; ks < 2; ++ks) {
      int po = (lr * 128 + ks * 64 + g * 16) ^ ((lr & 7) << 4);
      s8v pa = *reinterpret_cast<const s8v*>(&Ps[wid][po >> 1]);
#pragma unroll
      for (int ni = 0; ni < 4; ++ni) {
        int vo = ((ni * 16 + lr) * 128 + ks * 64 + g * 16) ^ ((lr & 7) << 4);
        s8v vf = *reinterpret_cast<const s8v*>(&Vs[cur][vo >> 1]);
        accy[ni] = __builtin_amdgcn_mfma_f32_16x16x32_bf16(pa, vf, accy[ni], 0, 0, 0);
      }
    }
    __builtin_amdgcn_s_setprio(0);
    cur ^= 1;
  }

  float lq[4];
#pragma unroll
  for (int r2 = 0; r2 < 4; ++r2) lq[r2] = 1.f / __shfl(l_run, (lane >> 4) * 4 + r2);
  int n = nh >> 4, hh = nh & 15;
  float* xb = x + ((size_t)(n * 1024 + qt * 64 + wid * 16)) * 1024 + hh * 64;
#pragma unroll
  for (int r2 = 0; r2 < 4; ++r2) {
    float* xr = xb + (size_t)(g * 4 + r2) * 1024;
#pragma unroll
    for (int ni = 0; ni < 4; ++ni)
      xr[ni * 16 + lr] += accy[ni][r2] * lq[r2];
  }
}

// ---------------------------------------------------------------------------
extern "C" void kernel_launch(void* const* d_in, const int* in_sizes, int n_in,
                              void* d_out, int out_size, void* d_ws, size_t ws_size,
                              hipStream_t stream) {
  const int*   ids  = (const int*)  d_in[0];
  const float* emb  = (const float*)d_in[1];
  const float* ln1w = (const float*)d_in[2];
  const float* ln1b = (const float*)d_in[3];
  const float* wq   = (const float*)d_in[4];
  const float* wk   = (const float*)d_in[5];
  const float* wv   = (const float*)d_in[6];
  const float* ln2w = (const float*)d_in[7];
  const float* ln2b = (const float*)d_in[8];
  const float* fc1w = (const float*)d_in[9];
  const float* fc1b = (const float*)d_in[10];
  const float* fc2w = (const float*)d_in[11];
  const float* fc2b = (const float*)d_in[12];
  const float* row_ = (const float*)d_in[13];
  const float* rob  = (const float*)d_in[14];
  (void)in_sizes; (void)n_in; (void)out_size;

  char* p = (char*)d_ws;
  auto carve = [&](size_t bytes) {
    char* r = p;
    p += (bytes + 255) & ~(size_t)255;
    return (void*)r;
  };
  ushort* ro_bf = (ushort*)carve(32000ull * 1024 * 2);
  float*  x     = (float*) carve(2048ull * 1024 * 4);
  ushort* h     = (ushort*)carve(2048ull * 1024 * 2);
  ushort* qkvb  = (ushort*)carve(3ull * 2097152 * 2);   // bf16 q/k [z][nh][t][64]
  ushort* vtb   = (ushort*)carve(2097152ull * 2);       // bf16 vT [nh][64][1024]
  ushort* mbuf  = (ushort*)carve(2048ull * 4096 * 2);
  ushort* xb    = (ushort*)carve(2048ull * 1024 * 2);
  size_t used_common = (size_t)(p - (char*)d_ws);

  const size_t SZ_WQKV_ALL = 3ull * 8388608 * 2;   // merged [L][3][1M]
  const size_t SZ_FC_ALL   = 33554432ull * 2;
  const size_t SZ_WQKV_1   = 3ull * 1048576 * 2;
  const size_t SZ_FC_1     = 4194304ull * 2;
  bool upfront = ws_size >= used_common + SZ_WQKV_ALL + 2 * SZ_FC_ALL + 4096;

  ushort *wqkv_bf, *fc1_bf, *fc2_bf;
  size_t lq3, lf;
  if (upfront) {
    wqkv_bf = (ushort*)carve(SZ_WQKV_ALL);
    fc1_bf  = (ushort*)carve(SZ_FC_ALL);
    fc2_bf  = (ushort*)carve(SZ_FC_ALL);
    lq3 = 3145728; lf = 4194304;
    cvtall_kernel<<<15264, 256, 0, stream>>>(wq, wk, wv, fc1w, fc2w, row_,
                                             wqkv_bf, fc1_bf, fc2_bf, ro_bf);
  } else {
    wqkv_bf = (ushort*)carve(SZ_WQKV_1);
    fc1_bf  = (ushort*)carve(SZ_FC_1);
    fc2_bf  = (ushort*)carve(SZ_FC_1);
    lq3 = 0; lf = 0;
    cvt_kernel<<<32000, 256, 0, stream>>>(row_, ro_bf, 32768000);
  }

  embed_kernel<<<2048, 256, 0, stream>>>(ids, emb, x);

  for (int l = 0; l < 8; ++l) {
    if (!upfront) {
      cvt_kernel<<<1024, 256, 0, stream>>>(wq + (size_t)l * 1048576, wqkv_bf, 1048576);
      cvt_kernel<<<1024, 256, 0, stream>>>(wk + (size_t)l * 1048576, wqkv_bf + 1048576, 1048576);
      cvt_kernel<<<1024, 256, 0, stream>>>(wv + (size_t)l * 1048576, wqkv_bf + 2097152, 1048576);
      cvt_kernel<<<4096, 256, 0, stream>>>(fc1w + (size_t)l * 4194304, fc1_bf, 4194304);
      cvt_kernel<<<4096, 256, 0, stream>>>(fc2w + (size_t)l * 4194304, fc2_bf, 4194304);
    }
    const ushort* wqkv_l = wqkv_bf + (size_t)l * lq3;
    const ushort* fc1_l  = fc1_bf + (size_t)l * lf;
    const ushort* fc2_l  = fc2_bf + (size_t)l * lf;

    ln_kernel<<<2048, 256, 0, stream>>>(x, ln1w + l * 1024, ln1b + l * 1024, h);
    gemm_kernel<EPI_QKV, 64><<<dim3(32, 24), 256, 0, stream>>>(
        h, wqkv_l, nullptr, qkvb, vtb, 2048, 3072, 1024, 0);
    attn_kernel<<<512, 256, 0, stream>>>(qkvb, qkvb + 2097152, vtb, x);
    ln_kernel<<<2048, 256, 0, stream>>>(x, ln2w + l * 1024, ln2b + l * 1024, h);
    gemm_kernel<EPI_GELU, 64><<<dim3(32, 32), 256, 0, stream>>>(
        h, fc1_l, fc1b + (size_t)l * 4096, mbuf, nullptr, 2048, 4096, 1024, 0);
    gemm_kernel<EPI_RES, 64><<<dim3(32, 8, 4), 256, 0, stream>>>(
        mbuf, fc2_l, fc2b + (size_t)l * 1024, x, nullptr, 2048, 1024, 4096, 1024);
  }
  cvt_kernel<<<2048, 256, 0, stream>>>(x, xb, 2097152);
  gemm_kernel<EPI_BIAS, 128><<<dim3(16, 250), 256, 0, stream>>>(
      xb, ro_bf, rob, d_out, nullptr, 2048, 32000, 1024, 0);
}

// Round 15
// 1970.269 us; speedup vs baseline: 1.0262x; 1.0016x over previous
//
#include <hip/hip_runtime.h>
#include <cstdint>

// PicoGPT forward: V=32000 D=1024 DK=DV=64 H=16 DH=4096 L=8, input [2,1024]
// bf16 MFMA GEMMs: BK=64, XOR-swizzled LDS, global_load_lds both operands
// (m97+T2), XCD swizzle (T1). R15: BM=64 layer GEMMs at (256,5) — 96 total
// regs (64 arch + 32 acc) fits the 102/block budget; readout BM=128 stays
// (256,4) (64+64=128 exact fit). Attn 2/CU + setprio; cvtall nt loads.

#define DEVI __device__ __forceinline__
#define NEG_INF (-__builtin_inff())

typedef __attribute__((ext_vector_type(8))) short s8v;            // 8 x bf16
typedef __attribute__((ext_vector_type(8))) unsigned short us8;   // 8 x bf16 store
typedef __attribute__((ext_vector_type(4))) float f4v;

DEVI ushort f2bf(float f) {  // RTNE f32 -> bf16
  uint32_t x = __float_as_uint(f);
  x += 0x7fffu + ((x >> 16) & 1u);
  return (ushort)(x >> 16);
}

DEVI void gload16(const void* g, void* l) {  // async global->LDS, 16B/lane
  __builtin_amdgcn_global_load_lds((const __attribute__((address_space(1))) void*)g,
                                   (__attribute__((address_space(3))) void*)l, 16, 0, 0);
}

// ---------- f32 -> bf16 convert (generic) ----------
__global__ __launch_bounds__(256) void cvt_kernel(const float* __restrict__ in,
                                                  ushort* __restrict__ out, int n) {
  int i = (blockIdx.x * 256 + threadIdx.x) * 4;
  if (i >= n) return;
  float4 v = *reinterpret_cast<const float4*>(in + i);
  ushort4 o;
  o.x = f2bf(v.x); o.y = f2bf(v.y); o.z = f2bf(v.z); o.w = f2bf(v.w);
  *reinterpret_cast<ushort4*>(out + i) = o;
}

// ---------- all weights f32 -> bf16, 8-way ILP, nt loads ----------
// grid = 125042688/8192 = 15264 blocks; every segment boundary divides 8192.
__global__ __launch_bounds__(256) void cvtall_kernel(const float* __restrict__ wq,
                                                     const float* __restrict__ wk,
                                                     const float* __restrict__ wv,
                                                     const float* __restrict__ fc1w,
                                                     const float* __restrict__ fc2w,
                                                     const float* __restrict__ row_,
                                                     ushort* __restrict__ wqkv_bf,
                                                     ushort* __restrict__ fc1_bf,
                                                     ushort* __restrict__ fc2_bf,
                                                     ushort* __restrict__ ro_bf) {
  const size_t NQ3 = 25165824, NF = 33554432;   // 3*8M, 32M
  size_t b0 = (size_t)blockIdx.x * 8192;
  const float* src;
  ushort* dst;
  if (b0 < NQ3) {                                // qkv -> [L][3][1M] interleave
    int which = (int)(b0 >> 23);
    size_t j = b0 & 8388607;
    src = (which == 0 ? wq : which == 1 ? wk : wv) + j;
    dst = wqkv_bf + (j >> 20) * 3145728 + (size_t)which * 1048576 + (j & 1048575);
  } else if (b0 < NQ3 + NF) {
    size_t r = b0 - NQ3;
    src = fc1w + r; dst = fc1_bf + r;
  } else if (b0 < NQ3 + 2 * NF) {
    size_t r = b0 - NQ3 - NF;
    src = fc2w + r; dst = fc2_bf + r;
  } else {
    size_t r = b0 - NQ3 - 2 * NF;
    src = row_ + r; dst = ro_bf + r;
  }
  int t4 = threadIdx.x * 4;
  f4v v[8];
#pragma unroll
  for (int k = 0; k < 8; ++k)
    v[k] = __builtin_nontemporal_load(reinterpret_cast<const f4v*>(src + t4 + k * 1024));
#pragma unroll
  for (int k = 0; k < 8; ++k) {
    ushort4 o = {f2bf(v[k].x), f2bf(v[k].y), f2bf(v[k].z), f2bf(v[k].w)};
    *reinterpret_cast<ushort4*>(dst + t4 + k * 1024) = o;
  }
}

// ---------- embedding + sinusoidal pos encoding, grid = 2048 rows ----------
__global__ __launch_bounds__(256) void embed_kernel(const int* __restrict__ ids,
                                                    const float* __restrict__ emb,
                                                    float* __restrict__ x) {
  int row = blockIdx.x;  // n*1024 + t
  int t = row & 1023;
  int id = ids[row];
  int d0 = threadIdx.x * 4;
  float4 e = *reinterpret_cast<const float4*>(emb + (size_t)id * 1024 + d0);
  float pe[4];
#pragma unroll
  for (int i = 0; i < 4; ++i) {
    int d = d0 + i;
    float dv = expf((float)(d & ~1) * (-9.210340371976184f / 1024.f));
    float ang = (float)t * dv;
    pe[i] = (d & 1) ? cosf(ang) : sinf(ang);
  }
  float4 o;
  o.x = e.x + pe[0]; o.y = e.y + pe[1]; o.z = e.z + pe[2]; o.w = e.w + pe[3];
  *reinterpret_cast<float4*>(x + (size_t)row * 1024 + d0) = o;
}

// ---------- LayerNorm (f32 in, bf16 out), grid = 2048 rows ----------
__global__ __launch_bounds__(256) void ln_kernel(const float* __restrict__ x,
                                                 const float* __restrict__ w,
                                                 const float* __restrict__ b,
                                                 ushort* __restrict__ out) {
  int row = blockIdx.x, tid = threadIdx.x;
  int lane = tid & 63, wid = tid >> 6;
  const float* xr = x + (size_t)row * 1024;
  float4 v = reinterpret_cast<const float4*>(xr)[tid];
  __shared__ float red[8];
  float s = v.x + v.y + v.z + v.w;
#pragma unroll
  for (int o = 32; o; o >>= 1) s += __shfl_xor(s, o);
  if (lane == 0) red[wid] = s;
  __syncthreads();
  float mean = (red[0] + red[1] + red[2] + red[3]) * (1.f / 1024.f);
  float d0 = v.x - mean, d1 = v.y - mean, d2 = v.z - mean, d3 = v.w - mean;
  float s2 = d0 * d0 + d1 * d1 + d2 * d2 + d3 * d3;
#pragma unroll
  for (int o = 32; o; o >>= 1) s2 += __shfl_xor(s2, o);
  if (lane == 0) red[4 + wid] = s2;
  __syncthreads();
  float var = (red[4] + red[5] + red[6] + red[7]) * (1.f / 1024.f);
  float rstd = rsqrtf(var + 1e-5f);
  float4 wv = reinterpret_cast<const float4*>(w)[tid];
  float4 bv = reinterpret_cast<const float4*>(b)[tid];
  ushort4 o;
  o.x = f2bf(d0 * rstd * wv.x + bv.x);
  o.y = f2bf(d1 * rstd * wv.y + bv.y);
  o.z = f2bf(d2 * rstd * wv.z + bv.z);
  o.w = f2bf(d3 * rstd * wv.w + bv.w);
  *reinterpret_cast<ushort4*>(out + (size_t)row * 1024 + tid * 4) = o;
}

// ---------- bf16 MFMA GEMM: C[M,N] = A[M,K] * Bw[N,K]^T ----------
// BMx128 tile, BK=64, 256 thr = 4 waves (2x2), wave = (BM/2)x64.
// XCD-bijective swizzle (needs gridDim.x*gridDim.y % 8 == 0).
enum { EPI_QKV = 0, EPI_GELU = 1, EPI_RES = 2, EPI_BIAS = 3 };

template <int EPI, int BM>
__global__ __launch_bounds__(256, BM == 64 ? 5 : 4)
void gemm_kernel(const ushort* __restrict__ A,
                 const ushort* __restrict__ Bw,
                 const float* __restrict__ bias,
                 void* __restrict__ outp,
                 void* __restrict__ outp2,
                 int M, int N, int K, int kz) {
  constexpr int MI = BM / 32;            // 16-row frag groups per wave
  __shared__ char smem[BM * 128 + 16384];
  ushort* As = (ushort*)smem;            // [BM][64] bf16, chunk-swizzled
  ushort* Bs = (ushort*)(smem + BM * 128);  // [128][64]
  int tid = threadIdx.x;
  int lane = tid & 63;
  int wid = tid >> 6;
  int wr = wid >> 1, wc = wid & 1;       // 2x2 wave grid, wave = (BM/2)x64

  // XCD swizzle: consecutive tiles land on one XCD -> B panels fetched once/XCD
  int gx = gridDim.x;
  int nwg = gx * gridDim.y;
  int bid = blockIdx.x + blockIdx.y * gx;
  int swz = (bid & 7) * (nwg >> 3) + (bid >> 3);
  int bm = swz % gx, bn = swz / gx;

  int kbeg = 0, kend = K;
  if constexpr (EPI == EPI_RES) {        // split-K over gridDim.z
    kbeg = blockIdx.z * kz;
    kend = kbeg + kz;
  }

  const ushort* Ab = A + (size_t)(bm * BM) * K;
  const ushort* Bb = Bw + (size_t)(bn * 128) * K;

  auto stage = [&](int k0) {
#pragma unroll
    for (int i = 0; i < BM / 32; ++i) {  // BM*8 chunks of 16B
      int c = tid + i * 256;
      int row = c >> 3, j = c & 7;
      gload16(Ab + (size_t)row * K + k0 + ((j ^ (row & 7)) * 8), &As[c * 8]);
    }
#pragma unroll
    for (int i = 0; i < 4; ++i) {
      int c = tid + i * 256;
      int row = c >> 3, j = c & 7;
      gload16(Bb + (size_t)row * K + k0 + ((j ^ (row & 7)) * 8), &Bs[c * 8]);
    }
  };

  f4v acc[MI][4] = {};
  int lr = lane & 15, g = lane >> 4;
  int sx = lr & 7;  // swizzle key (row&7 of every frag row this lane reads)

  stage(kbeg);
  for (int k0 = kbeg; k0 < kend; k0 += 64) {
    __syncthreads();  // staging complete (compiler drains vmcnt at barrier)
    s8v af[MI], bf[4];
#pragma unroll
    for (int mi = 0; mi < MI; ++mi)
      af[mi] = *reinterpret_cast<const s8v*>(
          &As[(wr * (BM / 2) + mi * 16 + lr) * 64 + ((g ^ sx) * 8)]);
#pragma unroll
    for (int ni = 0; ni < 4; ++ni)
      bf[ni] = *reinterpret_cast<const s8v*>(
          &Bs[(wc * 64 + ni * 16 + lr) * 64 + ((g ^ sx) * 8)]);
#pragma unroll
    for (int mi = 0; mi < MI; ++mi)
#pragma unroll
      for (int ni = 0; ni < 4; ++ni)
        acc[mi][ni] = __builtin_amdgcn_mfma_f32_16x16x32_bf16(af[mi], bf[ni],
                                                              acc[mi][ni], 0, 0, 0);
    __builtin_amdgcn_sched_barrier(0);   // keep k-half-1 reads after MFMA batch
#pragma unroll
    for (int mi = 0; mi < MI; ++mi)
      af[mi] = *reinterpret_cast<const s8v*>(
          &As[(wr * (BM / 2) + mi * 16 + lr) * 64 + (((4 + g) ^ sx) * 8)]);
#pragma unroll
    for (int ni = 0; ni < 4; ++ni)
      bf[ni] = *reinterpret_cast<const s8v*>(
          &Bs[(wc * 64 + ni * 16 + lr) * 64 + (((4 + g) ^ sx) * 8)]);
    __syncthreads();               // all frag reads done -> LDS reusable
    if (k0 + 64 < kend) stage(k0 + 64);  // next-tile loads fly under MFMA
#pragma unroll
    for (int mi = 0; mi < MI; ++mi)
#pragma unroll
      for (int ni = 0; ni < 4; ++ni)
        acc[mi][ni] = __builtin_amdgcn_mfma_f32_16x16x32_bf16(af[mi], bf[ni],
                                                              acc[mi][ni], 0, 0, 0);
  }

  // ---- epilogue: per-wave LDS transpose (aliases As/Bs) -> coalesced stores ----
  __syncthreads();  // all frag reads done before aliasing
  float* sw = (float*)smem + wid * (16 * 36);
  int s = lane >> 3, q = lane & 7;
  for (int mi = 0; mi < MI; ++mi) {
    for (int np = 0; np < 2; ++np) {   // 2 column halves of the wave's 64 cols
#pragma unroll
      for (int ni2 = 0; ni2 < 2; ++ni2)
#pragma unroll
        for (int r = 0; r < 4; ++r)
          sw[(g * 4 + r) * 36 + ni2 * 16 + lr] = acc[mi][np * 2 + ni2][r];
      // wave-private scratch round-trip; compiler inserts lgkm waits
      int gnb = bn * 128 + wc * 64 + np * 32;      // wave-uniform col base
      if constexpr (EPI == EPI_QKV) {
        int z = gnb >> 10;                          // 0=q 1=k 2=v (uniform)
        int row0 = bm * BM + wr * (BM / 2) + mi * 16;  // t base (16 rows)
        int nb = row0 >> 10, tp0 = row0 & 1023;
        int hh = (gnb >> 6) & 15, dd0 = gnb & 63;
        if (z < 2) {                                // q/k: row-major [nh][t][64]
          ushort* o = (ushort*)outp;
#pragma unroll
          for (int h = 0; h < 2; ++h) {
            float4 v4 = *reinterpret_cast<const float4*>(&sw[(h * 8 + s) * 36 + q * 4]);
            int tpos = tp0 + h * 8 + s;
            ushort4 o4 = {f2bf(v4.x), f2bf(v4.y), f2bf(v4.z), f2bf(v4.w)};
            *reinterpret_cast<ushort4*>(o + (size_t)z * 2097152 + (size_t)nb * 1048576 +
                                        (size_t)hh * 65536 + (size_t)tpos * 64 +
                                        dd0 + q * 4) = o4;
          }
        } else {                                    // v: transposed [nh][dv][1024]
          ushort* ov = (ushort*)outp2;
          int dvq = lane & 31, hf = lane >> 5;
          us8 w;
#pragma unroll
          for (int j = 0; j < 8; ++j)
            w[j] = f2bf(sw[(hf * 8 + j) * 36 + dvq]);
          *reinterpret_cast<us8*>(ov + (size_t)nb * 1048576 + (size_t)hh * 65536 +
                                  (size_t)(dd0 + dvq) * 1024 + tp0 + hf * 8) = w;
        }
      } else {
#pragma unroll
        for (int h = 0; h < 2; ++h) {
          float4 v4 = *reinterpret_cast<const float4*>(&sw[(h * 8 + s) * 36 + q * 4]);
          int gm = bm * BM + wr * (BM / 2) + mi * 16 + h * 8 + s;
          int gn = gnb + q * 4;
          if constexpr (EPI == EPI_GELU) {
            const float4 bb = *reinterpret_cast<const float4*>(bias + gn);
            float u[4] = {v4.x + bb.x, v4.y + bb.y, v4.z + bb.z, v4.w + bb.w};
            ushort4 o4;
            ushort* po = (ushort*)&o4;
#pragma unroll
            for (int j = 0; j < 4; ++j) {
              float zz = u[j] * (1.5957691216f + 0.0713548162f * u[j] * u[j]);
              float gl = u[j] / (1.f + exp2f(zz * -1.4426950409f));
              po[j] = f2bf(gl);
            }
            *reinterpret_cast<ushort4*>((ushort*)outp + (size_t)gm * N + gn) = o4;
          } else if constexpr (EPI == EPI_RES) {
            float* o = (float*)outp + (size_t)gm * N + gn;
            float4 bb = *reinterpret_cast<const float4*>(bias + gn);
            bool addb = (blockIdx.z == 0);
            atomicAdd(o + 0, v4.x + (addb ? bb.x : 0.f));
            atomicAdd(o + 1, v4.y + (addb ? bb.y : 0.f));
            atomicAdd(o + 2, v4.z + (addb ? bb.z : 0.f));
            atomicAdd(o + 3, v4.w + (addb ? bb.w : 0.f));
          } else {  // EPI_BIAS (readout): non-temporal
            const float4 bb = *reinterpret_cast<const float4*>(bias + gn);
            f4v o4 = {v4.x + bb.x, v4.y + bb.y, v4.z + bb.z, v4.w + bb.w};
            __builtin_nontemporal_store(o4, (f4v*)((float*)outp + (size_t)gm * N + gn));
          }
        }
      }
    }
  }
}

// ---------- MFMA flash attention ----------
// grid 512: bid = half*256 + bx*32 + nh_r; qt = half ? 15-bx : bx.
// Co-resident blocks (c, c+256) share nh and have complementary qt -> each CU
// carries a constant 15+2 tile-steps with 8 waves resident (2 blocks/CU).
__global__ __launch_bounds__(256) void attn_kernel(const ushort* __restrict__ qg,
                                                   const ushort* __restrict__ kg,
                                                   const ushort* __restrict__ vtg,
                                                   float* __restrict__ x) {
  __shared__ ushort Ks[2][4096];  // [64 s][64 d] bf16, swizzled
  __shared__ ushort Vs[2][4096];  // [64 dv][64 s] bf16, swizzled
  __shared__ ushort Ps[4][1024];  // per-wave P [16 q][64 s] bf16, swizzled
  int bid = blockIdx.x;
  int half = bid >> 8, r = bid & 255;
  int bx = r >> 5, nh = r & 31;
  int qt = half ? (15 - bx) : bx;
  int tid = threadIdx.x, lane = tid & 63, wid = tid >> 6;
  int lr = lane & 15, g = lane >> 4;
  size_t base = (size_t)nh * 65536;
  const ushort* kb = kg + base;
  const ushort* vb = vtg + base;
  const float SCALE = 0.125f * 1.44269504088896f;

  auto stage = [&](int st, int buf) {
    int s0 = st * 64;
#pragma unroll
    for (int j = 0; j < 2; ++j) {
      int c = tid + j * 256;
      int row = c >> 3;
      int col = ((c & 7) ^ (row & 7)) * 8;  // inverse-swizzled source column
      gload16(kb + (size_t)(s0 + row) * 64 + col, &Ks[buf][c * 8]);
      gload16(vb + (size_t)row * 1024 + s0 + col, &Vs[buf][c * 8]);
    }
  };

  int qrow = qt * 64 + wid * 16 + lr;
  s8v qf[2];
  qf[0] = *reinterpret_cast<const s8v*>(qg + base + (size_t)qrow * 64 + g * 8);
  qf[1] = *reinterpret_cast<const s8v*>(qg + base + (size_t)qrow * 64 + 32 + g * 8);

  float m_run = NEG_INF, l_run = 0.f;
  f4v accy[4] = {};
  stage(0, 0);
  int cur = 0;
  for (int st = 0; st <= qt; ++st) {
    __syncthreads();
    if (st < qt) stage(st + 1, cur ^ 1);

    f4v accs[4] = {};
    __builtin_amdgcn_s_setprio(1);
#pragma unroll
    for (int kc = 0; kc < 2; ++kc)
#pragma unroll
      for (int mi = 0; mi < 4; ++mi) {
        int bo = ((mi * 16 + lr) * 128 + kc * 64 + g * 16) ^ ((lr & 7) << 4);
        s8v kf = *reinterpret_cast<const s8v*>(&Ks[cur][bo >> 1]);
        accs[mi] = __builtin_amdgcn_mfma_f32_16x16x32_bf16(kf, qf[kc], accs[mi], 0, 0, 0);
      }
    __builtin_amdgcn_s_setprio(0);

    float z[16];
    float tmax = NEG_INF;
    bool diag = (st == qt);
    int qcol = qt * 64 + wid * 16 + lr;
#pragma unroll
    for (int mi = 0; mi < 4; ++mi)
#pragma unroll
      for (int r2 = 0; r2 < 4; ++r2) {
        float zz = accs[mi][r2] * SCALE;
        if (diag && st * 64 + mi * 16 + g * 4 + r2 > qcol) zz = NEG_INF;
        z[mi * 4 + r2] = zz;
        tmax = fmaxf(tmax, zz);
      }
    tmax = fmaxf(tmax, __shfl_xor(tmax, 16));
    tmax = fmaxf(tmax, __shfl_xor(tmax, 32));
    float m_new = fmaxf(m_run, tmax);
    float corr = exp2f(m_run - m_new);
    float psum = 0.f;
    ushort pb[16];
#pragma unroll
    for (int i = 0; i < 16; ++i) {
      float pv = exp2f(z[i] - m_new);
      psum += pv;
      pb[i] = f2bf(pv);
    }
    psum += __shfl_xor(psum, 16);
    psum += __shfl_xor(psum, 32);
    l_run = l_run * corr + psum;
    m_run = m_new;

    {
      ushort* pw = Ps[wid];
#pragma unroll
      for (int mi = 0; mi < 4; ++mi) {
        int bo = (lr * 128 + mi * 32 + g * 8) ^ ((lr & 7) << 4);
        ushort4 w4 = {pb[mi * 4], pb[mi * 4 + 1], pb[mi * 4 + 2], pb[mi * 4 + 3]};
        *reinterpret_cast<ushort4*>(&pw[bo >> 1]) = w4;
      }
    }

    float cq[4];
#pragma unroll
    for (int r2 = 0; r2 < 4; ++r2) cq[r2] = __shfl(corr, (lane >> 4) * 4 + r2);
#pragma unroll
    for (int ni = 0; ni < 4; ++ni)
#pragma unroll
      for (int r2 = 0; r2 < 4; ++r2) accy[ni][r2] *= cq[r2];

    __builtin_amdgcn_s_setprio(1);
#pragma unroll
    for (int ks = 0; ks < 2; ++ks) {
      int po = (lr * 128 + ks * 64 + g * 16) ^ ((lr & 7) << 4);
      s8v pa = *reinterpret_cast<const s8v*>(&Ps[wid][po >> 1]);
#pragma unroll
      for (int ni = 0; ni < 4; ++ni) {
        int vo = ((ni * 16 + lr) * 128 + ks * 64 + g * 16) ^ ((lr & 7) << 4);
        s8v vf = *reinterpret_cast<const s8v*>(&Vs[cur][vo >> 1]);
        accy[ni] = __builtin_amdgcn_mfma_f32_16x16x32_bf16(pa, vf, accy[ni], 0, 0, 0);
      }
    }
    __builtin_amdgcn_s_setprio(0);
    cur ^= 1;
  }

  float lq[4];
#pragma unroll
  for (int r2 = 0; r2 < 4; ++r2) lq[r2] = 1.f / __shfl(l_run, (lane >> 4) * 4 + r2);
  int n = nh >> 4, hh = nh & 15;
  float* xb = x + ((size_t)(n * 1024 + qt * 64 + wid * 16)) * 1024 + hh * 64;
#pragma unroll
  for (int r2 = 0; r2 < 4; ++r2) {
    float* xr = xb + (size_t)(g * 4 + r2) * 1024;
#pragma unroll
    for (int ni = 0; ni < 4; ++ni)
      xr[ni * 16 + lr] += accy[ni][r2] * lq[r2];
  }
}

// ---------------------------------------------------------------------------
extern "C" void kernel_launch(void* const* d_in, const int* in_sizes, int n_in,
                              void* d_out, int out_size, void* d_ws, size_t ws_size,
                              hipStream_t stream) {
  const int*   ids  = (const int*)  d_in[0];
  const float* emb  = (const float*)d_in[1];
  const float* ln1w = (const float*)d_in[2];
  const float* ln1b = (const float*)d_in[3];
  const float* wq   = (const float*)d_in[4];
  const float* wk   = (const float*)d_in[5];
  const float* wv   = (const float*)d_in[6];
  const float* ln2w = (const float*)d_in[7];
  const float* ln2b = (const float*)d_in[8];
  const float* fc1w = (const float*)d_in[9];
  const float* fc1b = (const float*)d_in[10];
  const float* fc2w = (const float*)d_in[11];
  const float* fc2b = (const float*)d_in[12];
  const float* row_ = (const float*)d_in[13];
  const float* rob  = (const float*)d_in[14];
  (void)in_sizes; (void)n_in; (void)out_size;

  char* p = (char*)d_ws;
  auto carve = [&](size_t bytes) {
    char* r = p;
    p += (bytes + 255) & ~(size_t)255;
    return (void*)r;
  };
  ushort* ro_bf = (ushort*)carve(32000ull * 1024 * 2);
  float*  x     = (float*) carve(2048ull * 1024 * 4);
  ushort* h     = (ushort*)carve(2048ull * 1024 * 2);
  ushort* qkvb  = (ushort*)carve(3ull * 2097152 * 2);   // bf16 q/k [z][nh][t][64]
  ushort* vtb   = (ushort*)carve(2097152ull * 2);       // bf16 vT [nh][64][1024]
  ushort* mbuf  = (ushort*)carve(2048ull * 4096 * 2);
  ushort* xb    = (ushort*)carve(2048ull * 1024 * 2);
  size_t used_common = (size_t)(p - (char*)d_ws);

  const size_t SZ_WQKV_ALL = 3ull * 8388608 * 2;   // merged [L][3][1M]
  const size_t SZ_FC_ALL   = 33554432ull * 2;
  const size_t SZ_WQKV_1   = 3ull * 1048576 * 2;
  const size_t SZ_FC_1     = 4194304ull * 2;
  bool upfront = ws_size >= used_common + SZ_WQKV_ALL + 2 * SZ_FC_ALL + 4096;

  ushort *wqkv_bf, *fc1_bf, *fc2_bf;
  size_t lq3, lf;
  if (upfront) {
    wqkv_bf = (ushort*)carve(SZ_WQKV_ALL);
    fc1_bf  = (ushort*)carve(SZ_FC_ALL);
    fc2_bf  = (ushort*)carve(SZ_FC_ALL);
    lq3 = 3145728; lf = 4194304;
    cvtall_kernel<<<15264, 256, 0, stream>>>(wq, wk, wv, fc1w, fc2w, row_,
                                             wqkv_bf, fc1_bf, fc2_bf, ro_bf);
  } else {
    wqkv_bf = (ushort*)carve(SZ_WQKV_1);
    fc1_bf  = (ushort*)carve(SZ_FC_1);
    fc2_bf  = (ushort*)carve(SZ_FC_1);
    lq3 = 0; lf = 0;
    cvt_kernel<<<32000, 256, 0, stream>>>(row_, ro_bf, 32768000);
  }

  embed_kernel<<<2048, 256, 0, stream>>>(ids, emb, x);

  for (int l = 0; l < 8; ++l) {
    if (!upfront) {
      cvt_kernel<<<1024, 256, 0, stream>>>(wq + (size_t)l * 1048576, wqkv_bf, 1048576);
      cvt_kernel<<<1024, 256, 0, stream>>>(wk + (size_t)l * 1048576, wqkv_bf + 1048576, 1048576);
      cvt_kernel<<<1024, 256, 0, stream>>>(wv + (size_t)l * 1048576, wqkv_bf + 2097152, 1048576);
      cvt_kernel<<<4096, 256, 0, stream>>>(fc1w + (size_t)l * 4194304, fc1_bf, 4194304);
      cvt_kernel<<<4096, 256, 0, stream>>>(fc2w + (size_t)l * 4194304, fc2_bf, 4194304);
    }
    const ushort* wqkv_l = wqkv_bf + (size_t)l * lq3;
    const ushort* fc1_l  = fc1_bf + (size_t)l * lf;
    const ushort* fc2_l  = fc2_bf + (size_t)l * lf;

    ln_kernel<<<2048, 256, 0, stream>>>(x, ln1w + l * 1024, ln1b + l * 1024, h);
    gemm_kernel<EPI_QKV, 64><<<dim3(32, 24), 256, 0, stream>>>(
        h, wqkv_l, nullptr, qkvb, vtb, 2048, 3072, 1024, 0);
    attn_kernel<<<512, 256, 0, stream>>>(qkvb, qkvb + 2097152, vtb, x);
    ln_kernel<<<2048, 256, 0, stream>>>(x, ln2w + l * 1024, ln2b + l * 1024, h);
    gemm_kernel<EPI_GELU, 64><<<dim3(32, 32), 256, 0, stream>>>(
        h, fc1_l, fc1b + (size_t)l * 4096, mbuf, nullptr, 2048, 4096, 1024, 0);
    gemm_kernel<EPI_RES, 64><<<dim3(32, 8, 4), 256, 0, stream>>>(
        mbuf, fc2_l, fc2b + (size_t)l * 1024, x, nullptr, 2048, 1024, 4096, 1024);
  }
  cvt_kernel<<<2048, 256, 0, stream>>>(x, xb, 2097152);
  gemm_kernel<EPI_BIAS, 128><<<dim3(16, 250), 256, 0, stream>>>(
      xb, ro_bf, rob, d_out, nullptr, 2048, 32000, 1024, 0);
}

// Round 16
// 1340.277 us; speedup vs baseline: 1.5086x; 1.4700x over previous
//
#include <hip/hip_runtime.h>
#include <cstdint>

// PicoGPT forward: V=32000 D=1024 DK=DV=64 H=16 DH=4096 L=8, input [2,1024]
// bf16 MFMA GEMMs: BK=64, XOR-swizzled LDS, global_load_lds both operands
// (m97+T2), XCD swizzle (T1). R16: RES split-K atomics eliminated — z=2 plain
// f32 partials, folded into next layer's LN1 (or final cvtfold). Attn 2/CU +
// setprio; cvtall nt loads; layer GEMMs BM=64 (256,5), readout BM=128 (256,4).

#define DEVI __device__ __forceinline__
#define NEG_INF (-__builtin_inff())

typedef __attribute__((ext_vector_type(8))) short s8v;            // 8 x bf16
typedef __attribute__((ext_vector_type(8))) unsigned short us8;   // 8 x bf16 store
typedef __attribute__((ext_vector_type(4))) float f4v;

DEVI ushort f2bf(float f) {  // RTNE f32 -> bf16
  uint32_t x = __float_as_uint(f);
  x += 0x7fffu + ((x >> 16) & 1u);
  return (ushort)(x >> 16);
}

DEVI void gload16(const void* g, void* l) {  // async global->LDS, 16B/lane
  __builtin_amdgcn_global_load_lds((const __attribute__((address_space(1))) void*)g,
                                   (__attribute__((address_space(3))) void*)l, 16, 0, 0);
}

// ---------- f32 -> bf16 convert (generic) ----------
__global__ __launch_bounds__(256) void cvt_kernel(const float* __restrict__ in,
                                                  ushort* __restrict__ out, int n) {
  int i = (blockIdx.x * 256 + threadIdx.x) * 4;
  if (i >= n) return;
  float4 v = *reinterpret_cast<const float4*>(in + i);
  ushort4 o;
  o.x = f2bf(v.x); o.y = f2bf(v.y); o.z = f2bf(v.z); o.w = f2bf(v.w);
  *reinterpret_cast<ushort4*>(out + i) = o;
}

// ---------- final fold: xb = bf16(x + p0 + p1), grid 2048 ----------
__global__ __launch_bounds__(256) void cvtfold_kernel(const float* __restrict__ x,
                                                      const float* __restrict__ p0,
                                                      const float* __restrict__ p1,
                                                      ushort* __restrict__ out) {
  size_t i = ((size_t)blockIdx.x * 256 + threadIdx.x) * 4;
  float4 v = *reinterpret_cast<const float4*>(x + i);
  float4 a = *reinterpret_cast<const float4*>(p0 + i);
  float4 c = *reinterpret_cast<const float4*>(p1 + i);
  ushort4 o;
  o.x = f2bf(v.x + a.x + c.x);
  o.y = f2bf(v.y + a.y + c.y);
  o.z = f2bf(v.z + a.z + c.z);
  o.w = f2bf(v.w + a.w + c.w);
  *reinterpret_cast<ushort4*>(out + i) = o;
}

// ---------- all weights f32 -> bf16, 8-way ILP, nt loads ----------
// grid = 125042688/8192 = 15264 blocks; every segment boundary divides 8192.
__global__ __launch_bounds__(256) void cvtall_kernel(const float* __restrict__ wq,
                                                     const float* __restrict__ wk,
                                                     const float* __restrict__ wv,
                                                     const float* __restrict__ fc1w,
                                                     const float* __restrict__ fc2w,
                                                     const float* __restrict__ row_,
                                                     ushort* __restrict__ wqkv_bf,
                                                     ushort* __restrict__ fc1_bf,
                                                     ushort* __restrict__ fc2_bf,
                                                     ushort* __restrict__ ro_bf) {
  const size_t NQ3 = 25165824, NF = 33554432;   // 3*8M, 32M
  size_t b0 = (size_t)blockIdx.x * 8192;
  const float* src;
  ushort* dst;
  if (b0 < NQ3) {                                // qkv -> [L][3][1M] interleave
    int which = (int)(b0 >> 23);
    size_t j = b0 & 8388607;
    src = (which == 0 ? wq : which == 1 ? wk : wv) + j;
    dst = wqkv_bf + (j >> 20) * 3145728 + (size_t)which * 1048576 + (j & 1048575);
  } else if (b0 < NQ3 + NF) {
    size_t r = b0 - NQ3;
    src = fc1w + r; dst = fc1_bf + r;
  } else if (b0 < NQ3 + 2 * NF) {
    size_t r = b0 - NQ3 - NF;
    src = fc2w + r; dst = fc2_bf + r;
  } else {
    size_t r = b0 - NQ3 - 2 * NF;
    src = row_ + r; dst = ro_bf + r;
  }
  int t4 = threadIdx.x * 4;
  f4v v[8];
#pragma unroll
  for (int k = 0; k < 8; ++k)
    v[k] = __builtin_nontemporal_load(reinterpret_cast<const f4v*>(src + t4 + k * 1024));
#pragma unroll
  for (int k = 0; k < 8; ++k) {
    ushort4 o = {f2bf(v[k].x), f2bf(v[k].y), f2bf(v[k].z), f2bf(v[k].w)};
    *reinterpret_cast<ushort4*>(dst + t4 + k * 1024) = o;
  }
}

// ---------- embedding + sinusoidal pos encoding, grid = 2048 rows ----------
__global__ __launch_bounds__(256) void embed_kernel(const int* __restrict__ ids,
                                                    const float* __restrict__ emb,
                                                    float* __restrict__ x) {
  int row = blockIdx.x;  // n*1024 + t
  int t = row & 1023;
  int id = ids[row];
  int d0 = threadIdx.x * 4;
  float4 e = *reinterpret_cast<const float4*>(emb + (size_t)id * 1024 + d0);
  float pe[4];
#pragma unroll
  for (int i = 0; i < 4; ++i) {
    int d = d0 + i;
    float dv = expf((float)(d & ~1) * (-9.210340371976184f / 1024.f));
    float ang = (float)t * dv;
    pe[i] = (d & 1) ? cosf(ang) : sinf(ang);
  }
  float4 o;
  o.x = e.x + pe[0]; o.y = e.y + pe[1]; o.z = e.z + pe[2]; o.w = e.w + pe[3];
  *reinterpret_cast<float4*>(x + (size_t)row * 1024 + d0) = o;
}

// ---------- LayerNorm (+ optional partial-fold), grid = 2048 rows ----------
// fold: x += p0 + p1 (prev layer's RES split-K partials, bias already in p0),
// written back to x before LN. Each block owns its row -> race-free.
__global__ __launch_bounds__(256) void ln_kernel(float* __restrict__ x,
                                                 const float* __restrict__ p0,
                                                 const float* __restrict__ p1,
                                                 const float* __restrict__ w,
                                                 const float* __restrict__ b,
                                                 ushort* __restrict__ out, int fold) {
  int row = blockIdx.x, tid = threadIdx.x;
  int lane = tid & 63, wid = tid >> 6;
  float* xr = x + (size_t)row * 1024;
  float4 v = reinterpret_cast<const float4*>(xr)[tid];
  if (fold) {
    size_t off = (size_t)row * 1024 + tid * 4;
    float4 a = *reinterpret_cast<const float4*>(p0 + off);
    float4 c = *reinterpret_cast<const float4*>(p1 + off);
    v.x += a.x + c.x; v.y += a.y + c.y; v.z += a.z + c.z; v.w += a.w + c.w;
    reinterpret_cast<float4*>(xr)[tid] = v;
  }
  __shared__ float red[8];
  float s = v.x + v.y + v.z + v.w;
#pragma unroll
  for (int o = 32; o; o >>= 1) s += __shfl_xor(s, o);
  if (lane == 0) red[wid] = s;
  __syncthreads();
  float mean = (red[0] + red[1] + red[2] + red[3]) * (1.f / 1024.f);
  float d0 = v.x - mean, d1 = v.y - mean, d2 = v.z - mean, d3 = v.w - mean;
  float s2 = d0 * d0 + d1 * d1 + d2 * d2 + d3 * d3;
#pragma unroll
  for (int o = 32; o; o >>= 1) s2 += __shfl_xor(s2, o);
  if (lane == 0) red[4 + wid] = s2;
  __syncthreads();
  float var = (red[4] + red[5] + red[6] + red[7]) * (1.f / 1024.f);
  float rstd = rsqrtf(var + 1e-5f);
  float4 wv = reinterpret_cast<const float4*>(w)[tid];
  float4 bv = reinterpret_cast<const float4*>(b)[tid];
  ushort4 o;
  o.x = f2bf(d0 * rstd * wv.x + bv.x);
  o.y = f2bf(d1 * rstd * wv.y + bv.y);
  o.z = f2bf(d2 * rstd * wv.z + bv.z);
  o.w = f2bf(d3 * rstd * wv.w + bv.w);
  *reinterpret_cast<ushort4*>(out + (size_t)row * 1024 + tid * 4) = o;
}

// ---------- bf16 MFMA GEMM: C[M,N] = A[M,K] * Bw[N,K]^T ----------
// BMx128 tile, BK=64, 256 thr = 4 waves (2x2), wave = (BM/2)x64.
// XCD-bijective swizzle (needs gridDim.x*gridDim.y % 8 == 0).
enum { EPI_QKV = 0, EPI_GELU = 1, EPI_RES = 2, EPI_BIAS = 3 };

template <int EPI, int BM>
__global__ __launch_bounds__(256, BM == 64 ? 5 : 4)
void gemm_kernel(const ushort* __restrict__ A,
                 const ushort* __restrict__ Bw,
                 const float* __restrict__ bias,
                 void* __restrict__ outp,
                 void* __restrict__ outp2,
                 int M, int N, int K, int kz) {
  constexpr int MI = BM / 32;            // 16-row frag groups per wave
  __shared__ char smem[BM * 128 + 16384];
  ushort* As = (ushort*)smem;            // [BM][64] bf16, chunk-swizzled
  ushort* Bs = (ushort*)(smem + BM * 128);  // [128][64]
  int tid = threadIdx.x;
  int lane = tid & 63;
  int wid = tid >> 6;
  int wr = wid >> 1, wc = wid & 1;       // 2x2 wave grid, wave = (BM/2)x64

  // XCD swizzle: consecutive tiles land on one XCD -> B panels fetched once/XCD
  int gx = gridDim.x;
  int nwg = gx * gridDim.y;
  int bid = blockIdx.x + blockIdx.y * gx;
  int swz = (bid & 7) * (nwg >> 3) + (bid >> 3);
  int bm = swz % gx, bn = swz / gx;

  int kbeg = 0, kend = K;
  if constexpr (EPI == EPI_RES) {        // split-K over gridDim.z
    kbeg = blockIdx.z * kz;
    kend = kbeg + kz;
  }

  const ushort* Ab = A + (size_t)(bm * BM) * K;
  const ushort* Bb = Bw + (size_t)(bn * 128) * K;

  auto stage = [&](int k0) {
#pragma unroll
    for (int i = 0; i < BM / 32; ++i) {  // BM*8 chunks of 16B
      int c = tid + i * 256;
      int row = c >> 3, j = c & 7;
      gload16(Ab + (size_t)row * K + k0 + ((j ^ (row & 7)) * 8), &As[c * 8]);
    }
#pragma unroll
    for (int i = 0; i < 4; ++i) {
      int c = tid + i * 256;
      int row = c >> 3, j = c & 7;
      gload16(Bb + (size_t)row * K + k0 + ((j ^ (row & 7)) * 8), &Bs[c * 8]);
    }
  };

  f4v acc[MI][4] = {};
  int lr = lane & 15, g = lane >> 4;
  int sx = lr & 7;  // swizzle key (row&7 of every frag row this lane reads)

  stage(kbeg);
  for (int k0 = kbeg; k0 < kend; k0 += 64) {
    __syncthreads();  // staging complete (compiler drains vmcnt at barrier)
    s8v af[MI], bf[4];
#pragma unroll
    for (int mi = 0; mi < MI; ++mi)
      af[mi] = *reinterpret_cast<const s8v*>(
          &As[(wr * (BM / 2) + mi * 16 + lr) * 64 + ((g ^ sx) * 8)]);
#pragma unroll
    for (int ni = 0; ni < 4; ++ni)
      bf[ni] = *reinterpret_cast<const s8v*>(
          &Bs[(wc * 64 + ni * 16 + lr) * 64 + ((g ^ sx) * 8)]);
#pragma unroll
    for (int mi = 0; mi < MI; ++mi)
#pragma unroll
      for (int ni = 0; ni < 4; ++ni)
        acc[mi][ni] = __builtin_amdgcn_mfma_f32_16x16x32_bf16(af[mi], bf[ni],
                                                              acc[mi][ni], 0, 0, 0);
    __builtin_amdgcn_sched_barrier(0);   // keep k-half-1 reads after MFMA batch
#pragma unroll
    for (int mi = 0; mi < MI; ++mi)
      af[mi] = *reinterpret_cast<const s8v*>(
          &As[(wr * (BM / 2) + mi * 16 + lr) * 64 + (((4 + g) ^ sx) * 8)]);
#pragma unroll
    for (int ni = 0; ni < 4; ++ni)
      bf[ni] = *reinterpret_cast<const s8v*>(
          &Bs[(wc * 64 + ni * 16 + lr) * 64 + (((4 + g) ^ sx) * 8)]);
    __syncthreads();               // all frag reads done -> LDS reusable
    if (k0 + 64 < kend) stage(k0 + 64);  // next-tile loads fly under MFMA
#pragma unroll
    for (int mi = 0; mi < MI; ++mi)
#pragma unroll
      for (int ni = 0; ni < 4; ++ni)
        acc[mi][ni] = __builtin_amdgcn_mfma_f32_16x16x32_bf16(af[mi], bf[ni],
                                                              acc[mi][ni], 0, 0, 0);
  }

  // ---- epilogue: per-wave LDS transpose (aliases As/Bs) -> coalesced stores ----
  __syncthreads();  // all frag reads done before aliasing
  float* sw = (float*)smem + wid * (16 * 36);
  int s = lane >> 3, q = lane & 7;
  for (int mi = 0; mi < MI; ++mi) {
    for (int np = 0; np < 2; ++np) {   // 2 column halves of the wave's 64 cols
#pragma unroll
      for (int ni2 = 0; ni2 < 2; ++ni2)
#pragma unroll
        for (int r = 0; r < 4; ++r)
          sw[(g * 4 + r) * 36 + ni2 * 16 + lr] = acc[mi][np * 2 + ni2][r];
      // wave-private scratch round-trip; compiler inserts lgkm waits
      int gnb = bn * 128 + wc * 64 + np * 32;      // wave-uniform col base
      if constexpr (EPI == EPI_QKV) {
        int z = gnb >> 10;                          // 0=q 1=k 2=v (uniform)
        int row0 = bm * BM + wr * (BM / 2) + mi * 16;  // t base (16 rows)
        int nb = row0 >> 10, tp0 = row0 & 1023;
        int hh = (gnb >> 6) & 15, dd0 = gnb & 63;
        if (z < 2) {                                // q/k: row-major [nh][t][64]
          ushort* o = (ushort*)outp;
#pragma unroll
          for (int h = 0; h < 2; ++h) {
            float4 v4 = *reinterpret_cast<const float4*>(&sw[(h * 8 + s) * 36 + q * 4]);
            int tpos = tp0 + h * 8 + s;
            ushort4 o4 = {f2bf(v4.x), f2bf(v4.y), f2bf(v4.z), f2bf(v4.w)};
            *reinterpret_cast<ushort4*>(o + (size_t)z * 2097152 + (size_t)nb * 1048576 +
                                        (size_t)hh * 65536 + (size_t)tpos * 64 +
                                        dd0 + q * 4) = o4;
          }
        } else {                                    // v: transposed [nh][dv][1024]
          ushort* ov = (ushort*)outp2;
          int dvq = lane & 31, hf = lane >> 5;
          us8 w;
#pragma unroll
          for (int j = 0; j < 8; ++j)
            w[j] = f2bf(sw[(hf * 8 + j) * 36 + dvq]);
          *reinterpret_cast<us8*>(ov + (size_t)nb * 1048576 + (size_t)hh * 65536 +
                                  (size_t)(dd0 + dvq) * 1024 + tp0 + hf * 8) = w;
        }
      } else {
#pragma unroll
        for (int h = 0; h < 2; ++h) {
          float4 v4 = *reinterpret_cast<const float4*>(&sw[(h * 8 + s) * 36 + q * 4]);
          int gm = bm * BM + wr * (BM / 2) + mi * 16 + h * 8 + s;
          int gn = gnb + q * 4;
          if constexpr (EPI == EPI_GELU) {
            const float4 bb = *reinterpret_cast<const float4*>(bias + gn);
            float u[4] = {v4.x + bb.x, v4.y + bb.y, v4.z + bb.z, v4.w + bb.w};
            ushort4 o4;
            ushort* po = (ushort*)&o4;
#pragma unroll
            for (int j = 0; j < 4; ++j) {
              float zz = u[j] * (1.5957691216f + 0.0713548162f * u[j] * u[j]);
              float gl = u[j] / (1.f + exp2f(zz * -1.4426950409f));
              po[j] = f2bf(gl);
            }
            *reinterpret_cast<ushort4*>((ushort*)outp + (size_t)gm * N + gn) = o4;
          } else if constexpr (EPI == EPI_RES) {
            // split-K partials: plain f32 store to slice z; bias in slice 0 only
            float* o = (float*)outp + (size_t)blockIdx.z * 2097152 +
                       (size_t)gm * N + gn;
            float4 bb = *reinterpret_cast<const float4*>(bias + gn);
            bool addb = (blockIdx.z == 0);
            f4v o4 = {v4.x + (addb ? bb.x : 0.f), v4.y + (addb ? bb.y : 0.f),
                      v4.z + (addb ? bb.z : 0.f), v4.w + (addb ? bb.w : 0.f)};
            *reinterpret_cast<f4v*>(o) = o4;
          } else {  // EPI_BIAS (readout): non-temporal
            const float4 bb = *reinterpret_cast<const float4*>(bias + gn);
            f4v o4 = {v4.x + bb.x, v4.y + bb.y, v4.z + bb.z, v4.w + bb.w};
            __builtin_nontemporal_store(o4, (f4v*)((float*)outp + (size_t)gm * N + gn));
          }
        }
      }
    }
  }
}

// ---------- MFMA flash attention ----------
// grid 512: bid = half*256 + bx*32 + nh_r; qt = half ? 15-bx : bx.
// Co-resident blocks (c, c+256) share nh and have complementary qt.
__global__ __launch_bounds__(256) void attn_kernel(const ushort* __restrict__ qg,
                                                   const ushort* __restrict__ kg,
                                                   const ushort* __restrict__ vtg,
                                                   float* __restrict__ x) {
  __shared__ ushort Ks[2][4096];  // [64 s][64 d] bf16, swizzled
  __shared__ ushort Vs[2][4096];  // [64 dv][64 s] bf16, swizzled
  __shared__ ushort Ps[4][1024];  // per-wave P [16 q][64 s] bf16, swizzled
  int bid = blockIdx.x;
  int half = bid >> 8, r = bid & 255;
  int bx = r >> 5, nh = r & 31;
  int qt = half ? (15 - bx) : bx;
  int tid = threadIdx.x, lane = tid & 63, wid = tid >> 6;
  int lr = lane & 15, g = lane >> 4;
  size_t base = (size_t)nh * 65536;
  const ushort* kb = kg + base;
  const ushort* vb = vtg + base;
  const float SCALE = 0.125f * 1.44269504088896f;

  auto stage = [&](int st, int buf) {
    int s0 = st * 64;
#pragma unroll
    for (int j = 0; j < 2; ++j) {
      int c = tid + j * 256;
      int row = c >> 3;
      int col = ((c & 7) ^ (row & 7)) * 8;  // inverse-swizzled source column
      gload16(kb + (size_t)(s0 + row) * 64 + col, &Ks[buf][c * 8]);
      gload16(vb + (size_t)row * 1024 + s0 + col, &Vs[buf][c * 8]);
    }
  };

  int qrow = qt * 64 + wid * 16 + lr;
  s8v qf[2];
  qf[0] = *reinterpret_cast<const s8v*>(qg + base + (size_t)qrow * 64 + g * 8);
  qf[1] = *reinterpret_cast<const s8v*>(qg + base + (size_t)qrow * 64 + 32 + g * 8);

  float m_run = NEG_INF, l_run = 0.f;
  f4v accy[4] = {};
  stage(0, 0);
  int cur = 0;
  for (int st = 0; st <= qt; ++st) {
    __syncthreads();
    if (st < qt) stage(st + 1, cur ^ 1);

    f4v accs[4] = {};
    __builtin_amdgcn_s_setprio(1);
#pragma unroll
    for (int kc = 0; kc < 2; ++kc)
#pragma unroll
      for (int mi = 0; mi < 4; ++mi) {
        int bo = ((mi * 16 + lr) * 128 + kc * 64 + g * 16) ^ ((lr & 7) << 4);
        s8v kf = *reinterpret_cast<const s8v*>(&Ks[cur][bo >> 1]);
        accs[mi] = __builtin_amdgcn_mfma_f32_16x16x32_bf16(kf, qf[kc], accs[mi], 0, 0, 0);
      }
    __builtin_amdgcn_s_setprio(0);

    float z[16];
    float tmax = NEG_INF;
    bool diag = (st == qt);
    int qcol = qt * 64 + wid * 16 + lr;
#pragma unroll
    for (int mi = 0; mi < 4; ++mi)
#pragma unroll
      for (int r2 = 0; r2 < 4; ++r2) {
        float zz = accs[mi][r2] * SCALE;
        if (diag && st * 64 + mi * 16 + g * 4 + r2 > qcol) zz = NEG_INF;
        z[mi * 4 + r2] = zz;
        tmax = fmaxf(tmax, zz);
      }
    tmax = fmaxf(tmax, __shfl_xor(tmax, 16));
    tmax = fmaxf(tmax, __shfl_xor(tmax, 32));
    float m_new = fmaxf(m_run, tmax);
    float corr = exp2f(m_run - m_new);
    float psum = 0.f;
    ushort pb[16];
#pragma unroll
    for (int i = 0; i < 16; ++i) {
      float pv = exp2f(z[i] - m_new);
      psum += pv;
      pb[i] = f2bf(pv);
    }
    psum += __shfl_xor(psum, 16);
    psum += __shfl_xor(psum, 32);
    l_run = l_run * corr + psum;
    m_run = m_new;

    {
      ushort* pw = Ps[wid];
#pragma unroll
      for (int mi = 0; mi < 4; ++mi) {
        int bo = (lr * 128 + mi * 32 + g * 8) ^ ((lr & 7) << 4);
        ushort4 w4 = {pb[mi * 4], pb[mi * 4 + 1], pb[mi * 4 + 2], pb[mi * 4 + 3]};
        *reinterpret_cast<ushort4*>(&pw[bo >> 1]) = w4;
      }
    }

    float cq[4];
#pragma unroll
    for (int r2 = 0; r2 < 4; ++r2) cq[r2] = __shfl(corr, (lane >> 4) * 4 + r2);
#pragma unroll
    for (int ni = 0; ni < 4; ++ni)
#pragma unroll
      for (int r2 = 0; r2 < 4; ++r2) accy[ni][r2] *= cq[r2];

    __builtin_amdgcn_s_setprio(1);
#pragma unroll
    for (int ks = 0; ks < 2; ++ks) {
      int po = (lr * 128 + ks * 64 + g * 16) ^ ((lr & 7) << 4);
      s8v pa = *reinterpret_cast<const s8v*>(&Ps[wid][po >> 1]);
#pragma unroll
      for (int ni = 0; ni < 4; ++ni) {
        int vo = ((ni * 16 + lr) * 128 + ks * 64 + g * 16) ^ ((lr & 7) << 4);
        s8v vf = *reinterpret_cast<const s8v*>(&Vs[cur][vo >> 1]);
        accy[ni] = __builtin_amdgcn_mfma_f32_16x16x32_bf16(pa, vf, accy[ni], 0, 0, 0);
      }
    }
    __builtin_amdgcn_s_setprio(0);
    cur ^= 1;
  }

  float lq[4];
#pragma unroll
  for (int r2 = 0; r2 < 4; ++r2) lq[r2] = 1.f / __shfl(l_run, (lane >> 4) * 4 + r2);
  int n = nh >> 4, hh = nh & 15;
  float* xb = x + ((size_t)(n * 1024 + qt * 64 + wid * 16)) * 1024 + hh * 64;
#pragma unroll
  for (int r2 = 0; r2 < 4; ++r2) {
    float* xr = xb + (size_t)(g * 4 + r2) * 1024;
#pragma unroll
    for (int ni = 0; ni < 4; ++ni)
      xr[ni * 16 + lr] += accy[ni][r2] * lq[r2];
  }
}

// ---------------------------------------------------------------------------
extern "C" void kernel_launch(void* const* d_in, const int* in_sizes, int n_in,
                              void* d_out, int out_size, void* d_ws, size_t ws_size,
                              hipStream_t stream) {
  const int*   ids  = (const int*)  d_in[0];
  const float* emb  = (const float*)d_in[1];
  const float* ln1w = (const float*)d_in[2];
  const float* ln1b = (const float*)d_in[3];
  const float* wq   = (const float*)d_in[4];
  const float* wk   = (const float*)d_in[5];
  const float* wv   = (const float*)d_in[6];
  const float* ln2w = (const float*)d_in[7];
  const float* ln2b = (const float*)d_in[8];
  const float* fc1w = (const float*)d_in[9];
  const float* fc1b = (const float*)d_in[10];
  const float* fc2w = (const float*)d_in[11];
  const float* fc2b = (const float*)d_in[12];
  const float* row_ = (const float*)d_in[13];
  const float* rob  = (const float*)d_in[14];
  (void)in_sizes; (void)n_in; (void)out_size;

  char* p = (char*)d_ws;
  auto carve = [&](size_t bytes) {
    char* r = p;
    p += (bytes + 255) & ~(size_t)255;
    return (void*)r;
  };
  ushort* ro_bf = (ushort*)carve(32000ull * 1024 * 2);
  float*  x     = (float*) carve(2048ull * 1024 * 4);
  ushort* h     = (ushort*)carve(2048ull * 1024 * 2);
  ushort* qkvb  = (ushort*)carve(3ull * 2097152 * 2);   // bf16 q/k [z][nh][t][64]
  ushort* vtb   = (ushort*)carve(2097152ull * 2);       // bf16 vT [nh][64][1024]
  ushort* mbuf  = (ushort*)carve(2048ull * 4096 * 2);
  ushort* xb    = (ushort*)carve(2048ull * 1024 * 2);
  float*  pbuf  = (float*) carve(2ull * 2097152 * 4);   // RES split-K partials
  size_t used_common = (size_t)(p - (char*)d_ws);

  const size_t SZ_WQKV_ALL = 3ull * 8388608 * 2;   // merged [L][3][1M]
  const size_t SZ_FC_ALL   = 33554432ull * 2;
  const size_t SZ_WQKV_1   = 3ull * 1048576 * 2;
  const size_t SZ_FC_1     = 4194304ull * 2;
  bool upfront = ws_size >= used_common + SZ_WQKV_ALL + 2 * SZ_FC_ALL + 4096;

  ushort *wqkv_bf, *fc1_bf, *fc2_bf;
  size_t lq3, lf;
  if (upfront) {
    wqkv_bf = (ushort*)carve(SZ_WQKV_ALL);
    fc1_bf  = (ushort*)carve(SZ_FC_ALL);
    fc2_bf  = (ushort*)carve(SZ_FC_ALL);
    lq3 = 3145728; lf = 4194304;
    cvtall_kernel<<<15264, 256, 0, stream>>>(wq, wk, wv, fc1w, fc2w, row_,
                                             wqkv_bf, fc1_bf, fc2_bf, ro_bf);
  } else {
    wqkv_bf = (ushort*)carve(SZ_WQKV_1);
    fc1_bf  = (ushort*)carve(SZ_FC_1);
    fc2_bf  = (ushort*)carve(SZ_FC_1);
    lq3 = 0; lf = 0;
    cvt_kernel<<<32000, 256, 0, stream>>>(row_, ro_bf, 32768000);
  }

  embed_kernel<<<2048, 256, 0, stream>>>(ids, emb, x);

  for (int l = 0; l < 8; ++l) {
    if (!upfront) {
      cvt_kernel<<<1024, 256, 0, stream>>>(wq + (size_t)l * 1048576, wqkv_bf, 1048576);
      cvt_kernel<<<1024, 256, 0, stream>>>(wk + (size_t)l * 1048576, wqkv_bf + 1048576, 1048576);
      cvt_kernel<<<1024, 256, 0, stream>>>(wv + (size_t)l * 1048576, wqkv_bf + 2097152, 1048576);
      cvt_kernel<<<4096, 256, 0, stream>>>(fc1w + (size_t)l * 4194304, fc1_bf, 4194304);
      cvt_kernel<<<4096, 256, 0, stream>>>(fc2w + (size_t)l * 4194304, fc2_bf, 4194304);
    }
    const ushort* wqkv_l = wqkv_bf + (size_t)l * lq3;
    const ushort* fc1_l  = fc1_bf + (size_t)l * lf;
    const ushort* fc2_l  = fc2_bf + (size_t)l * lf;

    // LN1 folds previous layer's RES partials into x (layer 0: no fold)
    ln_kernel<<<2048, 256, 0, stream>>>(x, pbuf, pbuf + 2097152,
                                        ln1w + l * 1024, ln1b + l * 1024, h, l > 0);
    gemm_kernel<EPI_QKV, 64><<<dim3(32, 24), 256, 0, stream>>>(
        h, wqkv_l, nullptr, qkvb, vtb, 2048, 3072, 1024, 0);
    attn_kernel<<<512, 256, 0, stream>>>(qkvb, qkvb + 2097152, vtb, x);
    ln_kernel<<<2048, 256, 0, stream>>>(x, nullptr, nullptr,
                                        ln2w + l * 1024, ln2b + l * 1024, h, 0);
    gemm_kernel<EPI_GELU, 64><<<dim3(32, 32), 256, 0, stream>>>(
        h, fc1_l, fc1b + (size_t)l * 4096, mbuf, nullptr, 2048, 4096, 1024, 0);
    gemm_kernel<EPI_RES, 64><<<dim3(32, 8, 2), 256, 0, stream>>>(
        mbuf, fc2_l, fc2b + (size_t)l * 1024, pbuf, nullptr, 2048, 1024, 4096, 2048);
  }
  cvtfold_kernel<<<2048, 256, 0, stream>>>(x, pbuf, pbuf + 2097152, xb);
  gemm_kernel<EPI_BIAS, 128><<<dim3(16, 250), 256, 0, stream>>>(
      xb, ro_bf, rob, d_out, nullptr, 2048, 32000, 1024, 0);
}

// Round 17
// 1316.637 us; speedup vs baseline: 1.5357x; 1.0180x over previous
//
#include <hip/hip_runtime.h>
#include <cstdint>

// PicoGPT forward: V=32000 D=1024 DK=DV=64 H=16 DH=4096 L=8, input [2,1024]
// bf16 MFMA GEMMs: BK=64, XOR-swizzled LDS, global_load_lds both operands
// (m97+T2), XCD swizzle (T1). R17: RES split-K z=2 -> z=4 (plain f32 partials,
// 4 blocks/CU; LN1/cvtfold fold 4 slices). Attn 2/CU + setprio; cvtall nt.

#define DEVI __device__ __forceinline__
#define NEG_INF (-__builtin_inff())

typedef __attribute__((ext_vector_type(8))) short s8v;            // 8 x bf16
typedef __attribute__((ext_vector_type(8))) unsigned short us8;   // 8 x bf16 store
typedef __attribute__((ext_vector_type(4))) float f4v;

DEVI ushort f2bf(float f) {  // RTNE f32 -> bf16
  uint32_t x = __float_as_uint(f);
  x += 0x7fffu + ((x >> 16) & 1u);
  return (ushort)(x >> 16);
}

DEVI void gload16(const void* g, void* l) {  // async global->LDS, 16B/lane
  __builtin_amdgcn_global_load_lds((const __attribute__((address_space(1))) void*)g,
                                   (__attribute__((address_space(3))) void*)l, 16, 0, 0);
}

// ---------- f32 -> bf16 convert (generic) ----------
__global__ __launch_bounds__(256) void cvt_kernel(const float* __restrict__ in,
                                                  ushort* __restrict__ out, int n) {
  int i = (blockIdx.x * 256 + threadIdx.x) * 4;
  if (i >= n) return;
  float4 v = *reinterpret_cast<const float4*>(in + i);
  ushort4 o;
  o.x = f2bf(v.x); o.y = f2bf(v.y); o.z = f2bf(v.z); o.w = f2bf(v.w);
  *reinterpret_cast<ushort4*>(out + i) = o;
}

// ---------- final fold: xb = bf16(x + p0+p1+p2+p3), grid 2048 ----------
__global__ __launch_bounds__(256) void cvtfold_kernel(const float* __restrict__ x,
                                                      const float* __restrict__ pb,
                                                      ushort* __restrict__ out) {
  size_t i = ((size_t)blockIdx.x * 256 + threadIdx.x) * 4;
  float4 v = *reinterpret_cast<const float4*>(x + i);
#pragma unroll
  for (int z = 0; z < 4; ++z) {
    float4 a = *reinterpret_cast<const float4*>(pb + (size_t)z * 2097152 + i);
    v.x += a.x; v.y += a.y; v.z += a.z; v.w += a.w;
  }
  ushort4 o = {f2bf(v.x), f2bf(v.y), f2bf(v.z), f2bf(v.w)};
  *reinterpret_cast<ushort4*>(out + i) = o;
}

// ---------- all weights f32 -> bf16, 8-way ILP, nt loads ----------
// grid = 125042688/8192 = 15264 blocks; every segment boundary divides 8192.
__global__ __launch_bounds__(256) void cvtall_kernel(const float* __restrict__ wq,
                                                     const float* __restrict__ wk,
                                                     const float* __restrict__ wv,
                                                     const float* __restrict__ fc1w,
                                                     const float* __restrict__ fc2w,
                                                     const float* __restrict__ row_,
                                                     ushort* __restrict__ wqkv_bf,
                                                     ushort* __restrict__ fc1_bf,
                                                     ushort* __restrict__ fc2_bf,
                                                     ushort* __restrict__ ro_bf) {
  const size_t NQ3 = 25165824, NF = 33554432;   // 3*8M, 32M
  size_t b0 = (size_t)blockIdx.x * 8192;
  const float* src;
  ushort* dst;
  if (b0 < NQ3) {                                // qkv -> [L][3][1M] interleave
    int which = (int)(b0 >> 23);
    size_t j = b0 & 8388607;
    src = (which == 0 ? wq : which == 1 ? wk : wv) + j;
    dst = wqkv_bf + (j >> 20) * 3145728 + (size_t)which * 1048576 + (j & 1048575);
  } else if (b0 < NQ3 + NF) {
    size_t r = b0 - NQ3;
    src = fc1w + r; dst = fc1_bf + r;
  } else if (b0 < NQ3 + 2 * NF) {
    size_t r = b0 - NQ3 - NF;
    src = fc2w + r; dst = fc2_bf + r;
  } else {
    size_t r = b0 - NQ3 - 2 * NF;
    src = row_ + r; dst = ro_bf + r;
  }
  int t4 = threadIdx.x * 4;
  f4v v[8];
#pragma unroll
  for (int k = 0; k < 8; ++k)
    v[k] = __builtin_nontemporal_load(reinterpret_cast<const f4v*>(src + t4 + k * 1024));
#pragma unroll
  for (int k = 0; k < 8; ++k) {
    ushort4 o = {f2bf(v[k].x), f2bf(v[k].y), f2bf(v[k].z), f2bf(v[k].w)};
    *reinterpret_cast<ushort4*>(dst + t4 + k * 1024) = o;
  }
}

// ---------- embedding + sinusoidal pos encoding, grid = 2048 rows ----------
__global__ __launch_bounds__(256) void embed_kernel(const int* __restrict__ ids,
                                                    const float* __restrict__ emb,
                                                    float* __restrict__ x) {
  int row = blockIdx.x;  // n*1024 + t
  int t = row & 1023;
  int id = ids[row];
  int d0 = threadIdx.x * 4;
  float4 e = *reinterpret_cast<const float4*>(emb + (size_t)id * 1024 + d0);
  float pe[4];
#pragma unroll
  for (int i = 0; i < 4; ++i) {
    int d = d0 + i;
    float dv = expf((float)(d & ~1) * (-9.210340371976184f / 1024.f));
    float ang = (float)t * dv;
    pe[i] = (d & 1) ? cosf(ang) : sinf(ang);
  }
  float4 o;
  o.x = e.x + pe[0]; o.y = e.y + pe[1]; o.z = e.z + pe[2]; o.w = e.w + pe[3];
  *reinterpret_cast<float4*>(x + (size_t)row * 1024 + d0) = o;
}

// ---------- LayerNorm (+ optional 4-slice partial fold), grid = 2048 rows ----------
__global__ __launch_bounds__(256) void ln_kernel(float* __restrict__ x,
                                                 const float* __restrict__ pb,
                                                 const float* __restrict__ w,
                                                 const float* __restrict__ b,
                                                 ushort* __restrict__ out, int fold) {
  int row = blockIdx.x, tid = threadIdx.x;
  int lane = tid & 63, wid = tid >> 6;
  float* xr = x + (size_t)row * 1024;
  float4 v = reinterpret_cast<const float4*>(xr)[tid];
  if (fold) {
    size_t off = (size_t)row * 1024 + tid * 4;
#pragma unroll
    for (int z = 0; z < 4; ++z) {
      float4 a = *reinterpret_cast<const float4*>(pb + (size_t)z * 2097152 + off);
      v.x += a.x; v.y += a.y; v.z += a.z; v.w += a.w;
    }
    reinterpret_cast<float4*>(xr)[tid] = v;
  }
  __shared__ float red[8];
  float s = v.x + v.y + v.z + v.w;
#pragma unroll
  for (int o = 32; o; o >>= 1) s += __shfl_xor(s, o);
  if (lane == 0) red[wid] = s;
  __syncthreads();
  float mean = (red[0] + red[1] + red[2] + red[3]) * (1.f / 1024.f);
  float d0 = v.x - mean, d1 = v.y - mean, d2 = v.z - mean, d3 = v.w - mean;
  float s2 = d0 * d0 + d1 * d1 + d2 * d2 + d3 * d3;
#pragma unroll
  for (int o = 32; o; o >>= 1) s2 += __shfl_xor(s2, o);
  if (lane == 0) red[4 + wid] = s2;
  __syncthreads();
  float var = (red[4] + red[5] + red[6] + red[7]) * (1.f / 1024.f);
  float rstd = rsqrtf(var + 1e-5f);
  float4 wv = reinterpret_cast<const float4*>(w)[tid];
  float4 bv = reinterpret_cast<const float4*>(b)[tid];
  ushort4 o;
  o.x = f2bf(d0 * rstd * wv.x + bv.x);
  o.y = f2bf(d1 * rstd * wv.y + bv.y);
  o.z = f2bf(d2 * rstd * wv.z + bv.z);
  o.w = f2bf(d3 * rstd * wv.w + bv.w);
  *reinterpret_cast<ushort4*>(out + (size_t)row * 1024 + tid * 4) = o;
}

// ---------- bf16 MFMA GEMM: C[M,N] = A[M,K] * Bw[N,K]^T ----------
// BMx128 tile, BK=64, 256 thr = 4 waves (2x2), wave = (BM/2)x64.
// XCD-bijective swizzle (needs gridDim.x*gridDim.y % 8 == 0).
enum { EPI_QKV = 0, EPI_GELU = 1, EPI_RES = 2, EPI_BIAS = 3 };

template <int EPI, int BM>
__global__ __launch_bounds__(256, BM == 64 ? 5 : 4)
void gemm_kernel(const ushort* __restrict__ A,
                 const ushort* __restrict__ Bw,
                 const float* __restrict__ bias,
                 void* __restrict__ outp,
                 void* __restrict__ outp2,
                 int M, int N, int K, int kz) {
  constexpr int MI = BM / 32;            // 16-row frag groups per wave
  __shared__ char smem[BM * 128 + 16384];
  ushort* As = (ushort*)smem;            // [BM][64] bf16, chunk-swizzled
  ushort* Bs = (ushort*)(smem + BM * 128);  // [128][64]
  int tid = threadIdx.x;
  int lane = tid & 63;
  int wid = tid >> 6;
  int wr = wid >> 1, wc = wid & 1;       // 2x2 wave grid, wave = (BM/2)x64

  // XCD swizzle: consecutive tiles land on one XCD -> B panels fetched once/XCD
  int gx = gridDim.x;
  int nwg = gx * gridDim.y;
  int bid = blockIdx.x + blockIdx.y * gx;
  int swz = (bid & 7) * (nwg >> 3) + (bid >> 3);
  int bm = swz % gx, bn = swz / gx;

  int kbeg = 0, kend = K;
  if constexpr (EPI == EPI_RES) {        // split-K over gridDim.z
    kbeg = blockIdx.z * kz;
    kend = kbeg + kz;
  }

  const ushort* Ab = A + (size_t)(bm * BM) * K;
  const ushort* Bb = Bw + (size_t)(bn * 128) * K;

  auto stage = [&](int k0) {
#pragma unroll
    for (int i = 0; i < BM / 32; ++i) {  // BM*8 chunks of 16B
      int c = tid + i * 256;
      int row = c >> 3, j = c & 7;
      gload16(Ab + (size_t)row * K + k0 + ((j ^ (row & 7)) * 8), &As[c * 8]);
    }
#pragma unroll
    for (int i = 0; i < 4; ++i) {
      int c = tid + i * 256;
      int row = c >> 3, j = c & 7;
      gload16(Bb + (size_t)row * K + k0 + ((j ^ (row & 7)) * 8), &Bs[c * 8]);
    }
  };

  f4v acc[MI][4] = {};
  int lr = lane & 15, g = lane >> 4;
  int sx = lr & 7;  // swizzle key (row&7 of every frag row this lane reads)

  stage(kbeg);
  for (int k0 = kbeg; k0 < kend; k0 += 64) {
    __syncthreads();  // staging complete (compiler drains vmcnt at barrier)
    s8v af[MI], bf[4];
#pragma unroll
    for (int mi = 0; mi < MI; ++mi)
      af[mi] = *reinterpret_cast<const s8v*>(
          &As[(wr * (BM / 2) + mi * 16 + lr) * 64 + ((g ^ sx) * 8)]);
#pragma unroll
    for (int ni = 0; ni < 4; ++ni)
      bf[ni] = *reinterpret_cast<const s8v*>(
          &Bs[(wc * 64 + ni * 16 + lr) * 64 + ((g ^ sx) * 8)]);
#pragma unroll
    for (int mi = 0; mi < MI; ++mi)
#pragma unroll
      for (int ni = 0; ni < 4; ++ni)
        acc[mi][ni] = __builtin_amdgcn_mfma_f32_16x16x32_bf16(af[mi], bf[ni],
                                                              acc[mi][ni], 0, 0, 0);
    __builtin_amdgcn_sched_barrier(0);   // keep k-half-1 reads after MFMA batch
#pragma unroll
    for (int mi = 0; mi < MI; ++mi)
      af[mi] = *reinterpret_cast<const s8v*>(
          &As[(wr * (BM / 2) + mi * 16 + lr) * 64 + (((4 + g) ^ sx) * 8)]);
#pragma unroll
    for (int ni = 0; ni < 4; ++ni)
      bf[ni] = *reinterpret_cast<const s8v*>(
          &Bs[(wc * 64 + ni * 16 + lr) * 64 + (((4 + g) ^ sx) * 8)]);
    __syncthreads();               // all frag reads done -> LDS reusable
    if (k0 + 64 < kend) stage(k0 + 64);  // next-tile loads fly under MFMA
#pragma unroll
    for (int mi = 0; mi < MI; ++mi)
#pragma unroll
      for (int ni = 0; ni < 4; ++ni)
        acc[mi][ni] = __builtin_amdgcn_mfma_f32_16x16x32_bf16(af[mi], bf[ni],
                                                              acc[mi][ni], 0, 0, 0);
  }

  // ---- epilogue: per-wave LDS transpose (aliases As/Bs) -> coalesced stores ----
  __syncthreads();  // all frag reads done before aliasing
  float* sw = (float*)smem + wid * (16 * 36);
  int s = lane >> 3, q = lane & 7;
  for (int mi = 0; mi < MI; ++mi) {
    for (int np = 0; np < 2; ++np) {   // 2 column halves of the wave's 64 cols
#pragma unroll
      for (int ni2 = 0; ni2 < 2; ++ni2)
#pragma unroll
        for (int r = 0; r < 4; ++r)
          sw[(g * 4 + r) * 36 + ni2 * 16 + lr] = acc[mi][np * 2 + ni2][r];
      // wave-private scratch round-trip; compiler inserts lgkm waits
      int gnb = bn * 128 + wc * 64 + np * 32;      // wave-uniform col base
      if constexpr (EPI == EPI_QKV) {
        int z = gnb >> 10;                          // 0=q 1=k 2=v (uniform)
        int row0 = bm * BM + wr * (BM / 2) + mi * 16;  // t base (16 rows)
        int nb = row0 >> 10, tp0 = row0 & 1023;
        int hh = (gnb >> 6) & 15, dd0 = gnb & 63;
        if (z < 2) {                                // q/k: row-major [nh][t][64]
          ushort* o = (ushort*)outp;
#pragma unroll
          for (int h = 0; h < 2; ++h) {
            float4 v4 = *reinterpret_cast<const float4*>(&sw[(h * 8 + s) * 36 + q * 4]);
            int tpos = tp0 + h * 8 + s;
            ushort4 o4 = {f2bf(v4.x), f2bf(v4.y), f2bf(v4.z), f2bf(v4.w)};
            *reinterpret_cast<ushort4*>(o + (size_t)z * 2097152 + (size_t)nb * 1048576 +
                                        (size_t)hh * 65536 + (size_t)tpos * 64 +
                                        dd0 + q * 4) = o4;
          }
        } else {                                    // v: transposed [nh][dv][1024]
          ushort* ov = (ushort*)outp2;
          int dvq = lane & 31, hf = lane >> 5;
          us8 w;
#pragma unroll
          for (int j = 0; j < 8; ++j)
            w[j] = f2bf(sw[(hf * 8 + j) * 36 + dvq]);
          *reinterpret_cast<us8*>(ov + (size_t)nb * 1048576 + (size_t)hh * 65536 +
                                  (size_t)(dd0 + dvq) * 1024 + tp0 + hf * 8) = w;
        }
      } else {
#pragma unroll
        for (int h = 0; h < 2; ++h) {
          float4 v4 = *reinterpret_cast<const float4*>(&sw[(h * 8 + s) * 36 + q * 4]);
          int gm = bm * BM + wr * (BM / 2) + mi * 16 + h * 8 + s;
          int gn = gnb + q * 4;
          if constexpr (EPI == EPI_GELU) {
            const float4 bb = *reinterpret_cast<const float4*>(bias + gn);
            float u[4] = {v4.x + bb.x, v4.y + bb.y, v4.z + bb.z, v4.w + bb.w};
            ushort4 o4;
            ushort* po = (ushort*)&o4;
#pragma unroll
            for (int j = 0; j < 4; ++j) {
              float zz = u[j] * (1.5957691216f + 0.0713548162f * u[j] * u[j]);
              float gl = u[j] / (1.f + exp2f(zz * -1.4426950409f));
              po[j] = f2bf(gl);
            }
            *reinterpret_cast<ushort4*>((ushort*)outp + (size_t)gm * N + gn) = o4;
          } else if constexpr (EPI == EPI_RES) {
            // split-K partials: plain f32 store to slice z; bias in slice 0 only
            float* o = (float*)outp + (size_t)blockIdx.z * 2097152 +
                       (size_t)gm * N + gn;
            float4 bb = *reinterpret_cast<const float4*>(bias + gn);
            bool addb = (blockIdx.z == 0);
            f4v o4 = {v4.x + (addb ? bb.x : 0.f), v4.y + (addb ? bb.y : 0.f),
                      v4.z + (addb ? bb.z : 0.f), v4.w + (addb ? bb.w : 0.f)};
            *reinterpret_cast<f4v*>(o) = o4;
          } else {  // EPI_BIAS (readout): non-temporal
            const float4 bb = *reinterpret_cast<const float4*>(bias + gn);
            f4v o4 = {v4.x + bb.x, v4.y + bb.y, v4.z + bb.z, v4.w + bb.w};
            __builtin_nontemporal_store(o4, (f4v*)((float*)outp + (size_t)gm * N + gn));
          }
        }
      }
    }
  }
}

// ---------- MFMA flash attention ----------
// grid 512: bid = half*256 + bx*32 + nh_r; qt = half ? 15-bx : bx.
// Co-resident blocks (c, c+256) share nh and have complementary qt.
__global__ __launch_bounds__(256) void attn_kernel(const ushort* __restrict__ qg,
                                                   const ushort* __restrict__ kg,
                                                   const ushort* __restrict__ vtg,
                                                   float* __restrict__ x) {
  __shared__ ushort Ks[2][4096];  // [64 s][64 d] bf16, swizzled
  __shared__ ushort Vs[2][4096];  // [64 dv][64 s] bf16, swizzled
  __shared__ ushort Ps[4][1024];  // per-wave P [16 q][64 s] bf16, swizzled
  int bid = blockIdx.x;
  int half = bid >> 8, r = bid & 255;
  int bx = r >> 5, nh = r & 31;
  int qt = half ? (15 - bx) : bx;
  int tid = threadIdx.x, lane = tid & 63, wid = tid >> 6;
  int lr = lane & 15, g = lane >> 4;
  size_t base = (size_t)nh * 65536;
  const ushort* kb = kg + base;
  const ushort* vb = vtg + base;
  const float SCALE = 0.125f * 1.44269504088896f;

  auto stage = [&](int st, int buf) {
    int s0 = st * 64;
#pragma unroll
    for (int j = 0; j < 2; ++j) {
      int c = tid + j * 256;
      int row = c >> 3;
      int col = ((c & 7) ^ (row & 7)) * 8;  // inverse-swizzled source column
      gload16(kb + (size_t)(s0 + row) * 64 + col, &Ks[buf][c * 8]);
      gload16(vb + (size_t)row * 1024 + s0 + col, &Vs[buf][c * 8]);
    }
  };

  int qrow = qt * 64 + wid * 16 + lr;
  s8v qf[2];
  qf[0] = *reinterpret_cast<const s8v*>(qg + base + (size_t)qrow * 64 + g * 8);
  qf[1] = *reinterpret_cast<const s8v*>(qg + base + (size_t)qrow * 64 + 32 + g * 8);

  float m_run = NEG_INF, l_run = 0.f;
  f4v accy[4] = {};
  stage(0, 0);
  int cur = 0;
  for (int st = 0; st <= qt; ++st) {
    __syncthreads();
    if (st < qt) stage(st + 1, cur ^ 1);

    f4v accs[4] = {};
    __builtin_amdgcn_s_setprio(1);
#pragma unroll
    for (int kc = 0; kc < 2; ++kc)
#pragma unroll
      for (int mi = 0; mi < 4; ++mi) {
        int bo = ((mi * 16 + lr) * 128 + kc * 64 + g * 16) ^ ((lr & 7) << 4);
        s8v kf = *reinterpret_cast<const s8v*>(&Ks[cur][bo >> 1]);
        accs[mi] = __builtin_amdgcn_mfma_f32_16x16x32_bf16(kf, qf[kc], accs[mi], 0, 0, 0);
      }
    __builtin_amdgcn_s_setprio(0);

    float z[16];
    float tmax = NEG_INF;
    bool diag = (st == qt);
    int qcol = qt * 64 + wid * 16 + lr;
#pragma unroll
    for (int mi = 0; mi < 4; ++mi)
#pragma unroll
      for (int r2 = 0; r2 < 4; ++r2) {
        float zz = accs[mi][r2] * SCALE;
        if (diag && st * 64 + mi * 16 + g * 4 + r2 > qcol) zz = NEG_INF;
        z[mi * 4 + r2] = zz;
        tmax = fmaxf(tmax, zz);
      }
    tmax = fmaxf(tmax, __shfl_xor(tmax, 16));
    tmax = fmaxf(tmax, __shfl_xor(tmax, 32));
    float m_new = fmaxf(m_run, tmax);
    float corr = exp2f(m_run - m_new);
    float psum = 0.f;
    ushort pb[16];
#pragma unroll
    for (int i = 0; i < 16; ++i) {
      float pv = exp2f(z[i] - m_new);
      psum += pv;
      pb[i] = f2bf(pv);
    }
    psum += __shfl_xor(psum, 16);
    psum += __shfl_xor(psum, 32);
    l_run = l_run * corr + psum;
    m_run = m_new;

    {
      ushort* pw = Ps[wid];
#pragma unroll
      for (int mi = 0; mi < 4; ++mi) {
        int bo = (lr * 128 + mi * 32 + g * 8) ^ ((lr & 7) << 4);
        ushort4 w4 = {pb[mi * 4], pb[mi * 4 + 1], pb[mi * 4 + 2], pb[mi * 4 + 3]};
        *reinterpret_cast<ushort4*>(&pw[bo >> 1]) = w4;
      }
    }

    float cq[4];
#pragma unroll
    for (int r2 = 0; r2 < 4; ++r2) cq[r2] = __shfl(corr, (lane >> 4) * 4 + r2);
#pragma unroll
    for (int ni = 0; ni < 4; ++ni)
#pragma unroll
      for (int r2 = 0; r2 < 4; ++r2) accy[ni][r2] *= cq[r2];

    __builtin_amdgcn_s_setprio(1);
#pragma unroll
    for (int ks = 0; ks < 2; ++ks) {
      int po = (lr * 128 + ks * 64 + g * 16) ^ ((lr & 7) << 4);
      s8v pa = *reinterpret_cast<const s8v*>(&Ps[wid][po >> 1]);
#pragma unroll
      for (int ni = 0; ni < 4; ++ni) {
        int vo = ((ni * 16 + lr) * 128 + ks * 64 + g * 16) ^ ((lr & 7) << 4);
        s8v vf = *reinterpret_cast<const s8v*>(&Vs[cur][vo >> 1]);
        accy[ni] = __builtin_amdgcn_mfma_f32_16x16x32_bf16(pa, vf, accy[ni], 0, 0, 0);
      }
    }
    __builtin_amdgcn_s_setprio(0);
    cur ^= 1;
  }

  float lq[4];
#pragma unroll
  for (int r2 = 0; r2 < 4; ++r2) lq[r2] = 1.f / __shfl(l_run, (lane >> 4) * 4 + r2);
  int n = nh >> 4, hh = nh & 15;
  float* xb = x + ((size_t)(n * 1024 + qt * 64 + wid * 16)) * 1024 + hh * 64;
#pragma unroll
  for (int r2 = 0; r2 < 4; ++r2) {
    float* xr = xb + (size_t)(g * 4 + r2) * 1024;
#pragma unroll
    for (int ni = 0; ni < 4; ++ni)
      xr[ni * 16 + lr] += accy[ni][r2] * lq[r2];
  }
}

// ---------------------------------------------------------------------------
extern "C" void kernel_launch(void* const* d_in, const int* in_sizes, int n_in,
                              void* d_out, int out_size, void* d_ws, size_t ws_size,
                              hipStream_t stream) {
  const int*   ids  = (const int*)  d_in[0];
  const float* emb  = (const float*)d_in[1];
  const float* ln1w = (const float*)d_in[2];
  const float* ln1b = (const float*)d_in[3];
  const float* wq   = (const float*)d_in[4];
  const float* wk   = (const float*)d_in[5];
  const float* wv   = (const float*)d_in[6];
  const float* ln2w = (const float*)d_in[7];
  const float* ln2b = (const float*)d_in[8];
  const float* fc1w = (const float*)d_in[9];
  const float* fc1b = (const float*)d_in[10];
  const float* fc2w = (const float*)d_in[11];
  const float* fc2b = (const float*)d_in[12];
  const float* row_ = (const float*)d_in[13];
  const float* rob  = (const float*)d_in[14];
  (void)in_sizes; (void)n_in; (void)out_size;

  char* p = (char*)d_ws;
  auto carve = [&](size_t bytes) {
    char* r = p;
    p += (bytes + 255) & ~(size_t)255;
    return (void*)r;
  };
  ushort* ro_bf = (ushort*)carve(32000ull * 1024 * 2);
  float*  x     = (float*) carve(2048ull * 1024 * 4);
  ushort* h     = (ushort*)carve(2048ull * 1024 * 2);
  ushort* qkvb  = (ushort*)carve(3ull * 2097152 * 2);   // bf16 q/k [z][nh][t][64]
  ushort* vtb   = (ushort*)carve(2097152ull * 2);       // bf16 vT [nh][64][1024]
  ushort* mbuf  = (ushort*)carve(2048ull * 4096 * 2);
  ushort* xb    = (ushort*)carve(2048ull * 1024 * 2);
  float*  pbuf  = (float*) carve(4ull * 2097152 * 4);   // RES split-K partials (z=4)
  size_t used_common = (size_t)(p - (char*)d_ws);

  const size_t SZ_WQKV_ALL = 3ull * 8388608 * 2;   // merged [L][3][1M]
  const size_t SZ_FC_ALL   = 33554432ull * 2;
  const size_t SZ_WQKV_1   = 3ull * 1048576 * 2;
  const size_t SZ_FC_1     = 4194304ull * 2;
  bool upfront = ws_size >= used_common + SZ_WQKV_ALL + 2 * SZ_FC_ALL + 4096;

  ushort *wqkv_bf, *fc1_bf, *fc2_bf;
  size_t lq3, lf;
  if (upfront) {
    wqkv_bf = (ushort*)carve(SZ_WQKV_ALL);
    fc1_bf  = (ushort*)carve(SZ_FC_ALL);
    fc2_bf  = (ushort*)carve(SZ_FC_ALL);
    lq3 = 3145728; lf = 4194304;
    cvtall_kernel<<<15264, 256, 0, stream>>>(wq, wk, wv, fc1w, fc2w, row_,
                                             wqkv_bf, fc1_bf, fc2_bf, ro_bf);
  } else {
    wqkv_bf = (ushort*)carve(SZ_WQKV_1);
    fc1_bf  = (ushort*)carve(SZ_FC_1);
    fc2_bf  = (ushort*)carve(SZ_FC_1);
    lq3 = 0; lf = 0;
    cvt_kernel<<<32000, 256, 0, stream>>>(row_, ro_bf, 32768000);
  }

  embed_kernel<<<2048, 256, 0, stream>>>(ids, emb, x);

  for (int l = 0; l < 8; ++l) {
    if (!upfront) {
      cvt_kernel<<<1024, 256, 0, stream>>>(wq + (size_t)l * 1048576, wqkv_bf, 1048576);
      cvt_kernel<<<1024, 256, 0, stream>>>(wk + (size_t)l * 1048576, wqkv_bf + 1048576, 1048576);
      cvt_kernel<<<1024, 256, 0, stream>>>(wv + (size_t)l * 1048576, wqkv_bf + 2097152, 1048576);
      cvt_kernel<<<4096, 256, 0, stream>>>(fc1w + (size_t)l * 4194304, fc1_bf, 4194304);
      cvt_kernel<<<4096, 256, 0, stream>>>(fc2w + (size_t)l * 4194304, fc2_bf, 4194304);
    }
    const ushort* wqkv_l = wqkv_bf + (size_t)l * lq3;
    const ushort* fc1_l  = fc1_bf + (size_t)l * lf;
    const ushort* fc2_l  = fc2_bf + (size_t)l * lf;

    // LN1 folds previous layer's RES partials into x (layer 0: no fold)
    ln_kernel<<<2048, 256, 0, stream>>>(x, pbuf, ln1w + l * 1024, ln1b + l * 1024,
                                        h, l > 0);
    gemm_kernel<EPI_QKV, 64><<<dim3(32, 24), 256, 0, stream>>>(
        h, wqkv_l, nullptr, qkvb, vtb, 2048, 3072, 1024, 0);
    attn_kernel<<<512, 256, 0, stream>>>(qkvb, qkvb + 2097152, vtb, x);
    ln_kernel<<<2048, 256, 0, stream>>>(x, nullptr, ln2w + l * 1024, ln2b + l * 1024,
                                        h, 0);
    gemm_kernel<EPI_GELU, 64><<<dim3(32, 32), 256, 0, stream>>>(
        h, fc1_l, fc1b + (size_t)l * 4096, mbuf, nullptr, 2048, 4096, 1024, 0);
    gemm_kernel<EPI_RES, 64><<<dim3(32, 8, 4), 256, 0, stream>>>(
        mbuf, fc2_l, fc2b + (size_t)l * 1024, pbuf, nullptr, 2048, 1024, 4096, 1024);
  }
  cvtfold_kernel<<<2048, 256, 0, stream>>>(x, pbuf, xb);
  gemm_kernel<EPI_BIAS, 128><<<dim3(16, 250), 256, 0, stream>>>(
      xb, ro_bf, rob, d_out, nullptr, 2048, 32000, 1024, 0);
}

// Round 18
// 1221.738 us; speedup vs baseline: 1.6550x; 1.0777x over previous
//
#include <hip/hip_runtime.h>
#include <cstdint>

// PicoGPT forward: V=32000 D=1024 DK=DV=64 H=16 DH=4096 L=8, input [2,1024]
// bf16 MFMA GEMMs: BK=64, XOR-swizzled LDS, global_load_lds both operands
// (m97+T2), XCD swizzle (T1), RES split-K z=4 plain partials folded in LN1.
// R18: T5 setprio around GEMM MFMA clusters (multi-block/CU phase diversity);
// nt-store for ro_bf in cvtall (consumed ~1ms later, keep L2 for layer weights).

#define DEVI __device__ __forceinline__
#define NEG_INF (-__builtin_inff())

typedef __attribute__((ext_vector_type(8))) short s8v;            // 8 x bf16
typedef __attribute__((ext_vector_type(8))) unsigned short us8;   // 8 x bf16 store
typedef __attribute__((ext_vector_type(4))) unsigned short us4;   // 4 x bf16 store
typedef __attribute__((ext_vector_type(4))) float f4v;

DEVI ushort f2bf(float f) {  // RTNE f32 -> bf16
  uint32_t x = __float_as_uint(f);
  x += 0x7fffu + ((x >> 16) & 1u);
  return (ushort)(x >> 16);
}

DEVI void gload16(const void* g, void* l) {  // async global->LDS, 16B/lane
  __builtin_amdgcn_global_load_lds((const __attribute__((address_space(1))) void*)g,
                                   (__attribute__((address_space(3))) void*)l, 16, 0, 0);
}

// ---------- f32 -> bf16 convert (generic) ----------
__global__ __launch_bounds__(256) void cvt_kernel(const float* __restrict__ in,
                                                  ushort* __restrict__ out, int n) {
  int i = (blockIdx.x * 256 + threadIdx.x) * 4;
  if (i >= n) return;
  float4 v = *reinterpret_cast<const float4*>(in + i);
  ushort4 o;
  o.x = f2bf(v.x); o.y = f2bf(v.y); o.z = f2bf(v.z); o.w = f2bf(v.w);
  *reinterpret_cast<ushort4*>(out + i) = o;
}

// ---------- final fold: xb = bf16(x + p0+p1+p2+p3), grid 2048 ----------
__global__ __launch_bounds__(256) void cvtfold_kernel(const float* __restrict__ x,
                                                      const float* __restrict__ pb,
                                                      ushort* __restrict__ out) {
  size_t i = ((size_t)blockIdx.x * 256 + threadIdx.x) * 4;
  float4 v = *reinterpret_cast<const float4*>(x + i);
#pragma unroll
  for (int z = 0; z < 4; ++z) {
    float4 a = *reinterpret_cast<const float4*>(pb + (size_t)z * 2097152 + i);
    v.x += a.x; v.y += a.y; v.z += a.z; v.w += a.w;
  }
  ushort4 o = {f2bf(v.x), f2bf(v.y), f2bf(v.z), f2bf(v.w)};
  *reinterpret_cast<ushort4*>(out + i) = o;
}

// ---------- all weights f32 -> bf16, 8-way ILP, nt loads ----------
// grid = 125042688/8192 = 15264 blocks; every segment boundary divides 8192.
__global__ __launch_bounds__(256) void cvtall_kernel(const float* __restrict__ wq,
                                                     const float* __restrict__ wk,
                                                     const float* __restrict__ wv,
                                                     const float* __restrict__ fc1w,
                                                     const float* __restrict__ fc2w,
                                                     const float* __restrict__ row_,
                                                     ushort* __restrict__ wqkv_bf,
                                                     ushort* __restrict__ fc1_bf,
                                                     ushort* __restrict__ fc2_bf,
                                                     ushort* __restrict__ ro_bf) {
  const size_t NQ3 = 25165824, NF = 33554432;   // 3*8M, 32M
  size_t b0 = (size_t)blockIdx.x * 8192;
  const float* src;
  ushort* dst;
  bool is_ro = false;
  if (b0 < NQ3) {                                // qkv -> [L][3][1M] interleave
    int which = (int)(b0 >> 23);
    size_t j = b0 & 8388607;
    src = (which == 0 ? wq : which == 1 ? wk : wv) + j;
    dst = wqkv_bf + (j >> 20) * 3145728 + (size_t)which * 1048576 + (j & 1048575);
  } else if (b0 < NQ3 + NF) {
    size_t r = b0 - NQ3;
    src = fc1w + r; dst = fc1_bf + r;
  } else if (b0 < NQ3 + 2 * NF) {
    size_t r = b0 - NQ3 - NF;
    src = fc2w + r; dst = fc2_bf + r;
  } else {
    size_t r = b0 - NQ3 - 2 * NF;
    src = row_ + r; dst = ro_bf + r;
    is_ro = true;                                // consumed ~1ms later: nt store
  }
  int t4 = threadIdx.x * 4;
  f4v v[8];
#pragma unroll
  for (int k = 0; k < 8; ++k)
    v[k] = __builtin_nontemporal_load(reinterpret_cast<const f4v*>(src + t4 + k * 1024));
  if (is_ro) {
#pragma unroll
    for (int k = 0; k < 8; ++k) {
      us4 o = {f2bf(v[k].x), f2bf(v[k].y), f2bf(v[k].z), f2bf(v[k].w)};
      __builtin_nontemporal_store(o, reinterpret_cast<us4*>(dst + t4 + k * 1024));
    }
  } else {
#pragma unroll
    for (int k = 0; k < 8; ++k) {
      ushort4 o = {f2bf(v[k].x), f2bf(v[k].y), f2bf(v[k].z), f2bf(v[k].w)};
      *reinterpret_cast<ushort4*>(dst + t4 + k * 1024) = o;
    }
  }
}

// ---------- embedding + sinusoidal pos encoding, grid = 2048 rows ----------
__global__ __launch_bounds__(256) void embed_kernel(const int* __restrict__ ids,
                                                    const float* __restrict__ emb,
                                                    float* __restrict__ x) {
  int row = blockIdx.x;  // n*1024 + t
  int t = row & 1023;
  int id = ids[row];
  int d0 = threadIdx.x * 4;
  float4 e = *reinterpret_cast<const float4*>(emb + (size_t)id * 1024 + d0);
  float pe[4];
#pragma unroll
  for (int i = 0; i < 4; ++i) {
    int d = d0 + i;
    float dv = expf((float)(d & ~1) * (-9.210340371976184f / 1024.f));
    float ang = (float)t * dv;
    pe[i] = (d & 1) ? cosf(ang) : sinf(ang);
  }
  float4 o;
  o.x = e.x + pe[0]; o.y = e.y + pe[1]; o.z = e.z + pe[2]; o.w = e.w + pe[3];
  *reinterpret_cast<float4*>(x + (size_t)row * 1024 + d0) = o;
}

// ---------- LayerNorm (+ optional 4-slice partial fold), grid = 2048 rows ----------
__global__ __launch_bounds__(256) void ln_kernel(float* __restrict__ x,
                                                 const float* __restrict__ pb,
                                                 const float* __restrict__ w,
                                                 const float* __restrict__ b,
                                                 ushort* __restrict__ out, int fold) {
  int row = blockIdx.x, tid = threadIdx.x;
  int lane = tid & 63, wid = tid >> 6;
  float* xr = x + (size_t)row * 1024;
  float4 v = reinterpret_cast<const float4*>(xr)[tid];
  if (fold) {
    size_t off = (size_t)row * 1024 + tid * 4;
#pragma unroll
    for (int z = 0; z < 4; ++z) {
      float4 a = *reinterpret_cast<const float4*>(pb + (size_t)z * 2097152 + off);
      v.x += a.x; v.y += a.y; v.z += a.z; v.w += a.w;
    }
    reinterpret_cast<float4*>(xr)[tid] = v;
  }
  __shared__ float red[8];
  float s = v.x + v.y + v.z + v.w;
#pragma unroll
  for (int o = 32; o; o >>= 1) s += __shfl_xor(s, o);
  if (lane == 0) red[wid] = s;
  __syncthreads();
  float mean = (red[0] + red[1] + red[2] + red[3]) * (1.f / 1024.f);
  float d0 = v.x - mean, d1 = v.y - mean, d2 = v.z - mean, d3 = v.w - mean;
  float s2 = d0 * d0 + d1 * d1 + d2 * d2 + d3 * d3;
#pragma unroll
  for (int o = 32; o; o >>= 1) s2 += __shfl_xor(s2, o);
  if (lane == 0) red[4 + wid] = s2;
  __syncthreads();
  float var = (red[4] + red[5] + red[6] + red[7]) * (1.f / 1024.f);
  float rstd = rsqrtf(var + 1e-5f);
  float4 wv = reinterpret_cast<const float4*>(w)[tid];
  float4 bv = reinterpret_cast<const float4*>(b)[tid];
  ushort4 o;
  o.x = f2bf(d0 * rstd * wv.x + bv.x);
  o.y = f2bf(d1 * rstd * wv.y + bv.y);
  o.z = f2bf(d2 * rstd * wv.z + bv.z);
  o.w = f2bf(d3 * rstd * wv.w + bv.w);
  *reinterpret_cast<ushort4*>(out + (size_t)row * 1024 + tid * 4) = o;
}

// ---------- bf16 MFMA GEMM: C[M,N] = A[M,K] * Bw[N,K]^T ----------
// BMx128 tile, BK=64, 256 thr = 4 waves (2x2), wave = (BM/2)x64.
// XCD-bijective swizzle (needs gridDim.x*gridDim.y % 8 == 0).
enum { EPI_QKV = 0, EPI_GELU = 1, EPI_RES = 2, EPI_BIAS = 3 };

template <int EPI, int BM>
__global__ __launch_bounds__(256, BM == 64 ? 5 : 4)
void gemm_kernel(const ushort* __restrict__ A,
                 const ushort* __restrict__ Bw,
                 const float* __restrict__ bias,
                 void* __restrict__ outp,
                 void* __restrict__ outp2,
                 int M, int N, int K, int kz) {
  constexpr int MI = BM / 32;            // 16-row frag groups per wave
  __shared__ char smem[BM * 128 + 16384];
  ushort* As = (ushort*)smem;            // [BM][64] bf16, chunk-swizzled
  ushort* Bs = (ushort*)(smem + BM * 128);  // [128][64]
  int tid = threadIdx.x;
  int lane = tid & 63;
  int wid = tid >> 6;
  int wr = wid >> 1, wc = wid & 1;       // 2x2 wave grid, wave = (BM/2)x64

  // XCD swizzle: consecutive tiles land on one XCD -> B panels fetched once/XCD
  int gx = gridDim.x;
  int nwg = gx * gridDim.y;
  int bid = blockIdx.x + blockIdx.y * gx;
  int swz = (bid & 7) * (nwg >> 3) + (bid >> 3);
  int bm = swz % gx, bn = swz / gx;

  int kbeg = 0, kend = K;
  if constexpr (EPI == EPI_RES) {        // split-K over gridDim.z
    kbeg = blockIdx.z * kz;
    kend = kbeg + kz;
  }

  const ushort* Ab = A + (size_t)(bm * BM) * K;
  const ushort* Bb = Bw + (size_t)(bn * 128) * K;

  auto stage = [&](int k0) {
#pragma unroll
    for (int i = 0; i < BM / 32; ++i) {  // BM*8 chunks of 16B
      int c = tid + i * 256;
      int row = c >> 3, j = c & 7;
      gload16(Ab + (size_t)row * K + k0 + ((j ^ (row & 7)) * 8), &As[c * 8]);
    }
#pragma unroll
    for (int i = 0; i < 4; ++i) {
      int c = tid + i * 256;
      int row = c >> 3, j = c & 7;
      gload16(Bb + (size_t)row * K + k0 + ((j ^ (row & 7)) * 8), &Bs[c * 8]);
    }
  };

  f4v acc[MI][4] = {};
  int lr = lane & 15, g = lane >> 4;
  int sx = lr & 7;  // swizzle key (row&7 of every frag row this lane reads)

  stage(kbeg);
  for (int k0 = kbeg; k0 < kend; k0 += 64) {
    __syncthreads();  // staging complete (compiler drains vmcnt at barrier)
    s8v af[MI], bf[4];
#pragma unroll
    for (int mi = 0; mi < MI; ++mi)
      af[mi] = *reinterpret_cast<const s8v*>(
          &As[(wr * (BM / 2) + mi * 16 + lr) * 64 + ((g ^ sx) * 8)]);
#pragma unroll
    for (int ni = 0; ni < 4; ++ni)
      bf[ni] = *reinterpret_cast<const s8v*>(
          &Bs[(wc * 64 + ni * 16 + lr) * 64 + ((g ^ sx) * 8)]);
    __builtin_amdgcn_s_setprio(1);
#pragma unroll
    for (int mi = 0; mi < MI; ++mi)
#pragma unroll
      for (int ni = 0; ni < 4; ++ni)
        acc[mi][ni] = __builtin_amdgcn_mfma_f32_16x16x32_bf16(af[mi], bf[ni],
                                                              acc[mi][ni], 0, 0, 0);
    __builtin_amdgcn_s_setprio(0);
    __builtin_amdgcn_sched_barrier(0);   // keep k-half-1 reads after MFMA batch
#pragma unroll
    for (int mi = 0; mi < MI; ++mi)
      af[mi] = *reinterpret_cast<const s8v*>(
          &As[(wr * (BM / 2) + mi * 16 + lr) * 64 + (((4 + g) ^ sx) * 8)]);
#pragma unroll
    for (int ni = 0; ni < 4; ++ni)
      bf[ni] = *reinterpret_cast<const s8v*>(
          &Bs[(wc * 64 + ni * 16 + lr) * 64 + (((4 + g) ^ sx) * 8)]);
    __syncthreads();               // all frag reads done -> LDS reusable
    if (k0 + 64 < kend) stage(k0 + 64);  // next-tile loads fly under MFMA
    __builtin_amdgcn_s_setprio(1);
#pragma unroll
    for (int mi = 0; mi < MI; ++mi)
#pragma unroll
      for (int ni = 0; ni < 4; ++ni)
        acc[mi][ni] = __builtin_amdgcn_mfma_f32_16x16x32_bf16(af[mi], bf[ni],
                                                              acc[mi][ni], 0, 0, 0);
    __builtin_amdgcn_s_setprio(0);
  }

  // ---- epilogue: per-wave LDS transpose (aliases As/Bs) -> coalesced stores ----
  __syncthreads();  // all frag reads done before aliasing
  float* sw = (float*)smem + wid * (16 * 36);
  int s = lane >> 3, q = lane & 7;
  for (int mi = 0; mi < MI; ++mi) {
    for (int np = 0; np < 2; ++np) {   // 2 column halves of the wave's 64 cols
#pragma unroll
      for (int ni2 = 0; ni2 < 2; ++ni2)
#pragma unroll
        for (int r = 0; r < 4; ++r)
          sw[(g * 4 + r) * 36 + ni2 * 16 + lr] = acc[mi][np * 2 + ni2][r];
      // wave-private scratch round-trip; compiler inserts lgkm waits
      int gnb = bn * 128 + wc * 64 + np * 32;      // wave-uniform col base
      if constexpr (EPI == EPI_QKV) {
        int z = gnb >> 10;                          // 0=q 1=k 2=v (uniform)
        int row0 = bm * BM + wr * (BM / 2) + mi * 16;  // t base (16 rows)
        int nb = row0 >> 10, tp0 = row0 & 1023;
        int hh = (gnb >> 6) & 15, dd0 = gnb & 63;
        if (z < 2) {                                // q/k: row-major [nh][t][64]
          ushort* o = (ushort*)outp;
#pragma unroll
          for (int h = 0; h < 2; ++h) {
            float4 v4 = *reinterpret_cast<const float4*>(&sw[(h * 8 + s) * 36 + q * 4]);
            int tpos = tp0 + h * 8 + s;
            ushort4 o4 = {f2bf(v4.x), f2bf(v4.y), f2bf(v4.z), f2bf(v4.w)};
            *reinterpret_cast<ushort4*>(o + (size_t)z * 2097152 + (size_t)nb * 1048576 +
                                        (size_t)hh * 65536 + (size_t)tpos * 64 +
                                        dd0 + q * 4) = o4;
          }
        } else {                                    // v: transposed [nh][dv][1024]
          ushort* ov = (ushort*)outp2;
          int dvq = lane & 31, hf = lane >> 5;
          us8 w;
#pragma unroll
          for (int j = 0; j < 8; ++j)
            w[j] = f2bf(sw[(hf * 8 + j) * 36 + dvq]);
          *reinterpret_cast<us8*>(ov + (size_t)nb * 1048576 + (size_t)hh * 65536 +
                                  (size_t)(dd0 + dvq) * 1024 + tp0 + hf * 8) = w;
        }
      } else {
#pragma unroll
        for (int h = 0; h < 2; ++h) {
          float4 v4 = *reinterpret_cast<const float4*>(&sw[(h * 8 + s) * 36 + q * 4]);
          int gm = bm * BM + wr * (BM / 2) + mi * 16 + h * 8 + s;
          int gn = gnb + q * 4;
          if constexpr (EPI == EPI_GELU) {
            const float4 bb = *reinterpret_cast<const float4*>(bias + gn);
            float u[4] = {v4.x + bb.x, v4.y + bb.y, v4.z + bb.z, v4.w + bb.w};
            ushort4 o4;
            ushort* po = (ushort*)&o4;
#pragma unroll
            for (int j = 0; j < 4; ++j) {
              float zz = u[j] * (1.5957691216f + 0.0713548162f * u[j] * u[j]);
              float gl = u[j] / (1.f + exp2f(zz * -1.4426950409f));
              po[j] = f2bf(gl);
            }
            *reinterpret_cast<ushort4*>((ushort*)outp + (size_t)gm * N + gn) = o4;
          } else if constexpr (EPI == EPI_RES) {
            // split-K partials: plain f32 store to slice z; bias in slice 0 only
            float* o = (float*)outp + (size_t)blockIdx.z * 2097152 +
                       (size_t)gm * N + gn;
            float4 bb = *reinterpret_cast<const float4*>(bias + gn);
            bool addb = (blockIdx.z == 0);
            f4v o4 = {v4.x + (addb ? bb.x : 0.f), v4.y + (addb ? bb.y : 0.f),
                      v4.z + (addb ? bb.z : 0.f), v4.w + (addb ? bb.w : 0.f)};
            *reinterpret_cast<f4v*>(o) = o4;
          } else {  // EPI_BIAS (readout): non-temporal
            const float4 bb = *reinterpret_cast<const float4*>(bias + gn);
            f4v o4 = {v4.x + bb.x, v4.y + bb.y, v4.z + bb.z, v4.w + bb.w};
            __builtin_nontemporal_store(o4, (f4v*)((float*)outp + (size_t)gm * N + gn));
          }
        }
      }
    }
  }
}

// ---------- MFMA flash attention ----------
// grid 512: bid = half*256 + bx*32 + nh_r; qt = half ? 15-bx : bx.
// Co-resident blocks (c, c+256) share nh and have complementary qt.
__global__ __launch_bounds__(256) void attn_kernel(const ushort* __restrict__ qg,
                                                   const ushort* __restrict__ kg,
                                                   const ushort* __restrict__ vtg,
                                                   float* __restrict__ x) {
  __shared__ ushort Ks[2][4096];  // [64 s][64 d] bf16, swizzled
  __shared__ ushort Vs[2][4096];  // [64 dv][64 s] bf16, swizzled
  __shared__ ushort Ps[4][1024];  // per-wave P [16 q][64 s] bf16, swizzled
  int bid = blockIdx.x;
  int half = bid >> 8, r = bid & 255;
  int bx = r >> 5, nh = r & 31;
  int qt = half ? (15 - bx) : bx;
  int tid = threadIdx.x, lane = tid & 63, wid = tid >> 6;
  int lr = lane & 15, g = lane >> 4;
  size_t base = (size_t)nh * 65536;
  const ushort* kb = kg + base;
  const ushort* vb = vtg + base;
  const float SCALE = 0.125f * 1.44269504088896f;

  auto stage = [&](int st, int buf) {
    int s0 = st * 64;
#pragma unroll
    for (int j = 0; j < 2; ++j) {
      int c = tid + j * 256;
      int row = c >> 3;
      int col = ((c & 7) ^ (row & 7)) * 8;  // inverse-swizzled source column
      gload16(kb + (size_t)(s0 + row) * 64 + col, &Ks[buf][c * 8]);
      gload16(vb + (size_t)row * 1024 + s0 + col, &Vs[buf][c * 8]);
    }
  };

  int qrow = qt * 64 + wid * 16 + lr;
  s8v qf[2];
  qf[0] = *reinterpret_cast<const s8v*>(qg + base + (size_t)qrow * 64 + g * 8);
  qf[1] = *reinterpret_cast<const s8v*>(qg + base + (size_t)qrow * 64 + 32 + g * 8);

  float m_run = NEG_INF, l_run = 0.f;
  f4v accy[4] = {};
  stage(0, 0);
  int cur = 0;
  for (int st = 0; st <= qt; ++st) {
    __syncthreads();
    if (st < qt) stage(st + 1, cur ^ 1);

    f4v accs[4] = {};
    __builtin_amdgcn_s_setprio(1);
#pragma unroll
    for (int kc = 0; kc < 2; ++kc)
#pragma unroll
      for (int mi = 0; mi < 4; ++mi) {
        int bo = ((mi * 16 + lr) * 128 + kc * 64 + g * 16) ^ ((lr & 7) << 4);
        s8v kf = *reinterpret_cast<const s8v*>(&Ks[cur][bo >> 1]);
        accs[mi] = __builtin_amdgcn_mfma_f32_16x16x32_bf16(kf, qf[kc], accs[mi], 0, 0, 0);
      }
    __builtin_amdgcn_s_setprio(0);

    float z[16];
    float tmax = NEG_INF;
    bool diag = (st == qt);
    int qcol = qt * 64 + wid * 16 + lr;
#pragma unroll
    for (int mi = 0; mi < 4; ++mi)
#pragma unroll
      for (int r2 = 0; r2 < 4; ++r2) {
        float zz = accs[mi][r2] * SCALE;
        if (diag && st * 64 + mi * 16 + g * 4 + r2 > qcol) zz = NEG_INF;
        z[mi * 4 + r2] = zz;
        tmax = fmaxf(tmax, zz);
      }
    tmax = fmaxf(tmax, __shfl_xor(tmax, 16));
    tmax = fmaxf(tmax, __shfl_xor(tmax, 32));
    float m_new = fmaxf(m_run, tmax);
    float corr = exp2f(m_run - m_new);
    float psum = 0.f;
    ushort pb[16];
#pragma unroll
    for (int i = 0; i < 16; ++i) {
      float pv = exp2f(z[i] - m_new);
      psum += pv;
      pb[i] = f2bf(pv);
    }
    psum += __shfl_xor(psum, 16);
    psum += __shfl_xor(psum, 32);
    l_run = l_run * corr + psum;
    m_run = m_new;

    {
      ushort* pw = Ps[wid];
#pragma unroll
      for (int mi = 0; mi < 4; ++mi) {
        int bo = (lr * 128 + mi * 32 + g * 8) ^ ((lr & 7) << 4);
        ushort4 w4 = {pb[mi * 4], pb[mi * 4 + 1], pb[mi * 4 + 2], pb[mi * 4 + 3]};
        *reinterpret_cast<ushort4*>(&pw[bo >> 1]) = w4;
      }
    }

    float cq[4];
#pragma unroll
    for (int r2 = 0; r2 < 4; ++r2) cq[r2] = __shfl(corr, (lane >> 4) * 4 + r2);
#pragma unroll
    for (int ni = 0; ni < 4; ++ni)
#pragma unroll
      for (int r2 = 0; r2 < 4; ++r2) accy[ni][r2] *= cq[r2];

    __builtin_amdgcn_s_setprio(1);
#pragma unroll
    for (int ks = 0; ks < 2; ++ks) {
      int po = (lr * 128 + ks * 64 + g * 16) ^ ((lr & 7) << 4);
      s8v pa = *reinterpret_cast<const s8v*>(&Ps[wid][po >> 1]);
#pragma unroll
      for (int ni = 0; ni < 4; ++ni) {
        int vo = ((ni * 16 + lr) * 128 + ks * 64 + g * 16) ^ ((lr & 7) << 4);
        s8v vf = *reinterpret_cast<const s8v*>(&Vs[cur][vo >> 1]);
        accy[ni] = __builtin_amdgcn_mfma_f32_16x16x32_bf16(pa, vf, accy[ni], 0, 0, 0);
      }
    }
    __builtin_amdgcn_s_setprio(0);
    cur ^= 1;
  }

  float lq[4];
#pragma unroll
  for (int r2 = 0; r2 < 4; ++r2) lq[r2] = 1.f / __shfl(l_run, (lane >> 4) * 4 + r2);
  int n = nh >> 4, hh = nh & 15;
  float* xb = x + ((size_t)(n * 1024 + qt * 64 + wid * 16)) * 1024 + hh * 64;
#pragma unroll
  for (int r2 = 0; r2 < 4; ++r2) {
    float* xr = xb + (size_t)(g * 4 + r2) * 1024;
#pragma unroll
    for (int ni = 0; ni < 4; ++ni)
      xr[ni * 16 + lr] += accy[ni][r2] * lq[r2];
  }
}

// ---------------------------------------------------------------------------
extern "C" void kernel_launch(void* const* d_in, const int* in_sizes, int n_in,
                              void* d_out, int out_size, void* d_ws, size_t ws_size,
                              hipStream_t stream) {
  const int*   ids  = (const int*)  d_in[0];
  const float* emb  = (const float*)d_in[1];
  const float* ln1w = (const float*)d_in[2];
  const float* ln1b = (const float*)d_in[3];
  const float* wq   = (const float*)d_in[4];
  const float* wk   = (const float*)d_in[5];
  const float* wv   = (const float*)d_in[6];
  const float* ln2w = (const float*)d_in[7];
  const float* ln2b = (const float*)d_in[8];
  const float* fc1w = (const float*)d_in[9];
  const float* fc1b = (const float*)d_in[10];
  const float* fc2w = (const float*)d_in[11];
  const float* fc2b = (const float*)d_in[12];
  const float* row_ = (const float*)d_in[13];
  const float* rob  = (const float*)d_in[14];
  (void)in_sizes; (void)n_in; (void)out_size;

  char* p = (char*)d_ws;
  auto carve = [&](size_t bytes) {
    char* r = p;
    p += (bytes + 255) & ~(size_t)255;
    return (void*)r;
  };
  ushort* ro_bf = (ushort*)carve(32000ull * 1024 * 2);
  float*  x     = (float*) carve(2048ull * 1024 * 4);
  ushort* h     = (ushort*)carve(2048ull * 1024 * 2);
  ushort* qkvb  = (ushort*)carve(3ull * 2097152 * 2);   // bf16 q/k [z][nh][t][64]
  ushort* vtb   = (ushort*)carve(2097152ull * 2);       // bf16 vT [nh][64][1024]
  ushort* mbuf  = (ushort*)carve(2048ull * 4096 * 2);
  ushort* xb    = (ushort*)carve(2048ull * 1024 * 2);
  float*  pbuf  = (float*) carve(4ull * 2097152 * 4);   // RES split-K partials (z=4)
  size_t used_common = (size_t)(p - (char*)d_ws);

  const size_t SZ_WQKV_ALL = 3ull * 8388608 * 2;   // merged [L][3][1M]
  const size_t SZ_FC_ALL   = 33554432ull * 2;
  const size_t SZ_WQKV_1   = 3ull * 1048576 * 2;
  const size_t SZ_FC_1     = 4194304ull * 2;
  bool upfront = ws_size >= used_common + SZ_WQKV_ALL + 2 * SZ_FC_ALL + 4096;

  ushort *wqkv_bf, *fc1_bf, *fc2_bf;
  size_t lq3, lf;
  if (upfront) {
    wqkv_bf = (ushort*)carve(SZ_WQKV_ALL);
    fc1_bf  = (ushort*)carve(SZ_FC_ALL);
    fc2_bf  = (ushort*)carve(SZ_FC_ALL);
    lq3 = 3145728; lf = 4194304;
    cvtall_kernel<<<15264, 256, 0, stream>>>(wq, wk, wv, fc1w, fc2w, row_,
                                             wqkv_bf, fc1_bf, fc2_bf, ro_bf);
  } else {
    wqkv_bf = (ushort*)carve(SZ_WQKV_1);
    fc1_bf  = (ushort*)carve(SZ_FC_1);
    fc2_bf  = (ushort*)carve(SZ_FC_1);
    lq3 = 0; lf = 0;
    cvt_kernel<<<32000, 256, 0, stream>>>(row_, ro_bf, 32768000);
  }

  embed_kernel<<<2048, 256, 0, stream>>>(ids, emb, x);

  for (int l = 0; l < 8; ++l) {
    if (!upfront) {
      cvt_kernel<<<1024, 256, 0, stream>>>(wq + (size_t)l * 1048576, wqkv_bf, 1048576);
      cvt_kernel<<<1024, 256, 0, stream>>>(wk + (size_t)l * 1048576, wqkv_bf + 1048576, 1048576);
      cvt_kernel<<<1024, 256, 0, stream>>>(wv + (size_t)l * 1048576, wqkv_bf + 2097152, 1048576);
      cvt_kernel<<<4096, 256, 0, stream>>>(fc1w + (size_t)l * 4194304, fc1_bf, 4194304);
      cvt_kernel<<<4096, 256, 0, stream>>>(fc2w + (size_t)l * 4194304, fc2_bf, 4194304);
    }
    const ushort* wqkv_l = wqkv_bf + (size_t)l * lq3;
    const ushort* fc1_l  = fc1_bf + (size_t)l * lf;
    const ushort* fc2_l  = fc2_bf + (size_t)l * lf;

    // LN1 folds previous layer's RES partials into x (layer 0: no fold)
    ln_kernel<<<2048, 256, 0, stream>>>(x, pbuf, ln1w + l * 1024, ln1b + l * 1024,
                                        h, l > 0);
    gemm_kernel<EPI_QKV, 64><<<dim3(32, 24), 256, 0, stream>>>(
        h, wqkv_l, nullptr, qkvb, vtb, 2048, 3072, 1024, 0);
    attn_kernel<<<512, 256, 0, stream>>>(qkvb, qkvb + 2097152, vtb, x);
    ln_kernel<<<2048, 256, 0, stream>>>(x, nullptr, ln2w + l * 1024, ln2b + l * 1024,
                                        h, 0);
    gemm_kernel<EPI_GELU, 64><<<dim3(32, 32), 256, 0, stream>>>(
        h, fc1_l, fc1b + (size_t)l * 4096, mbuf, nullptr, 2048, 4096, 1024, 0);
    gemm_kernel<EPI_RES, 64><<<dim3(32, 8, 4), 256, 0, stream>>>(
        mbuf, fc2_l, fc2b + (size_t)l * 1024, pbuf, nullptr, 2048, 1024, 4096, 1024);
  }
  cvtfold_kernel<<<2048, 256, 0, stream>>>(x, pbuf, xb);
  gemm_kernel<EPI_BIAS, 128><<<dim3(16, 250), 256, 0, stream>>>(
      xb, ro_bf, rob, d_out, nullptr, 2048, 32000, 1024, 0);
}

// Round 19
// 1164.603 us; speedup vs baseline: 1.7362x; 1.0491x over previous
//
#include <hip/hip_runtime.h>
#include <cstdint>

// PicoGPT forward: V=32000 D=1024 DK=DV=64 H=16 DH=4096 L=8, input [2,1024]
// bf16 MFMA GEMMs: BK=64, XOR-swizzled LDS, global_load_lds both operands
// (m97+T2), XCD swizzle (T1), RES split-K z=4 partials folded in LN1, T5
// setprio in all MFMA clusters. R19: bf16 RES partials (halves partial
// write + fold-read traffic; intermediates tolerate bf16 rounding).

#define DEVI __device__ __forceinline__
#define NEG_INF (-__builtin_inff())

typedef __attribute__((ext_vector_type(8))) short s8v;            // 8 x bf16
typedef __attribute__((ext_vector_type(8))) unsigned short us8;   // 8 x bf16 store
typedef __attribute__((ext_vector_type(4))) unsigned short us4;   // 4 x bf16 store
typedef __attribute__((ext_vector_type(4))) float f4v;

DEVI ushort f2bf(float f) {  // RTNE f32 -> bf16
  uint32_t x = __float_as_uint(f);
  x += 0x7fffu + ((x >> 16) & 1u);
  return (ushort)(x >> 16);
}

DEVI float bf2f(ushort u) { return __uint_as_float((uint32_t)u << 16); }

DEVI void gload16(const void* g, void* l) {  // async global->LDS, 16B/lane
  __builtin_amdgcn_global_load_lds((const __attribute__((address_space(1))) void*)g,
                                   (__attribute__((address_space(3))) void*)l, 16, 0, 0);
}

// ---------- f32 -> bf16 convert (generic) ----------
__global__ __launch_bounds__(256) void cvt_kernel(const float* __restrict__ in,
                                                  ushort* __restrict__ out, int n) {
  int i = (blockIdx.x * 256 + threadIdx.x) * 4;
  if (i >= n) return;
  float4 v = *reinterpret_cast<const float4*>(in + i);
  ushort4 o;
  o.x = f2bf(v.x); o.y = f2bf(v.y); o.z = f2bf(v.z); o.w = f2bf(v.w);
  *reinterpret_cast<ushort4*>(out + i) = o;
}

// ---------- final fold: xb = bf16(x + sum of 4 bf16 partial slices) ----------
__global__ __launch_bounds__(256) void cvtfold_kernel(const float* __restrict__ x,
                                                      const ushort* __restrict__ pb,
                                                      ushort* __restrict__ out) {
  size_t i = ((size_t)blockIdx.x * 256 + threadIdx.x) * 4;
  float4 v = *reinterpret_cast<const float4*>(x + i);
#pragma unroll
  for (int z = 0; z < 4; ++z) {
    ushort4 a = *reinterpret_cast<const ushort4*>(pb + (size_t)z * 2097152 + i);
    v.x += bf2f(a.x); v.y += bf2f(a.y); v.z += bf2f(a.z); v.w += bf2f(a.w);
  }
  ushort4 o = {f2bf(v.x), f2bf(v.y), f2bf(v.z), f2bf(v.w)};
  *reinterpret_cast<ushort4*>(out + i) = o;
}

// ---------- all weights f32 -> bf16, 8-way ILP, nt loads ----------
// grid = 125042688/8192 = 15264 blocks; every segment boundary divides 8192.
__global__ __launch_bounds__(256) void cvtall_kernel(const float* __restrict__ wq,
                                                     const float* __restrict__ wk,
                                                     const float* __restrict__ wv,
                                                     const float* __restrict__ fc1w,
                                                     const float* __restrict__ fc2w,
                                                     const float* __restrict__ row_,
                                                     ushort* __restrict__ wqkv_bf,
                                                     ushort* __restrict__ fc1_bf,
                                                     ushort* __restrict__ fc2_bf,
                                                     ushort* __restrict__ ro_bf) {
  const size_t NQ3 = 25165824, NF = 33554432;   // 3*8M, 32M
  size_t b0 = (size_t)blockIdx.x * 8192;
  const float* src;
  ushort* dst;
  bool is_ro = false;
  if (b0 < NQ3) {                                // qkv -> [L][3][1M] interleave
    int which = (int)(b0 >> 23);
    size_t j = b0 & 8388607;
    src = (which == 0 ? wq : which == 1 ? wk : wv) + j;
    dst = wqkv_bf + (j >> 20) * 3145728 + (size_t)which * 1048576 + (j & 1048575);
  } else if (b0 < NQ3 + NF) {
    size_t r = b0 - NQ3;
    src = fc1w + r; dst = fc1_bf + r;
  } else if (b0 < NQ3 + 2 * NF) {
    size_t r = b0 - NQ3 - NF;
    src = fc2w + r; dst = fc2_bf + r;
  } else {
    size_t r = b0 - NQ3 - 2 * NF;
    src = row_ + r; dst = ro_bf + r;
    is_ro = true;                                // consumed ~1ms later: nt store
  }
  int t4 = threadIdx.x * 4;
  f4v v[8];
#pragma unroll
  for (int k = 0; k < 8; ++k)
    v[k] = __builtin_nontemporal_load(reinterpret_cast<const f4v*>(src + t4 + k * 1024));
  if (is_ro) {
#pragma unroll
    for (int k = 0; k < 8; ++k) {
      us4 o = {f2bf(v[k].x), f2bf(v[k].y), f2bf(v[k].z), f2bf(v[k].w)};
      __builtin_nontemporal_store(o, reinterpret_cast<us4*>(dst + t4 + k * 1024));
    }
  } else {
#pragma unroll
    for (int k = 0; k < 8; ++k) {
      ushort4 o = {f2bf(v[k].x), f2bf(v[k].y), f2bf(v[k].z), f2bf(v[k].w)};
      *reinterpret_cast<ushort4*>(dst + t4 + k * 1024) = o;
    }
  }
}

// ---------- embedding + sinusoidal pos encoding, grid = 2048 rows ----------
__global__ __launch_bounds__(256) void embed_kernel(const int* __restrict__ ids,
                                                    const float* __restrict__ emb,
                                                    float* __restrict__ x) {
  int row = blockIdx.x;  // n*1024 + t
  int t = row & 1023;
  int id = ids[row];
  int d0 = threadIdx.x * 4;
  float4 e = *reinterpret_cast<const float4*>(emb + (size_t)id * 1024 + d0);
  float pe[4];
#pragma unroll
  for (int i = 0; i < 4; ++i) {
    int d = d0 + i;
    float dv = expf((float)(d & ~1) * (-9.210340371976184f / 1024.f));
    float ang = (float)t * dv;
    pe[i] = (d & 1) ? cosf(ang) : sinf(ang);
  }
  float4 o;
  o.x = e.x + pe[0]; o.y = e.y + pe[1]; o.z = e.z + pe[2]; o.w = e.w + pe[3];
  *reinterpret_cast<float4*>(x + (size_t)row * 1024 + d0) = o;
}

// ---------- LayerNorm (+ optional 4-slice bf16 partial fold), grid = 2048 ----------
__global__ __launch_bounds__(256) void ln_kernel(float* __restrict__ x,
                                                 const ushort* __restrict__ pb,
                                                 const float* __restrict__ w,
                                                 const float* __restrict__ b,
                                                 ushort* __restrict__ out, int fold) {
  int row = blockIdx.x, tid = threadIdx.x;
  int lane = tid & 63, wid = tid >> 6;
  float* xr = x + (size_t)row * 1024;
  float4 v = reinterpret_cast<const float4*>(xr)[tid];
  if (fold) {
    size_t off = (size_t)row * 1024 + tid * 4;
#pragma unroll
    for (int z = 0; z < 4; ++z) {
      ushort4 a = *reinterpret_cast<const ushort4*>(pb + (size_t)z * 2097152 + off);
      v.x += bf2f(a.x); v.y += bf2f(a.y); v.z += bf2f(a.z); v.w += bf2f(a.w);
    }
    reinterpret_cast<float4*>(xr)[tid] = v;
  }
  __shared__ float red[8];
  float s = v.x + v.y + v.z + v.w;
#pragma unroll
  for (int o = 32; o; o >>= 1) s += __shfl_xor(s, o);
  if (lane == 0) red[wid] = s;
  __syncthreads();
  float mean = (red[0] + red[1] + red[2] + red[3]) * (1.f / 1024.f);
  float d0 = v.x - mean, d1 = v.y - mean, d2 = v.z - mean, d3 = v.w - mean;
  float s2 = d0 * d0 + d1 * d1 + d2 * d2 + d3 * d3;
#pragma unroll
  for (int o = 32; o; o >>= 1) s2 += __shfl_xor(s2, o);
  if (lane == 0) red[4 + wid] = s2;
  __syncthreads();
  float var = (red[4] + red[5] + red[6] + red[7]) * (1.f / 1024.f);
  float rstd = rsqrtf(var + 1e-5f);
  float4 wv = reinterpret_cast<const float4*>(w)[tid];
  float4 bv = reinterpret_cast<const float4*>(b)[tid];
  ushort4 o;
  o.x = f2bf(d0 * rstd * wv.x + bv.x);
  o.y = f2bf(d1 * rstd * wv.y + bv.y);
  o.z = f2bf(d2 * rstd * wv.z + bv.z);
  o.w = f2bf(d3 * rstd * wv.w + bv.w);
  *reinterpret_cast<ushort4*>(out + (size_t)row * 1024 + tid * 4) = o;
}

// ---------- bf16 MFMA GEMM: C[M,N] = A[M,K] * Bw[N,K]^T ----------
// BMx128 tile, BK=64, 256 thr = 4 waves (2x2), wave = (BM/2)x64.
// XCD-bijective swizzle (needs gridDim.x*gridDim.y % 8 == 0).
enum { EPI_QKV = 0, EPI_GELU = 1, EPI_RES = 2, EPI_BIAS = 3 };

template <int EPI, int BM>
__global__ __launch_bounds__(256, BM == 64 ? 5 : 4)
void gemm_kernel(const ushort* __restrict__ A,
                 const ushort* __restrict__ Bw,
                 const float* __restrict__ bias,
                 void* __restrict__ outp,
                 void* __restrict__ outp2,
                 int M, int N, int K, int kz) {
  constexpr int MI = BM / 32;            // 16-row frag groups per wave
  __shared__ char smem[BM * 128 + 16384];
  ushort* As = (ushort*)smem;            // [BM][64] bf16, chunk-swizzled
  ushort* Bs = (ushort*)(smem + BM * 128);  // [128][64]
  int tid = threadIdx.x;
  int lane = tid & 63;
  int wid = tid >> 6;
  int wr = wid >> 1, wc = wid & 1;       // 2x2 wave grid, wave = (BM/2)x64

  // XCD swizzle: consecutive tiles land on one XCD -> B panels fetched once/XCD
  int gx = gridDim.x;
  int nwg = gx * gridDim.y;
  int bid = blockIdx.x + blockIdx.y * gx;
  int swz = (bid & 7) * (nwg >> 3) + (bid >> 3);
  int bm = swz % gx, bn = swz / gx;

  int kbeg = 0, kend = K;
  if constexpr (EPI == EPI_RES) {        // split-K over gridDim.z
    kbeg = blockIdx.z * kz;
    kend = kbeg + kz;
  }

  const ushort* Ab = A + (size_t)(bm * BM) * K;
  const ushort* Bb = Bw + (size_t)(bn * 128) * K;

  auto stage = [&](int k0) {
#pragma unroll
    for (int i = 0; i < BM / 32; ++i) {  // BM*8 chunks of 16B
      int c = tid + i * 256;
      int row = c >> 3, j = c & 7;
      gload16(Ab + (size_t)row * K + k0 + ((j ^ (row & 7)) * 8), &As[c * 8]);
    }
#pragma unroll
    for (int i = 0; i < 4; ++i) {
      int c = tid + i * 256;
      int row = c >> 3, j = c & 7;
      gload16(Bb + (size_t)row * K + k0 + ((j ^ (row & 7)) * 8), &Bs[c * 8]);
    }
  };

  f4v acc[MI][4] = {};
  int lr = lane & 15, g = lane >> 4;
  int sx = lr & 7;  // swizzle key (row&7 of every frag row this lane reads)

  stage(kbeg);
  for (int k0 = kbeg; k0 < kend; k0 += 64) {
    __syncthreads();  // staging complete (compiler drains vmcnt at barrier)
    s8v af[MI], bf[4];
#pragma unroll
    for (int mi = 0; mi < MI; ++mi)
      af[mi] = *reinterpret_cast<const s8v*>(
          &As[(wr * (BM / 2) + mi * 16 + lr) * 64 + ((g ^ sx) * 8)]);
#pragma unroll
    for (int ni = 0; ni < 4; ++ni)
      bf[ni] = *reinterpret_cast<const s8v*>(
          &Bs[(wc * 64 + ni * 16 + lr) * 64 + ((g ^ sx) * 8)]);
    __builtin_amdgcn_s_setprio(1);
#pragma unroll
    for (int mi = 0; mi < MI; ++mi)
#pragma unroll
      for (int ni = 0; ni < 4; ++ni)
        acc[mi][ni] = __builtin_amdgcn_mfma_f32_16x16x32_bf16(af[mi], bf[ni],
                                                              acc[mi][ni], 0, 0, 0);
    __builtin_amdgcn_s_setprio(0);
    __builtin_amdgcn_sched_barrier(0);   // keep k-half-1 reads after MFMA batch
#pragma unroll
    for (int mi = 0; mi < MI; ++mi)
      af[mi] = *reinterpret_cast<const s8v*>(
          &As[(wr * (BM / 2) + mi * 16 + lr) * 64 + (((4 + g) ^ sx) * 8)]);
#pragma unroll
    for (int ni = 0; ni < 4; ++ni)
      bf[ni] = *reinterpret_cast<const s8v*>(
          &Bs[(wc * 64 + ni * 16 + lr) * 64 + (((4 + g) ^ sx) * 8)]);
    __syncthreads();               // all frag reads done -> LDS reusable
    if (k0 + 64 < kend) stage(k0 + 64);  // next-tile loads fly under MFMA
    __builtin_amdgcn_s_setprio(1);
#pragma unroll
    for (int mi = 0; mi < MI; ++mi)
#pragma unroll
      for (int ni = 0; ni < 4; ++ni)
        acc[mi][ni] = __builtin_amdgcn_mfma_f32_16x16x32_bf16(af[mi], bf[ni],
                                                              acc[mi][ni], 0, 0, 0);
    __builtin_amdgcn_s_setprio(0);
  }

  // ---- epilogue: per-wave LDS transpose (aliases As/Bs) -> coalesced stores ----
  __syncthreads();  // all frag reads done before aliasing
  float* sw = (float*)smem + wid * (16 * 36);
  int s = lane >> 3, q = lane & 7;
  for (int mi = 0; mi < MI; ++mi) {
    for (int np = 0; np < 2; ++np) {   // 2 column halves of the wave's 64 cols
#pragma unroll
      for (int ni2 = 0; ni2 < 2; ++ni2)
#pragma unroll
        for (int r = 0; r < 4; ++r)
          sw[(g * 4 + r) * 36 + ni2 * 16 + lr] = acc[mi][np * 2 + ni2][r];
      // wave-private scratch round-trip; compiler inserts lgkm waits
      int gnb = bn * 128 + wc * 64 + np * 32;      // wave-uniform col base
      if constexpr (EPI == EPI_QKV) {
        int z = gnb >> 10;                          // 0=q 1=k 2=v (uniform)
        int row0 = bm * BM + wr * (BM / 2) + mi * 16;  // t base (16 rows)
        int nb = row0 >> 10, tp0 = row0 & 1023;
        int hh = (gnb >> 6) & 15, dd0 = gnb & 63;
        if (z < 2) {                                // q/k: row-major [nh][t][64]
          ushort* o = (ushort*)outp;
#pragma unroll
          for (int h = 0; h < 2; ++h) {
            float4 v4 = *reinterpret_cast<const float4*>(&sw[(h * 8 + s) * 36 + q * 4]);
            int tpos = tp0 + h * 8 + s;
            ushort4 o4 = {f2bf(v4.x), f2bf(v4.y), f2bf(v4.z), f2bf(v4.w)};
            *reinterpret_cast<ushort4*>(o + (size_t)z * 2097152 + (size_t)nb * 1048576 +
                                        (size_t)hh * 65536 + (size_t)tpos * 64 +
                                        dd0 + q * 4) = o4;
          }
        } else {                                    // v: transposed [nh][dv][1024]
          ushort* ov = (ushort*)outp2;
          int dvq = lane & 31, hf = lane >> 5;
          us8 w;
#pragma unroll
          for (int j = 0; j < 8; ++j)
            w[j] = f2bf(sw[(hf * 8 + j) * 36 + dvq]);
          *reinterpret_cast<us8*>(ov + (size_t)nb * 1048576 + (size_t)hh * 65536 +
                                  (size_t)(dd0 + dvq) * 1024 + tp0 + hf * 8) = w;
        }
      } else {
#pragma unroll
        for (int h = 0; h < 2; ++h) {
          float4 v4 = *reinterpret_cast<const float4*>(&sw[(h * 8 + s) * 36 + q * 4]);
          int gm = bm * BM + wr * (BM / 2) + mi * 16 + h * 8 + s;
          int gn = gnb + q * 4;
          if constexpr (EPI == EPI_GELU) {
            const float4 bb = *reinterpret_cast<const float4*>(bias + gn);
            float u[4] = {v4.x + bb.x, v4.y + bb.y, v4.z + bb.z, v4.w + bb.w};
            ushort4 o4;
            ushort* po = (ushort*)&o4;
#pragma unroll
            for (int j = 0; j < 4; ++j) {
              float zz = u[j] * (1.5957691216f + 0.0713548162f * u[j] * u[j]);
              float gl = u[j] / (1.f + exp2f(zz * -1.4426950409f));
              po[j] = f2bf(gl);
            }
            *reinterpret_cast<ushort4*>((ushort*)outp + (size_t)gm * N + gn) = o4;
          } else if constexpr (EPI == EPI_RES) {
            // split-K partials: bf16 store to slice z; bias in slice 0 only
            ushort* o = (ushort*)outp + (size_t)blockIdx.z * 2097152 +
                        (size_t)gm * N + gn;
            float4 bb = *reinterpret_cast<const float4*>(bias + gn);
            bool addb = (blockIdx.z == 0);
            ushort4 o4 = {f2bf(v4.x + (addb ? bb.x : 0.f)),
                          f2bf(v4.y + (addb ? bb.y : 0.f)),
                          f2bf(v4.z + (addb ? bb.z : 0.f)),
                          f2bf(v4.w + (addb ? bb.w : 0.f))};
            *reinterpret_cast<ushort4*>(o) = o4;
          } else {  // EPI_BIAS (readout): non-temporal
            const float4 bb = *reinterpret_cast<const float4*>(bias + gn);
            f4v o4 = {v4.x + bb.x, v4.y + bb.y, v4.z + bb.z, v4.w + bb.w};
            __builtin_nontemporal_store(o4, (f4v*)((float*)outp + (size_t)gm * N + gn));
          }
        }
      }
    }
  }
}

// ---------- MFMA flash attention ----------
// grid 512: bid = half*256 + bx*32 + nh_r; qt = half ? 15-bx : bx.
// Co-resident blocks (c, c+256) share nh and have complementary qt.
__global__ __launch_bounds__(256) void attn_kernel(const ushort* __restrict__ qg,
                                                   const ushort* __restrict__ kg,
                                                   const ushort* __restrict__ vtg,
                                                   float* __restrict__ x) {
  __shared__ ushort Ks[2][4096];  // [64 s][64 d] bf16, swizzled
  __shared__ ushort Vs[2][4096];  // [64 dv][64 s] bf16, swizzled
  __shared__ ushort Ps[4][1024];  // per-wave P [16 q][64 s] bf16, swizzled
  int bid = blockIdx.x;
  int half = bid >> 8, r = bid & 255;
  int bx = r >> 5, nh = r & 31;
  int qt = half ? (15 - bx) : bx;
  int tid = threadIdx.x, lane = tid & 63, wid = tid >> 6;
  int lr = lane & 15, g = lane >> 4;
  size_t base = (size_t)nh * 65536;
  const ushort* kb = kg + base;
  const ushort* vb = vtg + base;
  const float SCALE = 0.125f * 1.44269504088896f;

  auto stage = [&](int st, int buf) {
    int s0 = st * 64;
#pragma unroll
    for (int j = 0; j < 2; ++j) {
      int c = tid + j * 256;
      int row = c >> 3;
      int col = ((c & 7) ^ (row & 7)) * 8;  // inverse-swizzled source column
      gload16(kb + (size_t)(s0 + row) * 64 + col, &Ks[buf][c * 8]);
      gload16(vb + (size_t)row * 1024 + s0 + col, &Vs[buf][c * 8]);
    }
  };

  int qrow = qt * 64 + wid * 16 + lr;
  s8v qf[2];
  qf[0] = *reinterpret_cast<const s8v*>(qg + base + (size_t)qrow * 64 + g * 8);
  qf[1] = *reinterpret_cast<const s8v*>(qg + base + (size_t)qrow * 64 + 32 + g * 8);

  float m_run = NEG_INF, l_run = 0.f;
  f4v accy[4] = {};
  stage(0, 0);
  int cur = 0;
  for (int st = 0; st <= qt; ++st) {
    __syncthreads();
    if (st < qt) stage(st + 1, cur ^ 1);

    f4v accs[4] = {};
    __builtin_amdgcn_s_setprio(1);
#pragma unroll
    for (int kc = 0; kc < 2; ++kc)
#pragma unroll
      for (int mi = 0; mi < 4; ++mi) {
        int bo = ((mi * 16 + lr) * 128 + kc * 64 + g * 16) ^ ((lr & 7) << 4);
        s8v kf = *reinterpret_cast<const s8v*>(&Ks[cur][bo >> 1]);
        accs[mi] = __builtin_amdgcn_mfma_f32_16x16x32_bf16(kf, qf[kc], accs[mi], 0, 0, 0);
      }
    __builtin_amdgcn_s_setprio(0);

    float z[16];
    float tmax = NEG_INF;
    bool diag = (st == qt);
    int qcol = qt * 64 + wid * 16 + lr;
#pragma unroll
    for (int mi = 0; mi < 4; ++mi)
#pragma unroll
      for (int r2 = 0; r2 < 4; ++r2) {
        float zz = accs[mi][r2] * SCALE;
        if (diag && st * 64 + mi * 16 + g * 4 + r2 > qcol) zz = NEG_INF;
        z[mi * 4 + r2] = zz;
        tmax = fmaxf(tmax, zz);
      }
    tmax = fmaxf(tmax, __shfl_xor(tmax, 16));
    tmax = fmaxf(tmax, __shfl_xor(tmax, 32));
    float m_new = fmaxf(m_run, tmax);
    float corr = exp2f(m_run - m_new);
    float psum = 0.f;
    ushort pb[16];
#pragma unroll
    for (int i = 0; i < 16; ++i) {
      float pv = exp2f(z[i] - m_new);
      psum += pv;
      pb[i] = f2bf(pv);
    }
    psum += __shfl_xor(psum, 16);
    psum += __shfl_xor(psum, 32);
    l_run = l_run * corr + psum;
    m_run = m_new;

    {
      ushort* pw = Ps[wid];
#pragma unroll
      for (int mi = 0; mi < 4; ++mi) {
        int bo = (lr * 128 + mi * 32 + g * 8) ^ ((lr & 7) << 4);
        ushort4 w4 = {pb[mi * 4], pb[mi * 4 + 1], pb[mi * 4 + 2], pb[mi * 4 + 3]};
        *reinterpret_cast<ushort4*>(&pw[bo >> 1]) = w4;
      }
    }

    float cq[4];
#pragma unroll
    for (int r2 = 0; r2 < 4; ++r2) cq[r2] = __shfl(corr, (lane >> 4) * 4 + r2);
#pragma unroll
    for (int ni = 0; ni < 4; ++ni)
#pragma unroll
      for (int r2 = 0; r2 < 4; ++r2) accy[ni][r2] *= cq[r2];

    __builtin_amdgcn_s_setprio(1);
#pragma unroll
    for (int ks = 0; ks < 2; ++ks) {
      int po = (lr * 128 + ks * 64 + g * 16) ^ ((lr & 7) << 4);
      s8v pa = *reinterpret_cast<const s8v*>(&Ps[wid][po >> 1]);
#pragma unroll
      for (int ni = 0; ni < 4; ++ni) {
        int vo = ((ni * 16 + lr) * 128 + ks * 64 + g * 16) ^ ((lr & 7) << 4);
        s8v vf = *reinterpret_cast<const s8v*>(&Vs[cur][vo >> 1]);
        accy[ni] = __builtin_amdgcn_mfma_f32_16x16x32_bf16(pa, vf, accy[ni], 0, 0, 0);
      }
    }
    __builtin_amdgcn_s_setprio(0);
    cur ^= 1;
  }

  float lq[4];
#pragma unroll
  for (int r2 = 0; r2 < 4; ++r2) lq[r2] = 1.f / __shfl(l_run, (lane >> 4) * 4 + r2);
  int n = nh >> 4, hh = nh & 15;
  float* xb = x + ((size_t)(n * 1024 + qt * 64 + wid * 16)) * 1024 + hh * 64;
#pragma unroll
  for (int r2 = 0; r2 < 4; ++r2) {
    float* xr = xb + (size_t)(g * 4 + r2) * 1024;
#pragma unroll
    for (int ni = 0; ni < 4; ++ni)
      xr[ni * 16 + lr] += accy[ni][r2] * lq[r2];
  }
}

// ---------------------------------------------------------------------------
extern "C" void kernel_launch(void* const* d_in, const int* in_sizes, int n_in,
                              void* d_out, int out_size, void* d_ws, size_t ws_size,
                              hipStream_t stream) {
  const int*   ids  = (const int*)  d_in[0];
  const float* emb  = (const float*)d_in[1];
  const float* ln1w = (const float*)d_in[2];
  const float* ln1b = (const float*)d_in[3];
  const float* wq   = (const float*)d_in[4];
  const float* wk   = (const float*)d_in[5];
  const float* wv   = (const float*)d_in[6];
  const float* ln2w = (const float*)d_in[7];
  const float* ln2b = (const float*)d_in[8];
  const float* fc1w = (const float*)d_in[9];
  const float* fc1b = (const float*)d_in[10];
  const float* fc2w = (const float*)d_in[11];
  const float* fc2b = (const float*)d_in[12];
  const float* row_ = (const float*)d_in[13];
  const float* rob  = (const float*)d_in[14];
  (void)in_sizes; (void)n_in; (void)out_size;

  char* p = (char*)d_ws;
  auto carve = [&](size_t bytes) {
    char* r = p;
    p += (bytes + 255) & ~(size_t)255;
    return (void*)r;
  };
  ushort* ro_bf = (ushort*)carve(32000ull * 1024 * 2);
  float*  x     = (float*) carve(2048ull * 1024 * 4);
  ushort* h     = (ushort*)carve(2048ull * 1024 * 2);
  ushort* qkvb  = (ushort*)carve(3ull * 2097152 * 2);   // bf16 q/k [z][nh][t][64]
  ushort* vtb   = (ushort*)carve(2097152ull * 2);       // bf16 vT [nh][64][1024]
  ushort* mbuf  = (ushort*)carve(2048ull * 4096 * 2);
  ushort* xb    = (ushort*)carve(2048ull * 1024 * 2);
  ushort* pbuf  = (ushort*)carve(4ull * 2097152 * 2);   // RES split-K bf16 partials
  size_t used_common = (size_t)(p - (char*)d_ws);

  const size_t SZ_WQKV_ALL = 3ull * 8388608 * 2;   // merged [L][3][1M]
  const size_t SZ_FC_ALL   = 33554432ull * 2;
  const size_t SZ_WQKV_1   = 3ull * 1048576 * 2;
  const size_t SZ_FC_1     = 4194304ull * 2;
  bool upfront = ws_size >= used_common + SZ_WQKV_ALL + 2 * SZ_FC_ALL + 4096;

  ushort *wqkv_bf, *fc1_bf, *fc2_bf;
  size_t lq3, lf;
  if (upfront) {
    wqkv_bf = (ushort*)carve(SZ_WQKV_ALL);
    fc1_bf  = (ushort*)carve(SZ_FC_ALL);
    fc2_bf  = (ushort*)carve(SZ_FC_ALL);
    lq3 = 3145728; lf = 4194304;
    cvtall_kernel<<<15264, 256, 0, stream>>>(wq, wk, wv, fc1w, fc2w, row_,
                                             wqkv_bf, fc1_bf, fc2_bf, ro_bf);
  } else {
    wqkv_bf = (ushort*)carve(SZ_WQKV_1);
    fc1_bf  = (ushort*)carve(SZ_FC_1);
    fc2_bf  = (ushort*)carve(SZ_FC_1);
    lq3 = 0; lf = 0;
    cvt_kernel<<<32000, 256, 0, stream>>>(row_, ro_bf, 32768000);
  }

  embed_kernel<<<2048, 256, 0, stream>>>(ids, emb, x);

  for (int l = 0; l < 8; ++l) {
    if (!upfront) {
      cvt_kernel<<<1024, 256, 0, stream>>>(wq + (size_t)l * 1048576, wqkv_bf, 1048576);
      cvt_kernel<<<1024, 256, 0, stream>>>(wk + (size_t)l * 1048576, wqkv_bf + 1048576, 1048576);
      cvt_kernel<<<1024, 256, 0, stream>>>(wv + (size_t)l * 1048576, wqkv_bf + 2097152, 1048576);
      cvt_kernel<<<4096, 256, 0, stream>>>(fc1w + (size_t)l * 4194304, fc1_bf, 4194304);
      cvt_kernel<<<4096, 256, 0, stream>>>(fc2w + (size_t)l * 4194304, fc2_bf, 4194304);
    }
    const ushort* wqkv_l = wqkv_bf + (size_t)l * lq3;
    const ushort* fc1_l  = fc1_bf + (size_t)l * lf;
    const ushort* fc2_l  = fc2_bf + (size_t)l * lf;

    // LN1 folds previous layer's RES partials into x (layer 0: no fold)
    ln_kernel<<<2048, 256, 0, stream>>>(x, pbuf, ln1w + l * 1024, ln1b + l * 1024,
                                        h, l > 0);
    gemm_kernel<EPI_QKV, 64><<<dim3(32, 24), 256, 0, stream>>>(
        h, wqkv_l, nullptr, qkvb, vtb, 2048, 3072, 1024, 0);
    attn_kernel<<<512, 256, 0, stream>>>(qkvb, qkvb + 2097152, vtb, x);
    ln_kernel<<<2048, 256, 0, stream>>>(x, nullptr, ln2w + l * 1024, ln2b + l * 1024,
                                        h, 0);
    gemm_kernel<EPI_GELU, 64><<<dim3(32, 32), 256, 0, stream>>>(
        h, fc1_l, fc1b + (size_t)l * 4096, mbuf, nullptr, 2048, 4096, 1024, 0);
    gemm_kernel<EPI_RES, 64><<<dim3(32, 8, 4), 256, 0, stream>>>(
        mbuf, fc2_l, fc2b + (size_t)l * 1024, pbuf, nullptr, 2048, 1024, 4096, 1024);
  }
  cvtfold_kernel<<<2048, 256, 0, stream>>>(x, pbuf, xb);
  gemm_kernel<EPI_BIAS, 128><<<dim3(16, 250), 256, 0, stream>>>(
      xb, ro_bf, rob, d_out, nullptr, 2048, 32000, 1024, 0);
}